// Round 6
// baseline (2907.292 us; speedup 1.0000x reference)
//
#include <hip/hip_runtime.h>

#define NB 512
#define NT 274
#define ND 256
#define NH 512
#define NHH 1024
#define NPOS (NB*NT)
#define EPSF 1e-5f
#define UST 520    // LDS row stride for u/uc/v (1040B, 16B-mult, ==4 dw mod 32)

typedef float f32x4 __attribute__((ext_vector_type(4)));
typedef unsigned int u32x4 __attribute__((ext_vector_type(4)));
typedef unsigned int u32x2 __attribute__((ext_vector_type(2)));

__device__ __forceinline__ float bf2f(unsigned short s) {
    unsigned int u = ((unsigned int)s) << 16;
    float f; __builtin_memcpy(&f, &u, 4); return f;
}
__device__ __forceinline__ unsigned short f2bf(float f) {
    unsigned int u; __builtin_memcpy(&u, &f, 4);
    unsigned int r = u + 0x7FFFu + ((u >> 16) & 1u);   // round-to-nearest-even
    return (unsigned short)(r >> 16);
}

// ---------------- init: h = x[:,:,None]*w_in + b_in + pos ----------------
__global__ __launch_bounds__(256) void k_init(const float* __restrict__ x,
    const float* __restrict__ w_in, const float* __restrict__ b_in,
    const float* __restrict__ pos, float* __restrict__ h)
{
    int row = blockIdx.x;              // 0..NPOS-1  (b*NT + t)
    int d = threadIdx.x;
    int t = row % NT;
    float xv = x[row];
    h[(size_t)row*ND + d] = fmaf(xv, w_in[d], b_in[d] + pos[t*ND + d]);
}

// ------- prep: outw/mixw/inw (f32) -> bf16 -------
__global__ __launch_bounds__(256) void k_prep(const float* __restrict__ outw,
    const float* __restrict__ mixw, const float* __restrict__ inw,
    unsigned short* __restrict__ ob, unsigned short* __restrict__ mb,
    unsigned short* __restrict__ iwb)
{
    int i = blockIdx.x*256 + threadIdx.x;   // 0 .. 786431
    if (i < 524288)      ob[i] = f2bf(outw[i]);                     // L*D*H
    else if (i < 655360) mb[i - 524288] = f2bf(mixw[i - 524288]);   // L*H*64
    else                 iwb[i - 655360] = f2bf(inw[i - 655360]);   // L*1024*32
}

// ------- kA2: LN + grouped in-proj (MFMA 16x16x32, K=32) + silu/sigmoid -------
// Block: 32 time-rows of one batch. 4 waves.  (measured ~84us, ~BW floor)
__global__ __launch_bounds__(256) void kA2(const float* __restrict__ h,
    const float* __restrict__ lng, const float* __restrict__ lnb,
    const unsigned short* __restrict__ inw_b, const float* __restrict__ inb,
    unsigned short* __restrict__ u_ws, unsigned short* __restrict__ g_ws)
{
    const int b  = blockIdx.y;
    const int t0 = blockIdx.x * 32;
    const int tid = threadIdx.x;
    const int lane = tid & 63, wvid = tid >> 6;
    __shared__ __align__(16) unsigned short yl[32][264];  // y bf16, row stride 528B
    __shared__ float s_lng[ND], s_lnb[ND];
    __shared__ float s_inb[NHH];

    s_lng[tid] = lng[tid];
    s_lnb[tid] = lnb[tid];
    #pragma unroll
    for (int q = 0; q < 4; ++q) s_inb[tid + 256*q] = inb[tid + 256*q];

    {
        const int r  = tid >> 3;
        const int c0 = (tid & 7) * 32;
        const int trow = t0 + r;
        float vals[32];
        if (trow < NT) {
            const float4* hp = reinterpret_cast<const float4*>(
                h + ((size_t)b*NT + trow)*ND + c0);
            #pragma unroll
            for (int j = 0; j < 8; ++j) {
                float4 f = hp[j];
                vals[4*j+0]=f.x; vals[4*j+1]=f.y; vals[4*j+2]=f.z; vals[4*j+3]=f.w;
            }
        } else {
            #pragma unroll
            for (int j = 0; j < 32; ++j) vals[j] = 0.0f;
        }
        float s = 0.f, s2 = 0.f;
        #pragma unroll
        for (int j = 0; j < 32; ++j) { s += vals[j]; s2 += vals[j]*vals[j]; }
        #pragma unroll
        for (int off = 1; off < 8; off <<= 1) {
            s  += __shfl_xor(s, off);
            s2 += __shfl_xor(s2, off);
        }
        float mu  = s * (1.0f/ND);
        float var = s2 * (1.0f/ND) - mu*mu;
        float rs  = rsqrtf(var + EPSF);
        __syncthreads();   // s_lng/s_lnb ready
        #pragma unroll
        for (int j = 0; j < 16; ++j) {
            int c = c0 + 2*j;
            float y0 = (vals[2*j]   - mu) * rs * s_lng[c]   + s_lnb[c];
            float y1 = (vals[2*j+1] - mu) * rs * s_lng[c+1] + s_lnb[c+1];
            unsigned int packed = (unsigned)f2bf(y0) | ((unsigned)f2bf(y1) << 16);
            *reinterpret_cast<unsigned int*>(&yl[r][c]) = packed;
        }
    }
    __syncthreads();

    const int r_lo = lane & 15, kb = lane >> 4;
    for (int cb = 0; cb < 4; ++cb) {
        const int combo = wvid*4 + cb;        // 16 combos = 2 row-tiles x 8 groups
        const int rt = combo >> 3, g = combo & 7;
        const int arow = rt*16 + r_lo;
        u32x4 a = *reinterpret_cast<const u32x4*>(&yl[arow][g*32 + kb*8]);
        f32x4 acc[8];
        #pragma unroll
        for (int nt = 0; nt < 8; ++nt) acc[nt] = (f32x4){0.f,0.f,0.f,0.f};
        #pragma unroll
        for (int nt = 0; nt < 8; ++nt) {
            u32x4 bf = *reinterpret_cast<const u32x4*>(inw_b + (size_t)(g*128 + nt*16 + r_lo)*32 + kb*8);
            asm("v_mfma_f32_16x16x32_bf16 %0, %1, %2, %0"
                : "+v"(acc[nt]) : "v"(a), "v"(bf));
        }
        const int crow0 = rt*16 + kb*4;
        #pragma unroll
        for (int nt = 0; nt < 8; ++nt) {
            const int ocol = g*128 + nt*16 + r_lo;
            const float bia = s_inb[ocol];
            #pragma unroll
            for (int r = 0; r < 4; ++r) {
                int trow = t0 + crow0 + r;
                if (trow < NT) {
                    float tv = acc[nt][r] + bia;
                    float sg = 1.0f / (1.0f + __expf(-tv));
                    size_t base = ((size_t)b*NT + trow)*NH;
                    if (ocol < NH) u_ws[base + ocol]      = f2bf(tv * sg);
                    else           g_ws[base + ocol - NH] = f2bf(sg);
                }
            }
        }
    }
}

// ======= kBC: conv + grouped mix + gate + out-proj + residual (fused) =======
// Block: 16 time-rows of one batch (u halo 22 read from HBM). 4 waves. 39.5KB LDS.
__global__ __launch_bounds__(256) void kBC(const unsigned short* __restrict__ u_ws,
    const unsigned short* __restrict__ g_ws, const float* __restrict__ dww,
    const unsigned short* __restrict__ mixw_b, const float* __restrict__ mixb,
    const unsigned short* __restrict__ outw_b, const float* __restrict__ outb,
    float* __restrict__ h)
{
    const int b   = blockIdx.y;
    const int t0  = blockIdx.x * 16;
    const int tid = threadIdx.x;
    const int lane = tid & 63, wvid = tid >> 6;
    const int r_lo = lane & 15, kb = lane >> 4;
    __shared__ __align__(16) unsigned short s_u[22*UST];  // u halo -> later v (16 rows)
    __shared__ __align__(16) unsigned short s_c[16*UST];  // conv output uc

    // --- stage u halo rows t0-3 .. t0+18 (b128, coalesced) ---
    for (int idx = tid; idx < 22*64; idx += 256) {
        int r = idx >> 6, c16 = idx & 63;
        int t = t0 - 3 + r;
        u32x4 val = (u32x4){0u,0u,0u,0u};
        if (t >= 0 && t < NT)
            val = *reinterpret_cast<const u32x4*>(u_ws + ((size_t)b*NT + t)*NH + c16*8);
        *reinterpret_cast<u32x4*>(&s_u[r*UST + c16*8]) = val;
    }
    __syncthreads();

    // --- symmetric depthwise conv: thread owns channels 2*tid, 2*tid+1 ---
    {
        const int c0 = 2*tid;
        float wsa[7], wsb[7];
        #pragma unroll
        for (int k = 0; k < 7; ++k) {
            wsa[k] = 0.5f*(dww[c0*7 + k]     + dww[c0*7 + 6-k]);
            wsb[k] = 0.5f*(dww[(c0+1)*7 + k] + dww[(c0+1)*7 + 6-k]);
        }
        float ua[22], ub[22];
        #pragma unroll
        for (int r = 0; r < 22; ++r) {
            unsigned int raw = *reinterpret_cast<const unsigned int*>(&s_u[r*UST + c0]);
            ua[r] = bf2f((unsigned short)(raw & 0xffffu));
            ub[r] = bf2f((unsigned short)(raw >> 16));
        }
        #pragma unroll
        for (int cr = 0; cr < 16; ++cr) {
            float s0 = 0.0f, s1 = 0.0f;
            #pragma unroll
            for (int k = 0; k < 7; ++k) {
                s0 = fmaf(wsa[k], ua[cr + k], s0);
                s1 = fmaf(wsb[k], ub[cr + k], s1);
            }
            unsigned int packed = (unsigned)f2bf(s0) | ((unsigned)f2bf(s1) << 16);
            *reinterpret_cast<unsigned int*>(&s_c[cr*UST + c0]) = packed;
        }
    }
    __syncthreads();

    // --- grouped mix (MFMA, K=64) + gate (from HBM) -> v into s_u ---
    for (int cb = 0; cb < 2; ++cb) {
        const int g = wvid + 4*cb;           // 0..7
        u32x4 a0 = *reinterpret_cast<const u32x4*>(&s_c[r_lo*UST + g*64 + kb*8]);
        u32x4 a1 = *reinterpret_cast<const u32x4*>(&s_c[r_lo*UST + g*64 + 32 + kb*8]);
        f32x4 acc[4];
        #pragma unroll
        for (int nt = 0; nt < 4; ++nt) acc[nt] = (f32x4){0.f,0.f,0.f,0.f};
        #pragma unroll
        for (int nt = 0; nt < 4; ++nt) {
            u32x4 b0 = *reinterpret_cast<const u32x4*>(
                mixw_b + (size_t)(g*64 + nt*16 + r_lo)*64 + kb*8);
            asm("v_mfma_f32_16x16x32_bf16 %0, %1, %2, %0"
                : "+v"(acc[nt]) : "v"(a0), "v"(b0));
        }
        #pragma unroll
        for (int nt = 0; nt < 4; ++nt) {
            u32x4 b1 = *reinterpret_cast<const u32x4*>(
                mixw_b + (size_t)(g*64 + nt*16 + r_lo)*64 + 32 + kb*8);
            asm("v_mfma_f32_16x16x32_bf16 %0, %1, %2, %0"
                : "+v"(acc[nt]) : "v"(a1), "v"(b1));
        }
        #pragma unroll
        for (int nt = 0; nt < 4; ++nt) {
            const int ocol = g*64 + nt*16 + r_lo;
            const float bia = mixb[ocol];
            #pragma unroll
            for (int r = 0; r < 4; ++r) {
                const int cr = kb*4 + r;
                const int t = t0 + cr;
                if (t < NT) {
                    float gate = bf2f(g_ws[((size_t)b*NT + t)*NH + ocol]);
                    s_u[cr*UST + ocol] = f2bf((acc[nt][r] + bia) * gate);
                } else {
                    s_u[cr*UST + ocol] = 0;
                }
            }
        }
    }
    __syncthreads();

    // --- out-proj (MFMA, K=512) + bias + residual (in place) ---
    f32x4 acc4[4];
    #pragma unroll
    for (int c4 = 0; c4 < 4; ++c4) acc4[c4] = (f32x4){0.f,0.f,0.f,0.f};
    #pragma unroll
    for (int ks = 0; ks < 16; ++ks) {
        u32x4 a = *reinterpret_cast<const u32x4*>(&s_u[r_lo*UST + ks*32 + kb*8]);
        #pragma unroll
        for (int c4 = 0; c4 < 4; ++c4) {
            const int ocol = wvid*64 + c4*16 + r_lo;
            u32x4 bf = *reinterpret_cast<const u32x4*>(
                outw_b + (size_t)ocol*NH + ks*32 + kb*8);
            asm("v_mfma_f32_16x16x32_bf16 %0, %1, %2, %0"
                : "+v"(acc4[c4]) : "v"(a), "v"(bf));
        }
    }
    #pragma unroll
    for (int c4 = 0; c4 < 4; ++c4) {
        const int d = wvid*64 + c4*16 + r_lo;
        const float ob = outb[d];
        #pragma unroll
        for (int r = 0; r < 4; ++r) {
            const int cr = kb*4 + r;
            const int t = t0 + cr;
            if (t < NT) {
                size_t off = ((size_t)b*NT + t)*ND + d;
                h[off] += acc4[c4][r] + ob;
            }
        }
    }
}

// ---------------- final layernorm (in place) ----------------
__global__ __launch_bounds__(256) void kLN(float* __restrict__ h,
    const float* __restrict__ g, const float* __restrict__ bb)
{
    const int row = blockIdx.x;
    const int tid = threadIdx.x;
    const int lane = tid & 63, wvi = tid >> 6;
    __shared__ float2 part[4];
    float v = h[(size_t)row*ND + tid];
    float s = v, s2 = v*v;
    #pragma unroll
    for (int off = 32; off; off >>= 1) { s += __shfl_down(s, off); s2 += __shfl_down(s2, off); }
    if (lane == 0) part[wvi] = make_float2(s, s2);
    __syncthreads();
    float2 a0 = part[0], a1 = part[1], a2 = part[2], a3 = part[3];
    float S  = a0.x+a1.x+a2.x+a3.x;
    float S2 = a0.y+a1.y+a2.y+a3.y;
    float mu  = S*(1.0f/ND);
    float var = S2*(1.0f/ND) - mu*mu;
    float rs  = rsqrtf(var + EPSF);
    h[(size_t)row*ND + tid] = (v - mu)*rs*g[tid] + bb[tid];
}

extern "C" void kernel_launch(void* const* d_in, const int* in_sizes, int n_in,
                              void* d_out, int out_size, void* d_ws, size_t ws_size,
                              hipStream_t stream)
{
    const float* x    = (const float*)d_in[0];
    const float* w_in = (const float*)d_in[1];
    const float* b_in = (const float*)d_in[2];
    const float* pos  = (const float*)d_in[3];
    const float* ln_g = (const float*)d_in[4];
    const float* ln_b = (const float*)d_in[5];
    const float* inw  = (const float*)d_in[6];
    const float* inb  = (const float*)d_in[7];
    const float* dww  = (const float*)d_in[8];
    const float* mixw = (const float*)d_in[9];
    const float* mixb = (const float*)d_in[10];
    const float* outw = (const float*)d_in[11];
    const float* outb = (const float*)d_in[12];
    const float* olng = (const float*)d_in[13];
    const float* olnb = (const float*)d_in[14];
    float* h = (float*)d_out;

    const size_t UB = (size_t)NPOS * NH;          // 71,827,456 elems
    unsigned short* u_ws   = (unsigned short*)d_ws;
    unsigned short* g_ws   = u_ws + UB;
    unsigned short* outw_b = g_ws + UB;           // L*D*H = 524288 bf16
    unsigned short* mixw_b = outw_b + 524288;     // L*H*64 = 131072 bf16
    unsigned short* inw_b  = mixw_b + 131072;     // L*1024*32 = 131072 bf16

    k_init<<<NPOS, 256, 0, stream>>>(x, w_in, b_in, pos, h);
    k_prep<<<3072, 256, 0, stream>>>(outw, mixw, inw, outw_b, mixw_b, inw_b);
    for (int l = 0; l < 4; ++l) {
        kA2<<<dim3(9, NB), 256, 0, stream>>>(h, ln_g + l*ND, ln_b + l*ND,
            inw_b + (size_t)l*NHH*32, inb + l*NHH, u_ws, g_ws);
        kBC<<<dim3(18, NB), 256, 0, stream>>>(u_ws, g_ws, dww + l*NH*7,
            mixw_b + (size_t)l*NH*64, mixb + l*NH,
            outw_b + (size_t)l*ND*NH, outb + l*ND, h);
    }
    kLN<<<NPOS, 256, 0, stream>>>(h, olng, olnb);
}

// Round 7
// 2370.864 us; speedup vs baseline: 1.2263x; 1.2263x over previous
//
#include <hip/hip_runtime.h>

#define NB 512
#define NT 274
#define ND 256
#define NH 512
#define NHH 1024
#define NPOS (NB*NT)
#define EPSF 1e-5f
#define UST 520    // LDS row stride for u/uc/v (1040B, 16B-mult, ==4 dw mod 32)

typedef float f32x4 __attribute__((ext_vector_type(4)));
typedef unsigned int u32x4 __attribute__((ext_vector_type(4)));
typedef unsigned int u32x2 __attribute__((ext_vector_type(2)));

__device__ __forceinline__ float bf2f(unsigned short s) {
    unsigned int u = ((unsigned int)s) << 16;
    float f; __builtin_memcpy(&f, &u, 4); return f;
}
__device__ __forceinline__ unsigned short f2bf(float f) {
    unsigned int u; __builtin_memcpy(&u, &f, 4);
    unsigned int r = u + 0x7FFFu + ((u >> 16) & 1u);   // round-to-nearest-even
    return (unsigned short)(r >> 16);
}

// ---------------- init: h = x[:,:,None]*w_in + b_in + pos ----------------
__global__ __launch_bounds__(256) void k_init(const float* __restrict__ x,
    const float* __restrict__ w_in, const float* __restrict__ b_in,
    const float* __restrict__ pos, float* __restrict__ h)
{
    int row = blockIdx.x;              // 0..NPOS-1  (b*NT + t)
    int d = threadIdx.x;
    int t = row % NT;
    float xv = x[row];
    h[(size_t)row*ND + d] = fmaf(xv, w_in[d], b_in[d] + pos[t*ND + d]);
}

// ------- prep: convert weights to bf16 IN MFMA-FRAGMENT ORDER -------
// Fragment layout: B element (col = tile*16 + (lane&15), k = (lane>>4)*8 + j)
// stored at dst[(instr*64 + lane)*8 + j]  -> wave load = contiguous 1KB.
__global__ __launch_bounds__(256) void k_prep(const float* __restrict__ outw,
    const float* __restrict__ mixw, const float* __restrict__ inw,
    unsigned short* __restrict__ ob, unsigned short* __restrict__ mb,
    unsigned short* __restrict__ iwb)
{
    int i = blockIdx.x*256 + threadIdx.x;   // 0 .. 786431
    if (i < 524288) {
        // outw: per layer 256x512, instr = ks*16 + c4t  (ks 0..15, c4t 0..15)
        int l = i >> 17, q = i & 131071;
        int j = q & 7, lane = (q >> 3) & 63, c4t = (q >> 9) & 15, ks = q >> 13;
        int src = (c4t*16 + (lane & 15))*512 + ks*32 + (lane >> 4)*8 + j;
        ob[i] = f2bf(outw[(size_t)l*131072 + src]);
    } else if (i < 655360) {
        // mixw: per layer 512x64, instr = (g*4+nt)*2 + half
        int v = i - 524288;
        int l = v >> 15, q = v & 32767;
        int j = q & 7, lane = (q >> 3) & 63, half = (q >> 9) & 1, gnt = q >> 10;
        int g = gnt >> 2, nt = gnt & 3;
        int src = (g*64 + nt*16 + (lane & 15))*64 + half*32 + (lane >> 4)*8 + j;
        mb[v] = f2bf(mixw[(size_t)l*32768 + src]);
    } else {
        // inw: per layer 1024x32, instr = g*8 + nt
        int v = i - 655360;
        int l = v >> 15, q = v & 32767;
        int j = q & 7, lane = (q >> 3) & 63, gnt = q >> 9;
        int g = gnt >> 3, nt = gnt & 7;
        int src = (g*128 + nt*16 + (lane & 15))*32 + (lane >> 4)*8 + j;
        iwb[v] = f2bf(inw[(size_t)l*32768 + src]);
    }
}

// ------- kA2: LN + grouped in-proj (MFMA 16x16x32, K=32) + silu/sigmoid -------
__global__ __launch_bounds__(256) void kA2(const float* __restrict__ h,
    const float* __restrict__ lng, const float* __restrict__ lnb,
    const unsigned short* __restrict__ inw_b, const float* __restrict__ inb,
    unsigned short* __restrict__ u_ws, unsigned short* __restrict__ g_ws)
{
    const int b  = blockIdx.y;
    const int t0 = blockIdx.x * 32;
    const int tid = threadIdx.x;
    const int lane = tid & 63, wvid = tid >> 6;
    __shared__ __align__(16) unsigned short yl[32][264];  // y bf16, row stride 528B
    __shared__ float s_lng[ND], s_lnb[ND];
    __shared__ float s_inb[NHH];

    s_lng[tid] = lng[tid];
    s_lnb[tid] = lnb[tid];
    #pragma unroll
    for (int q = 0; q < 4; ++q) s_inb[tid + 256*q] = inb[tid + 256*q];

    {
        const int r  = tid >> 3;
        const int c0 = (tid & 7) * 32;
        const int trow = t0 + r;
        float vals[32];
        if (trow < NT) {
            const float4* hp = reinterpret_cast<const float4*>(
                h + ((size_t)b*NT + trow)*ND + c0);
            #pragma unroll
            for (int j = 0; j < 8; ++j) {
                float4 f = hp[j];
                vals[4*j+0]=f.x; vals[4*j+1]=f.y; vals[4*j+2]=f.z; vals[4*j+3]=f.w;
            }
        } else {
            #pragma unroll
            for (int j = 0; j < 32; ++j) vals[j] = 0.0f;
        }
        float s = 0.f, s2 = 0.f;
        #pragma unroll
        for (int j = 0; j < 32; ++j) { s += vals[j]; s2 += vals[j]*vals[j]; }
        #pragma unroll
        for (int off = 1; off < 8; off <<= 1) {
            s  += __shfl_xor(s, off);
            s2 += __shfl_xor(s2, off);
        }
        float mu  = s * (1.0f/ND);
        float var = s2 * (1.0f/ND) - mu*mu;
        float rs  = rsqrtf(var + EPSF);
        __syncthreads();   // s_lng/s_lnb ready
        #pragma unroll
        for (int j = 0; j < 16; ++j) {
            int c = c0 + 2*j;
            float y0 = (vals[2*j]   - mu) * rs * s_lng[c]   + s_lnb[c];
            float y1 = (vals[2*j+1] - mu) * rs * s_lng[c+1] + s_lnb[c+1];
            unsigned int packed = (unsigned)f2bf(y0) | ((unsigned)f2bf(y1) << 16);
            *reinterpret_cast<unsigned int*>(&yl[r][c]) = packed;
        }
    }
    __syncthreads();

    const int r_lo = lane & 15, kb = lane >> 4;
    for (int cb = 0; cb < 4; ++cb) {
        const int combo = wvid*4 + cb;        // 16 combos = 2 row-tiles x 8 groups
        const int rt = combo >> 3, g = combo & 7;
        const int arow = rt*16 + r_lo;
        u32x4 a = *reinterpret_cast<const u32x4*>(&yl[arow][g*32 + kb*8]);
        f32x4 acc[8];
        #pragma unroll
        for (int nt = 0; nt < 8; ++nt) acc[nt] = (f32x4){0.f,0.f,0.f,0.f};
        #pragma unroll
        for (int nt = 0; nt < 8; ++nt) {
            u32x4 bf = *reinterpret_cast<const u32x4*>(
                inw_b + (size_t)((g*8 + nt)*64 + lane)*8);
            asm("v_mfma_f32_16x16x32_bf16 %0, %1, %2, %0"
                : "+v"(acc[nt]) : "v"(a), "v"(bf));
        }
        const int crow0 = rt*16 + kb*4;
        #pragma unroll
        for (int nt = 0; nt < 8; ++nt) {
            const int ocol = g*128 + nt*16 + r_lo;
            const float bia = s_inb[ocol];
            #pragma unroll
            for (int r = 0; r < 4; ++r) {
                int trow = t0 + crow0 + r;
                if (trow < NT) {
                    float tv = acc[nt][r] + bia;
                    float sg = 1.0f / (1.0f + __expf(-tv));
                    size_t base = ((size_t)b*NT + trow)*NH;
                    if (ocol < NH) u_ws[base + ocol]      = f2bf(tv * sg);
                    else           g_ws[base + ocol - NH] = f2bf(sg);
                }
            }
        }
    }
}

// ======= kBC: conv + grouped mix + gate + out-proj + residual (fused) =======
__global__ __launch_bounds__(256) void kBC(const unsigned short* __restrict__ u_ws,
    const unsigned short* __restrict__ g_ws, const float* __restrict__ dww,
    const unsigned short* __restrict__ mixw_b, const float* __restrict__ mixb,
    const unsigned short* __restrict__ outw_b, const float* __restrict__ outb,
    float* __restrict__ h)
{
    const int b   = blockIdx.y;
    const int t0  = blockIdx.x * 16;
    const int tid = threadIdx.x;
    const int lane = tid & 63, wvid = tid >> 6;
    const int r_lo = lane & 15, kb = lane >> 4;
    __shared__ __align__(16) unsigned short s_u[22*UST];  // u halo -> later v (16 rows)
    __shared__ __align__(16) unsigned short s_c[16*UST];  // conv output uc

    // --- stage u halo rows t0-3 .. t0+18 (b128, coalesced) ---
    for (int idx = tid; idx < 22*64; idx += 256) {
        int r = idx >> 6, c16 = idx & 63;
        int t = t0 - 3 + r;
        u32x4 val = (u32x4){0u,0u,0u,0u};
        if (t >= 0 && t < NT)
            val = *reinterpret_cast<const u32x4*>(u_ws + ((size_t)b*NT + t)*NH + c16*8);
        *reinterpret_cast<u32x4*>(&s_u[r*UST + c16*8]) = val;
    }

    // --- hoist gate loads (latency hides under conv) ---
    float gv[32];   // [cb*16 + nt*4 + r]
    #pragma unroll
    for (int cb = 0; cb < 2; ++cb) {
        const int g = wvid + 4*cb;
        #pragma unroll
        for (int nt = 0; nt < 4; ++nt) {
            #pragma unroll
            for (int r = 0; r < 4; ++r) {
                const int t = t0 + kb*4 + r;
                gv[cb*16 + nt*4 + r] = (t < NT)
                    ? bf2f(g_ws[((size_t)b*NT + t)*NH + g*64 + nt*16 + r_lo]) : 0.0f;
            }
        }
    }
    __syncthreads();

    // --- symmetric depthwise conv: thread owns channels 2*tid, 2*tid+1 ---
    {
        const int c0 = 2*tid;
        float wsa[7], wsb[7];
        #pragma unroll
        for (int k = 0; k < 7; ++k) {
            wsa[k] = 0.5f*(dww[c0*7 + k]     + dww[c0*7 + 6-k]);
            wsb[k] = 0.5f*(dww[(c0+1)*7 + k] + dww[(c0+1)*7 + 6-k]);
        }
        float ua[22], ub[22];
        #pragma unroll
        for (int r = 0; r < 22; ++r) {
            unsigned int raw = *reinterpret_cast<const unsigned int*>(&s_u[r*UST + c0]);
            ua[r] = bf2f((unsigned short)(raw & 0xffffu));
            ub[r] = bf2f((unsigned short)(raw >> 16));
        }
        #pragma unroll
        for (int cr = 0; cr < 16; ++cr) {
            float s0 = 0.0f, s1 = 0.0f;
            #pragma unroll
            for (int k = 0; k < 7; ++k) {
                s0 = fmaf(wsa[k], ua[cr + k], s0);
                s1 = fmaf(wsb[k], ub[cr + k], s1);
            }
            unsigned int packed = (unsigned)f2bf(s0) | ((unsigned)f2bf(s1) << 16);
            *reinterpret_cast<unsigned int*>(&s_c[cr*UST + c0]) = packed;
        }
    }
    __syncthreads();

    // --- grouped mix (MFMA, K=64) + gate -> v into s_u ---
    for (int cb = 0; cb < 2; ++cb) {
        const int g = wvid + 4*cb;           // 0..7
        u32x4 a0 = *reinterpret_cast<const u32x4*>(&s_c[r_lo*UST + g*64 + kb*8]);
        u32x4 a1 = *reinterpret_cast<const u32x4*>(&s_c[r_lo*UST + g*64 + 32 + kb*8]);
        f32x4 acc[4];
        #pragma unroll
        for (int nt = 0; nt < 4; ++nt) acc[nt] = (f32x4){0.f,0.f,0.f,0.f};
        #pragma unroll
        for (int nt = 0; nt < 4; ++nt) {
            u32x4 b0 = *reinterpret_cast<const u32x4*>(
                mixw_b + (size_t)(((g*4 + nt)*2 + 0)*64 + lane)*8);
            asm("v_mfma_f32_16x16x32_bf16 %0, %1, %2, %0"
                : "+v"(acc[nt]) : "v"(a0), "v"(b0));
        }
        #pragma unroll
        for (int nt = 0; nt < 4; ++nt) {
            u32x4 b1 = *reinterpret_cast<const u32x4*>(
                mixw_b + (size_t)(((g*4 + nt)*2 + 1)*64 + lane)*8);
            asm("v_mfma_f32_16x16x32_bf16 %0, %1, %2, %0"
                : "+v"(acc[nt]) : "v"(a1), "v"(b1));
        }
        #pragma unroll
        for (int nt = 0; nt < 4; ++nt) {
            const int ocol = g*64 + nt*16 + r_lo;
            const float bia = mixb[ocol];
            #pragma unroll
            for (int r = 0; r < 4; ++r) {
                const int cr = kb*4 + r;
                const int t = t0 + cr;
                if (t < NT) {
                    s_u[cr*UST + ocol] = f2bf((acc[nt][r] + bia) * gv[cb*16 + nt*4 + r]);
                } else {
                    s_u[cr*UST + ocol] = 0;
                }
            }
        }
    }
    __syncthreads();

    // --- out-proj (MFMA, K=512) + bias + residual (in place) ---
    f32x4 acc4[4];
    #pragma unroll
    for (int c4 = 0; c4 < 4; ++c4) acc4[c4] = (f32x4){0.f,0.f,0.f,0.f};
    #pragma unroll
    for (int ks = 0; ks < 16; ++ks) {
        u32x4 a = *reinterpret_cast<const u32x4*>(&s_u[r_lo*UST + ks*32 + kb*8]);
        #pragma unroll
        for (int c4 = 0; c4 < 4; ++c4) {
            u32x4 bf = *reinterpret_cast<const u32x4*>(
                outw_b + (size_t)((ks*16 + wvid*4 + c4)*64 + lane)*8);
            asm("v_mfma_f32_16x16x32_bf16 %0, %1, %2, %0"
                : "+v"(acc4[c4]) : "v"(a), "v"(bf));
        }
    }
    #pragma unroll
    for (int c4 = 0; c4 < 4; ++c4) {
        const int d = wvid*64 + c4*16 + r_lo;
        const float ob = outb[d];
        #pragma unroll
        for (int r = 0; r < 4; ++r) {
            const int cr = kb*4 + r;
            const int t = t0 + cr;
            if (t < NT) {
                size_t off = ((size_t)b*NT + t)*ND + d;
                h[off] += acc4[c4][r] + ob;
            }
        }
    }
}

// ---------------- final layernorm (in place) ----------------
__global__ __launch_bounds__(256) void kLN(float* __restrict__ h,
    const float* __restrict__ g, const float* __restrict__ bb)
{
    const int row = blockIdx.x;
    const int tid = threadIdx.x;
    const int lane = tid & 63, wvi = tid >> 6;
    __shared__ float2 part[4];
    float v = h[(size_t)row*ND + tid];
    float s = v, s2 = v*v;
    #pragma unroll
    for (int off = 32; off; off >>= 1) { s += __shfl_down(s, off); s2 += __shfl_down(s2, off); }
    if (lane == 0) part[wvi] = make_float2(s, s2);
    __syncthreads();
    float2 a0 = part[0], a1 = part[1], a2 = part[2], a3 = part[3];
    float S  = a0.x+a1.x+a2.x+a3.x;
    float S2 = a0.y+a1.y+a2.y+a3.y;
    float mu  = S*(1.0f/ND);
    float var = S2*(1.0f/ND) - mu*mu;
    float rs  = rsqrtf(var + EPSF);
    h[(size_t)row*ND + tid] = (v - mu)*rs*g[tid] + bb[tid];
}

extern "C" void kernel_launch(void* const* d_in, const int* in_sizes, int n_in,
                              void* d_out, int out_size, void* d_ws, size_t ws_size,
                              hipStream_t stream)
{
    const float* x    = (const float*)d_in[0];
    const float* w_in = (const float*)d_in[1];
    const float* b_in = (const float*)d_in[2];
    const float* pos  = (const float*)d_in[3];
    const float* ln_g = (const float*)d_in[4];
    const float* ln_b = (const float*)d_in[5];
    const float* inw  = (const float*)d_in[6];
    const float* inb  = (const float*)d_in[7];
    const float* dww  = (const float*)d_in[8];
    const float* mixw = (const float*)d_in[9];
    const float* mixb = (const float*)d_in[10];
    const float* outw = (const float*)d_in[11];
    const float* outb = (const float*)d_in[12];
    const float* olng = (const float*)d_in[13];
    const float* olnb = (const float*)d_in[14];
    float* h = (float*)d_out;

    const size_t UB = (size_t)NPOS * NH;          // 71,827,456 elems
    unsigned short* u_ws   = (unsigned short*)d_ws;
    unsigned short* g_ws   = u_ws + UB;
    unsigned short* outw_b = g_ws + UB;           // L*D*H = 524288 bf16 (frag order)
    unsigned short* mixw_b = outw_b + 524288;     // L*H*64 = 131072 bf16 (frag order)
    unsigned short* inw_b  = mixw_b + 131072;     // L*1024*32 = 131072 bf16 (frag order)

    k_init<<<NPOS, 256, 0, stream>>>(x, w_in, b_in, pos, h);
    k_prep<<<3072, 256, 0, stream>>>(outw, mixw, inw, outw_b, mixw_b, inw_b);
    for (int l = 0; l < 4; ++l) {
        kA2<<<dim3(9, NB), 256, 0, stream>>>(h, ln_g + l*ND, ln_b + l*ND,
            inw_b + (size_t)l*32768, inb + l*NHH, u_ws, g_ws);
        kBC<<<dim3(18, NB), 256, 0, stream>>>(u_ws, g_ws, dww + l*NH*7,
            mixw_b + (size_t)l*32768, mixb + l*NH,
            outw_b + (size_t)l*131072, outb + l*ND, h);
    }
    kLN<<<NPOS, 256, 0, stream>>>(h, olng, olnb);
}

// Round 8
// 1918.120 us; speedup vs baseline: 1.5157x; 1.2360x over previous
//
#include <hip/hip_runtime.h>

#define NB 512
#define NT 274
#define ND 256
#define NH 512
#define NHH 1024
#define NPOS (NB*NT)
#define EPSF 1e-5f
#define UST 520    // LDS row stride for u/uc/v (1040B, 16B-mult, ==4 dw mod 32)

typedef float f32x4 __attribute__((ext_vector_type(4)));
typedef unsigned int u32x4 __attribute__((ext_vector_type(4)));
typedef unsigned int u32x2 __attribute__((ext_vector_type(2)));

__device__ __forceinline__ float bf2f(unsigned short s) {
    unsigned int u = ((unsigned int)s) << 16;
    float f; __builtin_memcpy(&f, &u, 4); return f;
}
__device__ __forceinline__ unsigned short f2bf(float f) {
    unsigned int u; __builtin_memcpy(&u, &f, 4);
    unsigned int r = u + 0x7FFFu + ((u >> 16) & 1u);   // round-to-nearest-even
    return (unsigned short)(r >> 16);
}

// ---------------- init: h = x[:,:,None]*w_in + b_in + pos ----------------
__global__ __launch_bounds__(256) void k_init(const float* __restrict__ x,
    const float* __restrict__ w_in, const float* __restrict__ b_in,
    const float* __restrict__ pos, float* __restrict__ h)
{
    int row = blockIdx.x;              // 0..NPOS-1  (b*NT + t)
    int d = threadIdx.x;
    int t = row % NT;
    float xv = x[row];
    h[(size_t)row*ND + d] = fmaf(xv, w_in[d], b_in[d] + pos[t*ND + d]);
}

// ------- prep: convert weights to bf16 IN MFMA-FRAGMENT ORDER -------
// Fragment layout: B element (col = tile*16 + (lane&15), k = (lane>>4)*8 + j)
// stored at dst[(instr*64 + lane)*8 + j]  -> wave load = contiguous 1KB.
__global__ __launch_bounds__(256) void k_prep(const float* __restrict__ outw,
    const float* __restrict__ mixw, const float* __restrict__ inw,
    unsigned short* __restrict__ ob, unsigned short* __restrict__ mb,
    unsigned short* __restrict__ iwb)
{
    int i = blockIdx.x*256 + threadIdx.x;   // 0 .. 786431
    if (i < 524288) {
        // outw: per layer 256x512, instr = ks*16 + c4t  (ks 0..15, c4t 0..15)
        int l = i >> 17, q = i & 131071;
        int j = q & 7, lane = (q >> 3) & 63, c4t = (q >> 9) & 15, ks = q >> 13;
        int src = (c4t*16 + (lane & 15))*512 + ks*32 + (lane >> 4)*8 + j;
        ob[i] = f2bf(outw[(size_t)l*131072 + src]);
    } else if (i < 655360) {
        // mixw: per layer 512x64, instr = (g*4+nt)*2 + half
        int v = i - 524288;
        int l = v >> 15, q = v & 32767;
        int j = q & 7, lane = (q >> 3) & 63, half = (q >> 9) & 1, gnt = q >> 10;
        int g = gnt >> 2, nt = gnt & 3;
        int src = (g*64 + nt*16 + (lane & 15))*64 + half*32 + (lane >> 4)*8 + j;
        mb[v] = f2bf(mixw[(size_t)l*32768 + src]);
    } else {
        // inw: per layer 1024x32, instr = g*8 + nt
        int v = i - 655360;
        int l = v >> 15, q = v & 32767;
        int j = q & 7, lane = (q >> 3) & 63, gnt = q >> 9;
        int g = gnt >> 3, nt = gnt & 7;
        int src = (g*128 + nt*16 + (lane & 15))*32 + (lane >> 4)*8 + j;
        iwb[v] = f2bf(inw[(size_t)l*32768 + src]);
    }
}

// ------- kA2: LN + grouped in-proj (MFMA 16x16x32, K=32) + silu/sigmoid -------
__global__ __launch_bounds__(256) void kA2(const float* __restrict__ h,
    const float* __restrict__ lng, const float* __restrict__ lnb,
    const unsigned short* __restrict__ inw_b, const float* __restrict__ inb,
    unsigned short* __restrict__ u_ws, unsigned short* __restrict__ g_ws)
{
    const int b  = blockIdx.y;
    const int t0 = blockIdx.x * 32;
    const int tid = threadIdx.x;
    const int lane = tid & 63, wvid = tid >> 6;
    __shared__ __align__(16) unsigned short yl[32][264];  // y bf16, row stride 528B
    __shared__ float s_lng[ND], s_lnb[ND];
    __shared__ float s_inb[NHH];

    s_lng[tid] = lng[tid];
    s_lnb[tid] = lnb[tid];
    #pragma unroll
    for (int q = 0; q < 4; ++q) s_inb[tid + 256*q] = inb[tid + 256*q];

    {
        const int r  = tid >> 3;
        const int c0 = (tid & 7) * 32;
        const int trow = t0 + r;
        float vals[32];
        if (trow < NT) {
            const float4* hp = reinterpret_cast<const float4*>(
                h + ((size_t)b*NT + trow)*ND + c0);
            #pragma unroll
            for (int j = 0; j < 8; ++j) {
                float4 f = hp[j];
                vals[4*j+0]=f.x; vals[4*j+1]=f.y; vals[4*j+2]=f.z; vals[4*j+3]=f.w;
            }
        } else {
            #pragma unroll
            for (int j = 0; j < 32; ++j) vals[j] = 0.0f;
        }
        float s = 0.f, s2 = 0.f;
        #pragma unroll
        for (int j = 0; j < 32; ++j) { s += vals[j]; s2 += vals[j]*vals[j]; }
        #pragma unroll
        for (int off = 1; off < 8; off <<= 1) {
            s  += __shfl_xor(s, off);
            s2 += __shfl_xor(s2, off);
        }
        float mu  = s * (1.0f/ND);
        float var = s2 * (1.0f/ND) - mu*mu;
        float rs  = rsqrtf(var + EPSF);
        __syncthreads();   // s_lng/s_lnb ready
        #pragma unroll
        for (int j = 0; j < 16; ++j) {
            int c = c0 + 2*j;
            float y0 = (vals[2*j]   - mu) * rs * s_lng[c]   + s_lnb[c];
            float y1 = (vals[2*j+1] - mu) * rs * s_lng[c+1] + s_lnb[c+1];
            unsigned int packed = (unsigned)f2bf(y0) | ((unsigned)f2bf(y1) << 16);
            *reinterpret_cast<unsigned int*>(&yl[r][c]) = packed;
        }
    }
    __syncthreads();

    const int r_lo = lane & 15, kb = lane >> 4;
    for (int cb = 0; cb < 4; ++cb) {
        const int combo = wvid*4 + cb;        // 16 combos = 2 row-tiles x 8 groups
        const int rt = combo >> 3, g = combo & 7;
        const int arow = rt*16 + r_lo;
        u32x4 a = *reinterpret_cast<const u32x4*>(&yl[arow][g*32 + kb*8]);
        f32x4 acc[8];
        #pragma unroll
        for (int nt = 0; nt < 8; ++nt) acc[nt] = (f32x4){0.f,0.f,0.f,0.f};
        #pragma unroll
        for (int nt = 0; nt < 8; ++nt) {
            u32x4 bf = *reinterpret_cast<const u32x4*>(
                inw_b + (size_t)((g*8 + nt)*64 + lane)*8);
            asm("v_mfma_f32_16x16x32_bf16 %0, %1, %2, %0"
                : "+v"(acc[nt]) : "v"(a), "v"(bf));
        }
        const int crow0 = rt*16 + kb*4;
        #pragma unroll
        for (int nt = 0; nt < 8; ++nt) {
            const int ocol = g*128 + nt*16 + r_lo;
            const float bia = s_inb[ocol];
            #pragma unroll
            for (int r = 0; r < 4; ++r) {
                int trow = t0 + crow0 + r;
                if (trow < NT) {
                    float tv = acc[nt][r] + bia;
                    float sg = 1.0f / (1.0f + __expf(-tv));
                    size_t base = ((size_t)b*NT + trow)*NH;
                    if (ocol < NH) u_ws[base + ocol]      = f2bf(tv * sg);
                    else           g_ws[base + ocol - NH] = f2bf(sg);
                }
            }
        }
    }
}

// ======= kBC: conv + grouped mix + gate + out-proj + residual (fused) =======
// 512 threads / 8 waves; 4 blocks/CU -> 32 waves/CU.
__global__ __launch_bounds__(512, 8) void kBC(const unsigned short* __restrict__ u_ws,
    const unsigned short* __restrict__ g_ws, const float* __restrict__ dww,
    const unsigned short* __restrict__ mixw_b, const float* __restrict__ mixb,
    const unsigned short* __restrict__ outw_b, const float* __restrict__ outb,
    float* __restrict__ h)
{
    const int b   = blockIdx.y;
    const int t0  = blockIdx.x * 16;
    const int tid = threadIdx.x;            // 0..511
    const int lane = tid & 63, wvid = tid >> 6;   // 8 waves
    const int r_lo = lane & 15, kb = lane >> 4;
    __shared__ __align__(16) unsigned short s_u[22*UST];  // u halo -> later v (16 rows)
    __shared__ __align__(16) unsigned short s_c[16*UST];  // conv output uc

    // --- stage u halo rows t0-3 .. t0+18 (b128, coalesced) ---
    for (int idx = tid; idx < 22*64; idx += 512) {
        int r = idx >> 6, c16 = idx & 63;
        int t = t0 - 3 + r;
        u32x4 val = (u32x4){0u,0u,0u,0u};
        if (t >= 0 && t < NT)
            val = *reinterpret_cast<const u32x4*>(u_ws + ((size_t)b*NT + t)*NH + c16*8);
        *reinterpret_cast<u32x4*>(&s_u[r*UST + c16*8]) = val;
    }
    __syncthreads();

    // --- symmetric depthwise conv: thread owns channel tid ---
    {
        const int c = tid;
        float ws[7];
        #pragma unroll
        for (int k = 0; k < 7; ++k)
            ws[k] = 0.5f*(dww[c*7 + k] + dww[c*7 + 6-k]);
        float uv[22];
        #pragma unroll
        for (int r = 0; r < 22; ++r)
            uv[r] = bf2f(s_u[r*UST + c]);
        #pragma unroll
        for (int cr = 0; cr < 16; ++cr) {
            float s = 0.0f;
            #pragma unroll
            for (int k = 0; k < 7; ++k) s = fmaf(ws[k], uv[cr + k], s);
            s_c[cr*UST + c] = f2bf(s);
        }
    }
    __syncthreads();

    // --- grouped mix (MFMA, K=64): wave owns group g = wvid ---
    {
        const int g = wvid;
        u32x4 a0 = *reinterpret_cast<const u32x4*>(&s_c[r_lo*UST + g*64 + kb*8]);
        u32x4 a1 = *reinterpret_cast<const u32x4*>(&s_c[r_lo*UST + g*64 + 32 + kb*8]);
        f32x4 acc[4];
        #pragma unroll
        for (int nt = 0; nt < 4; ++nt) acc[nt] = (f32x4){0.f,0.f,0.f,0.f};
        #pragma unroll
        for (int nt = 0; nt < 4; ++nt) {
            u32x4 b0 = *reinterpret_cast<const u32x4*>(
                mixw_b + (size_t)(((g*4 + nt)*2 + 0)*64 + lane)*8);
            asm("v_mfma_f32_16x16x32_bf16 %0, %1, %2, %0"
                : "+v"(acc[nt]) : "v"(a0), "v"(b0));
        }
        #pragma unroll
        for (int nt = 0; nt < 4; ++nt) {
            u32x4 b1 = *reinterpret_cast<const u32x4*>(
                mixw_b + (size_t)(((g*4 + nt)*2 + 1)*64 + lane)*8);
            asm("v_mfma_f32_16x16x32_bf16 %0, %1, %2, %0"
                : "+v"(acc[nt]) : "v"(a1), "v"(b1));
        }
        __syncthreads();   // s_c reads done block-wide; safe to overwrite s_u
        #pragma unroll
        for (int nt = 0; nt < 4; ++nt) {
            const int ocol = g*64 + nt*16 + r_lo;
            const float bia = mixb[ocol];
            #pragma unroll
            for (int r = 0; r < 4; ++r) {
                const int cr = kb*4 + r;
                const int t = t0 + cr;
                if (t < NT) {
                    float gate = bf2f(g_ws[((size_t)b*NT + t)*NH + ocol]);
                    s_u[cr*UST + ocol] = f2bf((acc[nt][r] + bia) * gate);
                } else {
                    s_u[cr*UST + ocol] = 0;
                }
            }
        }
    }
    __syncthreads();

    // --- out-proj (MFMA, K=512): wave owns d-cols wvid*32 .. +31 ---
    f32x4 acc4[2];
    #pragma unroll
    for (int c4 = 0; c4 < 2; ++c4) acc4[c4] = (f32x4){0.f,0.f,0.f,0.f};
    #pragma unroll
    for (int ks = 0; ks < 16; ++ks) {
        u32x4 a = *reinterpret_cast<const u32x4*>(&s_u[r_lo*UST + ks*32 + kb*8]);
        #pragma unroll
        for (int c4 = 0; c4 < 2; ++c4) {
            const int c4t = wvid*2 + c4;
            u32x4 bf = *reinterpret_cast<const u32x4*>(
                outw_b + (size_t)((ks*16 + c4t)*64 + lane)*8);
            asm("v_mfma_f32_16x16x32_bf16 %0, %1, %2, %0"
                : "+v"(acc4[c4]) : "v"(a), "v"(bf));
        }
    }
    #pragma unroll
    for (int c4 = 0; c4 < 2; ++c4) {
        const int d = wvid*32 + c4*16 + r_lo;
        const float ob = outb[d];
        #pragma unroll
        for (int r = 0; r < 4; ++r) {
            const int cr = kb*4 + r;
            const int t = t0 + cr;
            if (t < NT) {
                size_t off = ((size_t)b*NT + t)*ND + d;
                h[off] += acc4[c4][r] + ob;
            }
        }
    }
}

// ---------------- final layernorm (in place) ----------------
__global__ __launch_bounds__(256) void kLN(float* __restrict__ h,
    const float* __restrict__ g, const float* __restrict__ bb)
{
    const int row = blockIdx.x;
    const int tid = threadIdx.x;
    const int lane = tid & 63, wvi = tid >> 6;
    __shared__ float2 part[4];
    float v = h[(size_t)row*ND + tid];
    float s = v, s2 = v*v;
    #pragma unroll
    for (int off = 32; off; off >>= 1) { s += __shfl_down(s, off); s2 += __shfl_down(s2, off); }
    if (lane == 0) part[wvi] = make_float2(s, s2);
    __syncthreads();
    float2 a0 = part[0], a1 = part[1], a2 = part[2], a3 = part[3];
    float S  = a0.x+a1.x+a2.x+a3.x;
    float S2 = a0.y+a1.y+a2.y+a3.y;
    float mu  = S*(1.0f/ND);
    float var = S2*(1.0f/ND) - mu*mu;
    float rs  = rsqrtf(var + EPSF);
    h[(size_t)row*ND + tid] = (v - mu)*rs*g[tid] + bb[tid];
}

extern "C" void kernel_launch(void* const* d_in, const int* in_sizes, int n_in,
                              void* d_out, int out_size, void* d_ws, size_t ws_size,
                              hipStream_t stream)
{
    const float* x    = (const float*)d_in[0];
    const float* w_in = (const float*)d_in[1];
    const float* b_in = (const float*)d_in[2];
    const float* pos  = (const float*)d_in[3];
    const float* ln_g = (const float*)d_in[4];
    const float* ln_b = (const float*)d_in[5];
    const float* inw  = (const float*)d_in[6];
    const float* inb  = (const float*)d_in[7];
    const float* dww  = (const float*)d_in[8];
    const float* mixw = (const float*)d_in[9];
    const float* mixb = (const float*)d_in[10];
    const float* outw = (const float*)d_in[11];
    const float* outb = (const float*)d_in[12];
    const float* olng = (const float*)d_in[13];
    const float* olnb = (const float*)d_in[14];
    float* h = (float*)d_out;

    const size_t UB = (size_t)NPOS * NH;          // 71,827,456 elems
    unsigned short* u_ws   = (unsigned short*)d_ws;
    unsigned short* g_ws   = u_ws + UB;
    unsigned short* outw_b = g_ws + UB;           // L*D*H = 524288 bf16 (frag order)
    unsigned short* mixw_b = outw_b + 524288;     // L*H*64 = 131072 bf16 (frag order)
    unsigned short* inw_b  = mixw_b + 131072;     // L*1024*32 = 131072 bf16 (frag order)

    k_init<<<NPOS, 256, 0, stream>>>(x, w_in, b_in, pos, h);
    k_prep<<<3072, 256, 0, stream>>>(outw, mixw, inw, outw_b, mixw_b, inw_b);
    for (int l = 0; l < 4; ++l) {
        kA2<<<dim3(9, NB), 256, 0, stream>>>(h, ln_g + l*ND, ln_b + l*ND,
            inw_b + (size_t)l*32768, inb + l*NHH, u_ws, g_ws);
        kBC<<<dim3(18, NB), 512, 0, stream>>>(u_ws, g_ws, dww + l*NH*7,
            mixw_b + (size_t)l*32768, mixb + l*NH,
            outw_b + (size_t)l*131072, outb + l*ND, h);
    }
    kLN<<<NPOS, 256, 0, stream>>>(h, olng, olnb);
}

// Round 12
// 1740.015 us; speedup vs baseline: 1.6708x; 1.1024x over previous
//
#include <hip/hip_runtime.h>

#define NB 512
#define NT 274
#define ND 256
#define NH 512
#define NHH 1024
#define NPOS (NB*NT)
#define EPSF 1e-5f
#define UST 520    // LDS row stride for u/uc/v (1040B, 16B-mult, ==4 dw mod 32)

typedef float f32x4 __attribute__((ext_vector_type(4)));
typedef unsigned int u32x4 __attribute__((ext_vector_type(4)));
typedef short s16x8 __attribute__((ext_vector_type(8)));   // 8 bf16 = 4 VGPRs

__device__ __forceinline__ float bf2f(unsigned short s) {
    unsigned int u = ((unsigned int)s) << 16;
    float f; __builtin_memcpy(&f, &u, 4); return f;
}
__device__ __forceinline__ unsigned short f2bf(float f) {
    unsigned int u; __builtin_memcpy(&u, &f, 4);
    unsigned int r = u + 0x7FFFu + ((u >> 16) & 1u);   // round-to-nearest-even
    return (unsigned short)(r >> 16);
}

// ---------------- init: h = x[:,:,None]*w_in + b_in + pos ----------------
__global__ __launch_bounds__(256) void k_init(const float* __restrict__ x,
    const float* __restrict__ w_in, const float* __restrict__ b_in,
    const float* __restrict__ pos, float* __restrict__ h)
{
    int row = blockIdx.x;              // 0..NPOS-1  (b*NT + t)
    int d = threadIdx.x;
    int t = row % NT;
    float xv = x[row];
    h[(size_t)row*ND + d] = fmaf(xv, w_in[d], b_in[d] + pos[t*ND + d]);
}

// ------- prep: convert weights to bf16 IN MFMA-FRAGMENT ORDER -------
__global__ __launch_bounds__(256) void k_prep(const float* __restrict__ outw,
    const float* __restrict__ mixw, const float* __restrict__ inw,
    unsigned short* __restrict__ ob, unsigned short* __restrict__ mb,
    unsigned short* __restrict__ iwb)
{
    int i = blockIdx.x*256 + threadIdx.x;   // 0 .. 786431
    if (i < 524288) {
        // outw: per layer 256x512, instr = ks*16 + c4t
        int l = i >> 17, q = i & 131071;
        int j = q & 7, lane = (q >> 3) & 63, c4t = (q >> 9) & 15, ks = q >> 13;
        int src = (c4t*16 + (lane & 15))*512 + ks*32 + (lane >> 4)*8 + j;
        ob[i] = f2bf(outw[(size_t)l*131072 + src]);
    } else if (i < 655360) {
        // mixw: per layer 512x64, instr = (g*4+nt)*2 + half
        int v = i - 524288;
        int l = v >> 15, q = v & 32767;
        int j = q & 7, lane = (q >> 3) & 63, half = (q >> 9) & 1, gnt = q >> 10;
        int g = gnt >> 2, nt = gnt & 3;
        int src = (g*64 + nt*16 + (lane & 15))*64 + half*32 + (lane >> 4)*8 + j;
        mb[v] = f2bf(mixw[(size_t)l*32768 + src]);
    } else {
        // inw: per layer 1024x32, instr = g*8 + nt
        int v = i - 655360;
        int l = v >> 15, q = v & 32767;
        int j = q & 7, lane = (q >> 3) & 63, gnt = q >> 9;
        int g = gnt >> 3, nt = gnt & 7;
        int src = (g*128 + nt*16 + (lane & 15))*32 + (lane >> 4)*8 + j;
        iwb[v] = f2bf(inw[(size_t)l*32768 + src]);
    }
}

// ------- kA2: LN + grouped in-proj (MFMA intrinsic, K=32) + silu/sigmoid -------
__global__ __launch_bounds__(256) void kA2(const float* __restrict__ h,
    const float* __restrict__ lng, const float* __restrict__ lnb,
    const unsigned short* __restrict__ inw_b, const float* __restrict__ inb,
    unsigned short* __restrict__ u_ws, unsigned short* __restrict__ g_ws)
{
    const int b  = blockIdx.y;
    const int t0 = blockIdx.x * 32;
    const int tid = threadIdx.x;
    const int lane = tid & 63, wvid = tid >> 6;
    __shared__ __align__(16) unsigned short yl[32][264];  // y bf16, row stride 528B
    __shared__ float s_lng[ND], s_lnb[ND];
    __shared__ float s_inb[NHH];

    s_lng[tid] = lng[tid];
    s_lnb[tid] = lnb[tid];
    #pragma unroll
    for (int q = 0; q < 4; ++q) s_inb[tid + 256*q] = inb[tid + 256*q];

    {
        const int r  = tid >> 3;
        const int c0 = (tid & 7) * 32;
        const int trow = t0 + r;
        float vals[32];
        if (trow < NT) {
            const float4* hp = reinterpret_cast<const float4*>(
                h + ((size_t)b*NT + trow)*ND + c0);
            #pragma unroll
            for (int j = 0; j < 8; ++j) {
                float4 f = hp[j];
                vals[4*j+0]=f.x; vals[4*j+1]=f.y; vals[4*j+2]=f.z; vals[4*j+3]=f.w;
            }
        } else {
            #pragma unroll
            for (int j = 0; j < 32; ++j) vals[j] = 0.0f;
        }
        float s = 0.f, s2 = 0.f;
        #pragma unroll
        for (int j = 0; j < 32; ++j) { s += vals[j]; s2 += vals[j]*vals[j]; }
        #pragma unroll
        for (int off = 1; off < 8; off <<= 1) {
            s  += __shfl_xor(s, off);
            s2 += __shfl_xor(s2, off);
        }
        float mu  = s * (1.0f/ND);
        float var = s2 * (1.0f/ND) - mu*mu;
        float rs  = rsqrtf(var + EPSF);
        __syncthreads();   // s_lng/s_lnb ready
        #pragma unroll
        for (int j = 0; j < 16; ++j) {
            int c = c0 + 2*j;
            float y0 = (vals[2*j]   - mu) * rs * s_lng[c]   + s_lnb[c];
            float y1 = (vals[2*j+1] - mu) * rs * s_lng[c+1] + s_lnb[c+1];
            unsigned int packed = (unsigned)f2bf(y0) | ((unsigned)f2bf(y1) << 16);
            *reinterpret_cast<unsigned int*>(&yl[r][c]) = packed;
        }
    }
    __syncthreads();

    const int r_lo = lane & 15, kb = lane >> 4;
    for (int cb = 0; cb < 4; ++cb) {
        const int combo = wvid*4 + cb;        // 16 combos = 2 row-tiles x 8 groups
        const int rt = combo >> 3, g = combo & 7;
        const int arow = rt*16 + r_lo;
        s16x8 a = *reinterpret_cast<const s16x8*>(&yl[arow][g*32 + kb*8]);
        f32x4 acc[8];
        #pragma unroll
        for (int nt = 0; nt < 8; ++nt) acc[nt] = (f32x4){0.f,0.f,0.f,0.f};
        #pragma unroll
        for (int nt = 0; nt < 8; ++nt) {
            s16x8 bf = *reinterpret_cast<const s16x8*>(
                inw_b + (size_t)((g*8 + nt)*64 + lane)*8);
            acc[nt] = __builtin_amdgcn_mfma_f32_16x16x32_bf16(a, bf, acc[nt], 0, 0, 0);
        }
        const int crow0 = rt*16 + kb*4;
        #pragma unroll
        for (int nt = 0; nt < 8; ++nt) {
            const int ocol = g*128 + nt*16 + r_lo;
            const float bia = s_inb[ocol];
            #pragma unroll
            for (int r = 0; r < 4; ++r) {
                int trow = t0 + crow0 + r;
                if (trow < NT) {
                    float tv = acc[nt][r] + bia;
                    float sg = 1.0f / (1.0f + __expf(-tv));
                    size_t base = ((size_t)b*NT + trow)*NH;
                    if (ocol < NH) u_ws[base + ocol]      = f2bf(tv * sg);
                    else           g_ws[base + ocol - NH] = f2bf(sg);
                }
            }
        }
    }
}

// ======= kBC: conv + grouped mix + gate + out-proj + residual (fused) =======
// 512 threads / 8 waves; 4 blocks/CU. MFMA via intrinsics (hazard-safe);
// gate loads prefetched at entry (same addresses as round-8 epilogue).
__global__ __launch_bounds__(512, 8) void kBC(const unsigned short* __restrict__ u_ws,
    const unsigned short* __restrict__ g_ws, const float* __restrict__ dww,
    const unsigned short* __restrict__ mixw_b, const float* __restrict__ mixb,
    const unsigned short* __restrict__ outw_b, const float* __restrict__ outb,
    float* __restrict__ h)
{
    const int b   = blockIdx.y;
    const int t0  = blockIdx.x * 16;
    const int tid = threadIdx.x;            // 0..511
    const int lane = tid & 63, wvid = tid >> 6;   // 8 waves
    const int r_lo = lane & 15, kb = lane >> 4;
    __shared__ __align__(16) unsigned short s_u[22*UST];  // u halo -> later v (16 rows)
    __shared__ __align__(16) unsigned short s_c[16*UST];  // conv output uc

    // --- gate prefetch (round-8 addresses, issued early) ---
    float gatev[16];
    #pragma unroll
    for (int nt = 0; nt < 4; ++nt) {
        #pragma unroll
        for (int r = 0; r < 4; ++r) {
            const int t = t0 + kb*4 + r;
            gatev[nt*4 + r] = (t < NT)
                ? bf2f(g_ws[((size_t)b*NT + t)*NH + (wvid*64 + nt*16 + r_lo)])
                : 0.0f;
        }
    }

    // --- stage u halo rows t0-3 .. t0+18 (b128, coalesced) ---
    for (int idx = tid; idx < 22*64; idx += 512) {
        int r = idx >> 6, c16 = idx & 63;
        int t = t0 - 3 + r;
        u32x4 val = (u32x4){0u,0u,0u,0u};
        if (t >= 0 && t < NT)
            val = *reinterpret_cast<const u32x4*>(u_ws + ((size_t)b*NT + t)*NH + c16*8);
        *reinterpret_cast<u32x4*>(&s_u[r*UST + c16*8]) = val;
    }
    __syncthreads();

    // --- symmetric depthwise conv: thread owns channel tid ---
    {
        const int c = tid;
        float ws[7];
        #pragma unroll
        for (int k = 0; k < 7; ++k)
            ws[k] = 0.5f*(dww[c*7 + k] + dww[c*7 + 6-k]);
        float uv[22];
        #pragma unroll
        for (int r = 0; r < 22; ++r)
            uv[r] = bf2f(s_u[r*UST + c]);
        #pragma unroll
        for (int cr = 0; cr < 16; ++cr) {
            float s = 0.0f;
            #pragma unroll
            for (int k = 0; k < 7; ++k) s = fmaf(ws[k], uv[cr + k], s);
            s_c[cr*UST + c] = f2bf(s);
        }
    }
    __syncthreads();

    // --- grouped mix (MFMA, K=64): wave owns group g = wvid; gate from regs ---
    {
        const int g = wvid;
        s16x8 a0 = *reinterpret_cast<const s16x8*>(&s_c[r_lo*UST + g*64 + kb*8]);
        s16x8 a1 = *reinterpret_cast<const s16x8*>(&s_c[r_lo*UST + g*64 + 32 + kb*8]);
        f32x4 acc[4];
        #pragma unroll
        for (int nt = 0; nt < 4; ++nt) acc[nt] = (f32x4){0.f,0.f,0.f,0.f};
        #pragma unroll
        for (int nt = 0; nt < 4; ++nt) {
            s16x8 b0 = *reinterpret_cast<const s16x8*>(
                mixw_b + (size_t)(((g*4 + nt)*2 + 0)*64 + lane)*8);
            acc[nt] = __builtin_amdgcn_mfma_f32_16x16x32_bf16(a0, b0, acc[nt], 0, 0, 0);
        }
        #pragma unroll
        for (int nt = 0; nt < 4; ++nt) {
            s16x8 b1 = *reinterpret_cast<const s16x8*>(
                mixw_b + (size_t)(((g*4 + nt)*2 + 1)*64 + lane)*8);
            acc[nt] = __builtin_amdgcn_mfma_f32_16x16x32_bf16(a1, b1, acc[nt], 0, 0, 0);
        }
        __syncthreads();   // s_c reads done block-wide; safe to overwrite s_u
        #pragma unroll
        for (int nt = 0; nt < 4; ++nt) {
            const int ocol = g*64 + nt*16 + r_lo;
            const float bia = mixb[ocol];
            #pragma unroll
            for (int r = 0; r < 4; ++r) {
                const int cr = kb*4 + r;
                const int t = t0 + cr;
                if (t < NT) {
                    s_u[cr*UST + ocol] = f2bf((acc[nt][r] + bia) * gatev[nt*4 + r]);
                } else {
                    s_u[cr*UST + ocol] = 0;
                }
            }
        }
    }
    __syncthreads();

    // --- out-proj (MFMA, K=512): wave owns d-cols wvid*32 .. +31 ---
    f32x4 acc4[2];
    #pragma unroll
    for (int c4 = 0; c4 < 2; ++c4) acc4[c4] = (f32x4){0.f,0.f,0.f,0.f};
    #pragma unroll
    for (int ks = 0; ks < 16; ++ks) {
        s16x8 a = *reinterpret_cast<const s16x8*>(&s_u[r_lo*UST + ks*32 + kb*8]);
        #pragma unroll
        for (int c4 = 0; c4 < 2; ++c4) {
            const int c4t = wvid*2 + c4;
            s16x8 bf = *reinterpret_cast<const s16x8*>(
                outw_b + (size_t)((ks*16 + c4t)*64 + lane)*8);
            acc4[c4] = __builtin_amdgcn_mfma_f32_16x16x32_bf16(a, bf, acc4[c4], 0, 0, 0);
        }
    }
    #pragma unroll
    for (int c4 = 0; c4 < 2; ++c4) {
        const int d = wvid*32 + c4*16 + r_lo;
        const float ob = outb[d];
        #pragma unroll
        for (int r = 0; r < 4; ++r) {
            const int cr = kb*4 + r;
            const int t = t0 + cr;
            if (t < NT) {
                size_t off = ((size_t)b*NT + t)*ND + d;
                h[off] += acc4[c4][r] + ob;
            }
        }
    }
}

// ---------------- final layernorm (in place) ----------------
__global__ __launch_bounds__(256) void kLN(float* __restrict__ h,
    const float* __restrict__ g, const float* __restrict__ bb)
{
    const int row = blockIdx.x;
    const int tid = threadIdx.x;
    const int lane = tid & 63, wvi = tid >> 6;
    __shared__ float2 part[4];
    float v = h[(size_t)row*ND + tid];
    float s = v, s2 = v*v;
    #pragma unroll
    for (int off = 32; off; off >>= 1) { s += __shfl_down(s, off); s2 += __shfl_down(s2, off); }
    if (lane == 0) part[wvi] = make_float2(s, s2);
    __syncthreads();
    float2 a0 = part[0], a1 = part[1], a2 = part[2], a3 = part[3];
    float S  = a0.x+a1.x+a2.x+a3.x;
    float S2 = a0.y+a1.y+a2.y+a3.y;
    float mu  = S*(1.0f/ND);
    float var = S2*(1.0f/ND) - mu*mu;
    float rs  = rsqrtf(var + EPSF);
    h[(size_t)row*ND + tid] = (v - mu)*rs*g[tid] + bb[tid];
}

extern "C" void kernel_launch(void* const* d_in, const int* in_sizes, int n_in,
                              void* d_out, int out_size, void* d_ws, size_t ws_size,
                              hipStream_t stream)
{
    const float* x    = (const float*)d_in[0];
    const float* w_in = (const float*)d_in[1];
    const float* b_in = (const float*)d_in[2];
    const float* pos  = (const float*)d_in[3];
    const float* ln_g = (const float*)d_in[4];
    const float* ln_b = (const float*)d_in[5];
    const float* inw  = (const float*)d_in[6];
    const float* inb  = (const float*)d_in[7];
    const float* dww  = (const float*)d_in[8];
    const float* mixw = (const float*)d_in[9];
    const float* mixb = (const float*)d_in[10];
    const float* outw = (const float*)d_in[11];
    const float* outb = (const float*)d_in[12];
    const float* olng = (const float*)d_in[13];
    const float* olnb = (const float*)d_in[14];
    float* h = (float*)d_out;

    const size_t UB = (size_t)NPOS * NH;          // 71,827,456 elems
    unsigned short* u_ws   = (unsigned short*)d_ws;
    unsigned short* g_ws   = u_ws + UB;
    unsigned short* outw_b = g_ws + UB;           // L*D*H = 524288 bf16 (frag order)
    unsigned short* mixw_b = outw_b + 524288;     // L*H*64 = 131072 bf16 (frag order)
    unsigned short* inw_b  = mixw_b + 131072;     // L*1024*32 = 131072 bf16 (frag order)

    k_init<<<NPOS, 256, 0, stream>>>(x, w_in, b_in, pos, h);
    k_prep<<<3072, 256, 0, stream>>>(outw, mixw, inw, outw_b, mixw_b, inw_b);
    for (int l = 0; l < 4; ++l) {
        kA2<<<dim3(9, NB), 256, 0, stream>>>(h, ln_g + l*ND, ln_b + l*ND,
            inw_b + (size_t)l*32768, inb + l*NHH, u_ws, g_ws);
        kBC<<<dim3(18, NB), 512, 0, stream>>>(u_ws, g_ws, dww + l*NH*7,
            mixw_b + (size_t)l*32768, mixb + l*NH,
            outw_b + (size_t)l*131072, outb + l*ND, h);
    }
    kLN<<<NPOS, 256, 0, stream>>>(h, olng, olnb);
}

// Round 13
// 1581.753 us; speedup vs baseline: 1.8380x; 1.1001x over previous
//
#include <hip/hip_runtime.h>

#define NB 512
#define NT 274
#define ND 256
#define NH 512
#define NHH 1024
#define NPOS (NB*NT)
#define EPSF 1e-5f
#define UST 520    // LDS row stride for u/uc/v (1040B, 16B-mult, ==4 dw mod 32)

typedef float f32x4 __attribute__((ext_vector_type(4)));
typedef unsigned int u32x4 __attribute__((ext_vector_type(4)));
typedef unsigned int u32x2 __attribute__((ext_vector_type(2)));
typedef short s16x8 __attribute__((ext_vector_type(8)));   // 8 bf16 = 4 VGPRs

__device__ __forceinline__ float bf2f(unsigned short s) {
    unsigned int u = ((unsigned int)s) << 16;
    float f; __builtin_memcpy(&f, &u, 4); return f;
}
__device__ __forceinline__ unsigned short f2bf(float f) {
    unsigned int u; __builtin_memcpy(&u, &f, 4);
    unsigned int r = u + 0x7FFFu + ((u >> 16) & 1u);   // round-to-nearest-even
    return (unsigned short)(r >> 16);
}

// ---------------- init: h = x[:,:,None]*w_in + b_in + pos ----------------
__global__ __launch_bounds__(256) void k_init(const float* __restrict__ x,
    const float* __restrict__ w_in, const float* __restrict__ b_in,
    const float* __restrict__ pos, float* __restrict__ h)
{
    int row = blockIdx.x;              // 0..NPOS-1  (b*NT + t)
    int d = threadIdx.x;
    int t = row % NT;
    float xv = x[row];
    h[(size_t)row*ND + d] = fmaf(xv, w_in[d], b_in[d] + pos[t*ND + d]);
}

// ------- prep: weights -> bf16 in MFMA-FRAGMENT ORDER; dww -> symmetrized f32 -------
__global__ __launch_bounds__(256) void k_prep(const float* __restrict__ outw,
    const float* __restrict__ mixw, const float* __restrict__ inw,
    const float* __restrict__ dww,
    unsigned short* __restrict__ ob, unsigned short* __restrict__ mb,
    unsigned short* __restrict__ iwb, float* __restrict__ dws)
{
    int i = blockIdx.x*256 + threadIdx.x;   // 0 .. 794623
    if (i < 524288) {
        // outw: per layer 256x512, instr = ks*16 + c4t
        int l = i >> 17, q = i & 131071;
        int j = q & 7, lane = (q >> 3) & 63, c4t = (q >> 9) & 15, ks = q >> 13;
        int src = (c4t*16 + (lane & 15))*512 + ks*32 + (lane >> 4)*8 + j;
        ob[i] = f2bf(outw[(size_t)l*131072 + src]);
    } else if (i < 655360) {
        // mixw: per layer 512x64, instr = (g*4+nt)*2 + half
        int v = i - 524288;
        int l = v >> 15, q = v & 32767;
        int j = q & 7, lane = (q >> 3) & 63, half = (q >> 9) & 1, gnt = q >> 10;
        int g = gnt >> 2, nt = gnt & 3;
        int src = (g*64 + nt*16 + (lane & 15))*64 + half*32 + (lane >> 4)*8 + j;
        mb[v] = f2bf(mixw[(size_t)l*32768 + src]);
    } else if (i < 786432) {
        // inw: per layer 1024x32, instr = g*8 + nt
        int v = i - 655360;
        int l = v >> 15, q = v & 32767;
        int j = q & 7, lane = (q >> 3) & 63, gnt = q >> 9;
        int g = gnt >> 3, nt = gnt & 7;
        int src = (g*128 + nt*16 + (lane & 15))*32 + (lane >> 4)*8 + j;
        iwb[v] = f2bf(inw[(size_t)l*32768 + src]);
    } else if (i < 794624) {
        // dws[l][c][k] = 0.5*(dww[k] + dww[6-k]), k=0..3
        int v = i - 786432;
        int l = v >> 11, c = (v >> 2) & 511, k = v & 3;
        const float* w = dww + (size_t)l*3584 + c*7;
        dws[v] = 0.5f*(w[k] + w[6-k]);
    }
}

// ------- kA2: LN + grouped in-proj (MFMA intrinsic, K=32) + silu/sigmoid -------
// Gate stored PERMUTED: g_ws[row*NH + (oc>>6)*64 + (oc&15)*4 + ((oc>>4)&3)]
__global__ __launch_bounds__(256) void kA2(const float* __restrict__ h,
    const float* __restrict__ lng, const float* __restrict__ lnb,
    const unsigned short* __restrict__ inw_b, const float* __restrict__ inb,
    unsigned short* __restrict__ u_ws, unsigned short* __restrict__ g_ws)
{
    const int b  = blockIdx.y;
    const int t0 = blockIdx.x * 32;
    const int tid = threadIdx.x;
    const int lane = tid & 63, wvid = tid >> 6;
    __shared__ __align__(16) unsigned short yl[32][264];  // y bf16, row stride 528B
    __shared__ float s_lng[ND], s_lnb[ND];
    __shared__ float s_inb[NHH];

    s_lng[tid] = lng[tid];
    s_lnb[tid] = lnb[tid];
    #pragma unroll
    for (int q = 0; q < 4; ++q) s_inb[tid + 256*q] = inb[tid + 256*q];

    {
        const int r  = tid >> 3;
        const int c0 = (tid & 7) * 32;
        const int trow = t0 + r;
        float vals[32];
        if (trow < NT) {
            const float4* hp = reinterpret_cast<const float4*>(
                h + ((size_t)b*NT + trow)*ND + c0);
            #pragma unroll
            for (int j = 0; j < 8; ++j) {
                float4 f = hp[j];
                vals[4*j+0]=f.x; vals[4*j+1]=f.y; vals[4*j+2]=f.z; vals[4*j+3]=f.w;
            }
        } else {
            #pragma unroll
            for (int j = 0; j < 32; ++j) vals[j] = 0.0f;
        }
        float s = 0.f, s2 = 0.f;
        #pragma unroll
        for (int j = 0; j < 32; ++j) { s += vals[j]; s2 += vals[j]*vals[j]; }
        #pragma unroll
        for (int off = 1; off < 8; off <<= 1) {
            s  += __shfl_xor(s, off);
            s2 += __shfl_xor(s2, off);
        }
        float mu  = s * (1.0f/ND);
        float var = s2 * (1.0f/ND) - mu*mu;
        float rs  = rsqrtf(var + EPSF);
        __syncthreads();   // s_lng/s_lnb ready
        #pragma unroll
        for (int j = 0; j < 16; ++j) {
            int c = c0 + 2*j;
            float y0 = (vals[2*j]   - mu) * rs * s_lng[c]   + s_lnb[c];
            float y1 = (vals[2*j+1] - mu) * rs * s_lng[c+1] + s_lnb[c+1];
            unsigned int packed = (unsigned)f2bf(y0) | ((unsigned)f2bf(y1) << 16);
            *reinterpret_cast<unsigned int*>(&yl[r][c]) = packed;
        }
    }
    __syncthreads();

    const int r_lo = lane & 15, kb = lane >> 4;
    for (int cb = 0; cb < 4; ++cb) {
        const int combo = wvid*4 + cb;        // 16 combos = 2 row-tiles x 8 groups
        const int rt = combo >> 3, g = combo & 7;
        const int arow = rt*16 + r_lo;
        s16x8 a = *reinterpret_cast<const s16x8*>(&yl[arow][g*32 + kb*8]);
        f32x4 acc[8];
        #pragma unroll
        for (int nt = 0; nt < 8; ++nt) acc[nt] = (f32x4){0.f,0.f,0.f,0.f};
        #pragma unroll
        for (int nt = 0; nt < 8; ++nt) {
            s16x8 bf = *reinterpret_cast<const s16x8*>(
                inw_b + (size_t)((g*8 + nt)*64 + lane)*8);
            acc[nt] = __builtin_amdgcn_mfma_f32_16x16x32_bf16(a, bf, acc[nt], 0, 0, 0);
        }
        const int crow0 = rt*16 + kb*4;
        #pragma unroll
        for (int nt = 0; nt < 8; ++nt) {
            const int ocol = g*128 + nt*16 + r_lo;
            const float bia = s_inb[ocol];
            #pragma unroll
            for (int r = 0; r < 4; ++r) {
                int trow = t0 + crow0 + r;
                if (trow < NT) {
                    float tv = acc[nt][r] + bia;
                    float sg = 1.0f / (1.0f + __expf(-tv));
                    size_t base = ((size_t)b*NT + trow)*NH;
                    if (ocol < NH) {
                        u_ws[base + ocol] = f2bf(tv * sg);
                    } else {
                        int oc = ocol - NH;
                        g_ws[base + (oc >> 6)*64 + (oc & 15)*4 + ((oc >> 4) & 3)]
                            = f2bf(sg);
                    }
                }
            }
        }
    }
}

// ======= kBC: conv + grouped mix + gate + out-proj + residual (fused) =======
// 512 threads / 8 waves; 4 blocks/CU. MFMA intrinsics. Gates (permuted, 8B
// vector), residual h, and symmetrized conv weights prefetched at entry.
__global__ __launch_bounds__(512, 8) void kBC(const unsigned short* __restrict__ u_ws,
    const unsigned short* __restrict__ g_ws, const float* __restrict__ dws,
    const unsigned short* __restrict__ mixw_b, const float* __restrict__ mixb,
    const unsigned short* __restrict__ outw_b, const float* __restrict__ outb,
    float* __restrict__ h)
{
    const int b   = blockIdx.y;
    const int t0  = blockIdx.x * 16;
    const int tid = threadIdx.x;            // 0..511
    const int lane = tid & 63, wvid = tid >> 6;   // 8 waves
    const int r_lo = lane & 15, kb = lane >> 4;
    const size_t rowbase = (size_t)b*NT;
    __shared__ __align__(16) unsigned short s_u[22*UST];  // u halo -> later v (16 rows)
    __shared__ __align__(16) unsigned short s_c[16*UST];  // conv output uc

    // --- prefetch (issued first; latency hides under staging + conv) ---
    u32x2 gpk[4];                 // 4 gates per row r (nt=0..3), permuted layout
    #pragma unroll
    for (int r = 0; r < 4; ++r) {
        const int t = t0 + kb*4 + r;
        gpk[r] = (t < NT)
            ? *reinterpret_cast<const u32x2*>(g_ws + (rowbase + t)*NH + wvid*64 + r_lo*4)
            : (u32x2){0u, 0u};
    }
    float hres[2][4];             // residual h values
    #pragma unroll
    for (int c4 = 0; c4 < 2; ++c4) {
        const int d = wvid*32 + c4*16 + r_lo;
        #pragma unroll
        for (int r = 0; r < 4; ++r) {
            const int t = t0 + kb*4 + r;
            hres[c4][r] = (t < NT) ? h[(rowbase + t)*ND + d] : 0.0f;
        }
    }
    const float4 cw = *reinterpret_cast<const float4*>(dws + tid*4);

    // --- stage u halo rows t0-3 .. t0+18 (b128, coalesced) ---
    for (int idx = tid; idx < 22*64; idx += 512) {
        int r = idx >> 6, c16 = idx & 63;
        int t = t0 - 3 + r;
        u32x4 val = (u32x4){0u,0u,0u,0u};
        if (t >= 0 && t < NT)
            val = *reinterpret_cast<const u32x4*>(u_ws + (rowbase + t)*NH + c16*8);
        *reinterpret_cast<u32x4*>(&s_u[r*UST + c16*8]) = val;
    }
    __syncthreads();

    // --- symmetric depthwise conv (4 taps): thread owns channel tid ---
    {
        float uv[22];
        #pragma unroll
        for (int r = 0; r < 22; ++r)
            uv[r] = bf2f(s_u[r*UST + tid]);
        #pragma unroll
        for (int cr = 0; cr < 16; ++cr) {
            float s = cw.w * uv[cr + 3];
            s = fmaf(cw.x, uv[cr] + uv[cr + 6], s);
            s = fmaf(cw.y, uv[cr + 1] + uv[cr + 5], s);
            s = fmaf(cw.z, uv[cr + 2] + uv[cr + 4], s);
            s_c[cr*UST + tid] = f2bf(s);
        }
    }
    __syncthreads();

    // --- grouped mix (MFMA, K=64): wave owns group g = wvid; gate from regs ---
    {
        const int g = wvid;
        s16x8 a0 = *reinterpret_cast<const s16x8*>(&s_c[r_lo*UST + g*64 + kb*8]);
        s16x8 a1 = *reinterpret_cast<const s16x8*>(&s_c[r_lo*UST + g*64 + 32 + kb*8]);
        f32x4 acc[4];
        #pragma unroll
        for (int nt = 0; nt < 4; ++nt) acc[nt] = (f32x4){0.f,0.f,0.f,0.f};
        #pragma unroll
        for (int nt = 0; nt < 4; ++nt) {
            s16x8 b0 = *reinterpret_cast<const s16x8*>(
                mixw_b + (size_t)(((g*4 + nt)*2 + 0)*64 + lane)*8);
            acc[nt] = __builtin_amdgcn_mfma_f32_16x16x32_bf16(a0, b0, acc[nt], 0, 0, 0);
        }
        #pragma unroll
        for (int nt = 0; nt < 4; ++nt) {
            s16x8 b1 = *reinterpret_cast<const s16x8*>(
                mixw_b + (size_t)(((g*4 + nt)*2 + 1)*64 + lane)*8);
            acc[nt] = __builtin_amdgcn_mfma_f32_16x16x32_bf16(a1, b1, acc[nt], 0, 0, 0);
        }
        __syncthreads();   // s_c reads done block-wide; safe to overwrite s_u
        #pragma unroll
        for (int nt = 0; nt < 4; ++nt) {
            const int ocol = g*64 + nt*16 + r_lo;
            const float bia = mixb[ocol];
            #pragma unroll
            for (int r = 0; r < 4; ++r) {
                const int cr = kb*4 + r;
                const int t = t0 + cr;
                if (t < NT) {
                    unsigned short gu = (unsigned short)
                        ((gpk[r][nt >> 1] >> ((nt & 1)*16)) & 0xffffu);
                    s_u[cr*UST + ocol] = f2bf((acc[nt][r] + bia) * bf2f(gu));
                } else {
                    s_u[cr*UST + ocol] = 0;
                }
            }
        }
    }
    __syncthreads();

    // --- out-proj (MFMA, K=512): wave owns d-cols wvid*32 .. +31 ---
    f32x4 acc4[2];
    #pragma unroll
    for (int c4 = 0; c4 < 2; ++c4) acc4[c4] = (f32x4){0.f,0.f,0.f,0.f};
    #pragma unroll
    for (int ks = 0; ks < 16; ++ks) {
        s16x8 a = *reinterpret_cast<const s16x8*>(&s_u[r_lo*UST + ks*32 + kb*8]);
        #pragma unroll
        for (int c4 = 0; c4 < 2; ++c4) {
            const int c4t = wvid*2 + c4;
            s16x8 bf = *reinterpret_cast<const s16x8*>(
                outw_b + (size_t)((ks*16 + c4t)*64 + lane)*8);
            acc4[c4] = __builtin_amdgcn_mfma_f32_16x16x32_bf16(a, bf, acc4[c4], 0, 0, 0);
        }
    }
    #pragma unroll
    for (int c4 = 0; c4 < 2; ++c4) {
        const int d = wvid*32 + c4*16 + r_lo;
        const float ob = outb[d];
        #pragma unroll
        for (int r = 0; r < 4; ++r) {
            const int cr = kb*4 + r;
            const int t = t0 + cr;
            if (t < NT)
                h[(rowbase + t)*ND + d] = hres[c4][r] + acc4[c4][r] + ob;
        }
    }
}

// ---------------- final layernorm (in place) ----------------
__global__ __launch_bounds__(256) void kLN(float* __restrict__ h,
    const float* __restrict__ g, const float* __restrict__ bb)
{
    const int row = blockIdx.x;
    const int tid = threadIdx.x;
    const int lane = tid & 63, wvi = tid >> 6;
    __shared__ float2 part[4];
    float v = h[(size_t)row*ND + tid];
    float s = v, s2 = v*v;
    #pragma unroll
    for (int off = 32; off; off >>= 1) { s += __shfl_down(s, off); s2 += __shfl_down(s2, off); }
    if (lane == 0) part[wvi] = make_float2(s, s2);
    __syncthreads();
    float2 a0 = part[0], a1 = part[1], a2 = part[2], a3 = part[3];
    float S  = a0.x+a1.x+a2.x+a3.x;
    float S2 = a0.y+a1.y+a2.y+a3.y;
    float mu  = S*(1.0f/ND);
    float var = S2*(1.0f/ND) - mu*mu;
    float rs  = rsqrtf(var + EPSF);
    h[(size_t)row*ND + tid] = (v - mu)*rs*g[tid] + bb[tid];
}

extern "C" void kernel_launch(void* const* d_in, const int* in_sizes, int n_in,
                              void* d_out, int out_size, void* d_ws, size_t ws_size,
                              hipStream_t stream)
{
    const float* x    = (const float*)d_in[0];
    const float* w_in = (const float*)d_in[1];
    const float* b_in = (const float*)d_in[2];
    const float* pos  = (const float*)d_in[3];
    const float* ln_g = (const float*)d_in[4];
    const float* ln_b = (const float*)d_in[5];
    const float* inw  = (const float*)d_in[6];
    const float* inb  = (const float*)d_in[7];
    const float* dww  = (const float*)d_in[8];
    const float* mixw = (const float*)d_in[9];
    const float* mixb = (const float*)d_in[10];
    const float* outw = (const float*)d_in[11];
    const float* outb = (const float*)d_in[12];
    const float* olng = (const float*)d_in[13];
    const float* olnb = (const float*)d_in[14];
    float* h = (float*)d_out;

    const size_t UB = (size_t)NPOS * NH;          // 71,827,456 elems
    unsigned short* u_ws   = (unsigned short*)d_ws;
    unsigned short* g_ws   = u_ws + UB;
    unsigned short* outw_b = g_ws + UB;           // L*D*H = 524288 bf16 (frag order)
    unsigned short* mixw_b = outw_b + 524288;     // L*H*64 = 131072 bf16 (frag order)
    unsigned short* inw_b  = mixw_b + 131072;     // L*1024*32 = 131072 bf16 (frag order)
    float*          dws    = (float*)(inw_b + 131072);  // L*512*4 f32 symmetrized

    k_init<<<NPOS, 256, 0, stream>>>(x, w_in, b_in, pos, h);
    k_prep<<<3104, 256, 0, stream>>>(outw, mixw, inw, dww, outw_b, mixw_b, inw_b, dws);
    for (int l = 0; l < 4; ++l) {
        kA2<<<dim3(9, NB), 256, 0, stream>>>(h, ln_g + l*ND, ln_b + l*ND,
            inw_b + (size_t)l*32768, inb + l*NHH, u_ws, g_ws);
        kBC<<<dim3(18, NB), 512, 0, stream>>>(u_ws, g_ws, dws + (size_t)l*2048,
            mixw_b + (size_t)l*32768, mixb + l*NH,
            outw_b + (size_t)l*131072, outb + l*ND, h);
    }
    kLN<<<NPOS, 256, 0, stream>>>(h, olng, olnb);
}

// Round 14
// 1514.539 us; speedup vs baseline: 1.9196x; 1.0444x over previous
//
#include <hip/hip_runtime.h>

#define NB 512
#define NT 274
#define ND 256
#define NH 512
#define NHH 1024
#define NPOS (NB*NT)
#define EPSF 1e-5f
#define TILE 16
#define HALO 22
#define YST 264    // y row stride (elems); 32 rows in s_a
#define UST 520    // u/uc/v row stride

typedef float f32x4 __attribute__((ext_vector_type(4)));
typedef unsigned int u32x4 __attribute__((ext_vector_type(4)));
typedef unsigned int u32x2 __attribute__((ext_vector_type(2)));
typedef short s16x8 __attribute__((ext_vector_type(8)));   // 8 bf16 = 4 VGPRs

__device__ __forceinline__ float bf2f(unsigned short s) {
    unsigned int u = ((unsigned int)s) << 16;
    float f; __builtin_memcpy(&f, &u, 4); return f;
}
__device__ __forceinline__ unsigned short f2bf(float f) {
    unsigned int u; __builtin_memcpy(&u, &f, 4);
    unsigned int r = u + 0x7FFFu + ((u >> 16) & 1u);   // round-to-nearest-even
    return (unsigned short)(r >> 16);
}

// ---------------- init: h = x[:,:,None]*w_in + b_in + pos ----------------
__global__ __launch_bounds__(256) void k_init(const float* __restrict__ x,
    const float* __restrict__ w_in, const float* __restrict__ b_in,
    const float* __restrict__ pos, float* __restrict__ h)
{
    int row = blockIdx.x;              // 0..NPOS-1  (b*NT + t)
    int d = threadIdx.x;
    int t = row % NT;
    float xv = x[row];
    h[(size_t)row*ND + d] = fmaf(xv, w_in[d], b_in[d] + pos[t*ND + d]);
}

// ------- prep: weights -> bf16 in MFMA-FRAGMENT ORDER; dww -> symmetrized f32 -------
__global__ __launch_bounds__(256) void k_prep(const float* __restrict__ outw,
    const float* __restrict__ mixw, const float* __restrict__ inw,
    const float* __restrict__ dww,
    unsigned short* __restrict__ ob, unsigned short* __restrict__ mb,
    unsigned short* __restrict__ iwb, float* __restrict__ dws)
{
    int i = blockIdx.x*256 + threadIdx.x;   // 0 .. 794623
    if (i < 524288) {
        // outw: per layer 256x512, instr = ks*16 + c4t
        int l = i >> 17, q = i & 131071;
        int j = q & 7, lane = (q >> 3) & 63, c4t = (q >> 9) & 15, ks = q >> 13;
        int src = (c4t*16 + (lane & 15))*512 + ks*32 + (lane >> 4)*8 + j;
        ob[i] = f2bf(outw[(size_t)l*131072 + src]);
    } else if (i < 655360) {
        // mixw: per layer 512x64, instr = (g*4+nt)*2 + half
        int v = i - 524288;
        int l = v >> 15, q = v & 32767;
        int j = q & 7, lane = (q >> 3) & 63, half = (q >> 9) & 1, gnt = q >> 10;
        int g = gnt >> 2, nt = gnt & 3;
        int src = (g*64 + nt*16 + (lane & 15))*64 + half*32 + (lane >> 4)*8 + j;
        mb[v] = f2bf(mixw[(size_t)l*32768 + src]);
    } else if (i < 786432) {
        // inw: per layer 1024x32, instr = g*8 + nt
        int v = i - 655360;
        int l = v >> 15, q = v & 32767;
        int j = q & 7, lane = (q >> 3) & 63, gnt = q >> 9;
        int g = gnt >> 3, nt = gnt & 7;
        int src = (g*128 + nt*16 + (lane & 15))*32 + (lane >> 4)*8 + j;
        iwb[v] = f2bf(inw[(size_t)l*32768 + src]);
    } else if (i < 794624) {
        // dws[l][c][k] = 0.5*(dww[k] + dww[6-k]), k=0..3
        int v = i - 786432;
        int l = v >> 11, c = (v >> 2) & 511, k = v & 3;
        const float* w = dww + (size_t)l*3584 + c*7;
        dws[v] = 0.5f*(w[k] + w[6-k]);
    }
}

// ======= kL2: whole layer fused, 512 thr / 8 waves, 39.8KB LDS (4 blk/CU) =======
// P0 LN->y | P1 in-proj (u halo via MFMA; gates central rows -> REGISTERS) |
// P2 conv | P3 mix+gate->v | P4 out-proj + residual. h ping-pong (hin->hout).
__global__ __launch_bounds__(512, 8) void kL2(const float* __restrict__ hin,
    float* __restrict__ hout,
    const float* __restrict__ lng, const float* __restrict__ lnb,
    const unsigned short* __restrict__ inw_b, const float* __restrict__ inb,
    const float* __restrict__ dws,
    const unsigned short* __restrict__ mixw_b, const float* __restrict__ mixb,
    const unsigned short* __restrict__ outw_b, const float* __restrict__ outb)
{
    const int b   = blockIdx.y;
    const int t0  = blockIdx.x * TILE;
    const int tid = threadIdx.x;            // 0..511
    const int lane = tid & 63, wvid = tid >> 6;   // 8 waves
    const int r_lo = lane & 15, kb = lane >> 4;
    const size_t rowbase = (size_t)b*NT;
    __shared__ __align__(16) unsigned short s_a[32*YST];   // y (32 rows) -> uc (16xUST)
    __shared__ __align__(16) unsigned short s_u[HALO*UST]; // u (22 rows) -> v (16 rows)

    // --- prefetch residual h + conv weights (latency hides under P0/P1) ---
    float hres[2][4];
    #pragma unroll
    for (int c4 = 0; c4 < 2; ++c4) {
        const int d = wvid*32 + c4*16 + r_lo;
        #pragma unroll
        for (int r = 0; r < 4; ++r) {
            const int t = t0 + kb*4 + r;
            hres[c4][r] = (t < NT) ? hin[(rowbase + t)*ND + d] : 0.0f;
        }
    }
    const float4 cw = *reinterpret_cast<const float4*>(dws + tid*4);

    // --- P0: load h halo rows t0-3..t0+18, LN -> y (bf16 in s_a) ---
    {
        const int r  = tid >> 4;            // 0..31 (rows >=22 zeroed)
        const int c0 = (tid & 15) * 16;
        const int t  = t0 - 3 + r;
        const bool vld = (r < HALO) && (t >= 0) && (t < NT);
        float vals[16];
        if (vld) {
            const float4* hp = reinterpret_cast<const float4*>(
                hin + (rowbase + t)*ND + c0);
            #pragma unroll
            for (int j = 0; j < 4; ++j) {
                float4 f = hp[j];
                vals[4*j+0]=f.x; vals[4*j+1]=f.y; vals[4*j+2]=f.z; vals[4*j+3]=f.w;
            }
        } else {
            #pragma unroll
            for (int j = 0; j < 16; ++j) vals[j] = 0.0f;
        }
        float s = 0.f, s2 = 0.f;
        #pragma unroll
        for (int j = 0; j < 16; ++j) { s += vals[j]; s2 += vals[j]*vals[j]; }
        #pragma unroll
        for (int off = 1; off < 16; off <<= 1) {   // 16 lanes per row, aligned
            s  += __shfl_xor(s, off);
            s2 += __shfl_xor(s2, off);
        }
        float mu  = s * (1.0f/ND);
        float var = s2 * (1.0f/ND) - mu*mu;
        float rs  = rsqrtf(var + EPSF);
        if (vld) {
            #pragma unroll
            for (int j = 0; j < 4; ++j) {
                float4 g4 = *reinterpret_cast<const float4*>(lng + c0 + 4*j);
                float4 b4 = *reinterpret_cast<const float4*>(lnb + c0 + 4*j);
                float y0 = (vals[4*j+0]-mu)*rs*g4.x + b4.x;
                float y1 = (vals[4*j+1]-mu)*rs*g4.y + b4.y;
                float y2 = (vals[4*j+2]-mu)*rs*g4.z + b4.z;
                float y3 = (vals[4*j+3]-mu)*rs*g4.w + b4.w;
                u32x2 pk;
                pk[0] = (unsigned)f2bf(y0) | ((unsigned)f2bf(y1) << 16);
                pk[1] = (unsigned)f2bf(y2) | ((unsigned)f2bf(y3) << 16);
                *reinterpret_cast<u32x2*>(&s_a[r*YST + c0 + 4*j]) = pk;
            }
        } else {
            #pragma unroll
            for (int j = 0; j < 4; ++j)
                *reinterpret_cast<u32x2*>(&s_a[r*YST + c0 + 4*j]) = (u32x2){0u,0u};
        }
    }
    __syncthreads();

    // --- P1: grouped in-proj. u over halo rows -> s_u; gates (central) -> regs ---
    unsigned int gpk[8];    // gates bf16-packed: [nt*2 + (r>>1)]
    {
        // u-part: wave = (rt = wvid>>2, g = wvid&3); 8 col-tiles (nt 0..7)
        const int rt = wvid >> 2, g = wvid & 3;
        s16x8 a = *reinterpret_cast<const s16x8*>(
            &s_a[(rt*16 + r_lo)*YST + g*32 + kb*8]);
        #pragma unroll
        for (int half = 0; half < 2; ++half) {
            f32x4 acc[4];
            #pragma unroll
            for (int q = 0; q < 4; ++q) acc[q] = (f32x4){0.f,0.f,0.f,0.f};
            #pragma unroll
            for (int q = 0; q < 4; ++q) {
                const int nt = half*4 + q;
                s16x8 bf = *reinterpret_cast<const s16x8*>(
                    inw_b + (size_t)((g*8 + nt)*64 + lane)*8);
                acc[q] = __builtin_amdgcn_mfma_f32_16x16x32_bf16(a, bf, acc[q], 0, 0, 0);
            }
            #pragma unroll
            for (int q = 0; q < 4; ++q) {
                const int nt = half*4 + q;
                const int ocol = g*128 + nt*16 + r_lo;
                const float bia = inb[ocol];
                #pragma unroll
                for (int r = 0; r < 4; ++r) {
                    const int hr = rt*16 + kb*4 + r;
                    if (hr < HALO) {
                        const int t = t0 - 3 + hr;
                        unsigned short val = 0;
                        if (t >= 0 && t < NT) {
                            float tv = acc[q][r] + bia;
                            float sg = 1.0f / (1.0f + __expf(-tv));
                            val = f2bf(tv * sg);
                        }
                        s_u[hr*UST + ocol] = val;
                    }
                }
            }
        }
        // gate-part: central rows (y rows 3..18); wave owns gate cols wvid*64..+63.
        // C layout puts gate[row kb*4+r][col wvid*64+nt*16+r_lo] in THIS thread.
        s16x8 ag = *reinterpret_cast<const s16x8*>(
            &s_a[(3 + r_lo)*YST + 128 + (wvid >> 1)*32 + kb*8]);
        f32x4 gacc[4];
        #pragma unroll
        for (int nt = 0; nt < 4; ++nt) gacc[nt] = (f32x4){0.f,0.f,0.f,0.f};
        #pragma unroll
        for (int nt = 0; nt < 4; ++nt) {
            const int instr = (4 + (wvid >> 1))*8 + (wvid & 1)*4 + nt;
            s16x8 bf = *reinterpret_cast<const s16x8*>(
                inw_b + (size_t)(instr*64 + lane)*8);
            gacc[nt] = __builtin_amdgcn_mfma_f32_16x16x32_bf16(ag, bf, gacc[nt], 0, 0, 0);
        }
        #pragma unroll
        for (int nt = 0; nt < 4; ++nt) {
            const float bia = inb[512 + wvid*64 + nt*16 + r_lo];
            #pragma unroll
            for (int rp = 0; rp < 2; ++rp) {
                float s0 = 1.0f / (1.0f + __expf(-(gacc[nt][2*rp]   + bia)));
                float s1 = 1.0f / (1.0f + __expf(-(gacc[nt][2*rp+1] + bia)));
                gpk[nt*2 + rp] = (unsigned)f2bf(s0) | ((unsigned)f2bf(s1) << 16);
            }
        }
    }
    __syncthreads();

    // --- P2: symmetric depthwise conv (4 taps); thread owns channel tid -> s_a ---
    {
        float uv[HALO];
        #pragma unroll
        for (int r = 0; r < HALO; ++r)
            uv[r] = bf2f(s_u[r*UST + tid]);
        #pragma unroll
        for (int cr = 0; cr < TILE; ++cr) {
            float s = cw.w * uv[cr + 3];
            s = fmaf(cw.x, uv[cr] + uv[cr + 6], s);
            s = fmaf(cw.y, uv[cr + 1] + uv[cr + 5], s);
            s = fmaf(cw.z, uv[cr + 2] + uv[cr + 4], s);
            s_a[cr*UST + tid] = f2bf(s);
        }
    }
    __syncthreads();

    // --- P3: grouped mix (K=64) + in-reg gates -> v (s_u rows 0..15) ---
    {
        const int g = wvid;
        s16x8 a0 = *reinterpret_cast<const s16x8*>(&s_a[r_lo*UST + g*64 + kb*8]);
        s16x8 a1 = *reinterpret_cast<const s16x8*>(&s_a[r_lo*UST + g*64 + 32 + kb*8]);
        f32x4 acc[4];
        #pragma unroll
        for (int nt = 0; nt < 4; ++nt) acc[nt] = (f32x4){0.f,0.f,0.f,0.f};
        #pragma unroll
        for (int nt = 0; nt < 4; ++nt) {
            s16x8 b0 = *reinterpret_cast<const s16x8*>(
                mixw_b + (size_t)(((g*4 + nt)*2 + 0)*64 + lane)*8);
            acc[nt] = __builtin_amdgcn_mfma_f32_16x16x32_bf16(a0, b0, acc[nt], 0, 0, 0);
        }
        #pragma unroll
        for (int nt = 0; nt < 4; ++nt) {
            s16x8 b1 = *reinterpret_cast<const s16x8*>(
                mixw_b + (size_t)(((g*4 + nt)*2 + 1)*64 + lane)*8);
            acc[nt] = __builtin_amdgcn_mfma_f32_16x16x32_bf16(a1, b1, acc[nt], 0, 0, 0);
        }
        #pragma unroll
        for (int nt = 0; nt < 4; ++nt) {
            const int ocol = g*64 + nt*16 + r_lo;
            const float bia = mixb[ocol];
            #pragma unroll
            for (int r = 0; r < 4; ++r) {
                const int cr = kb*4 + r;
                unsigned short gu = (unsigned short)
                    ((gpk[nt*2 + (r >> 1)] >> ((r & 1)*16)) & 0xffffu);
                s_u[cr*UST + ocol] = f2bf((acc[nt][r] + bia) * bf2f(gu));
            }
        }
    }
    __syncthreads();

    // --- P4: out-proj (K=512) + bias + residual -> hout ---
    f32x4 acc4[2];
    #pragma unroll
    for (int c4 = 0; c4 < 2; ++c4) acc4[c4] = (f32x4){0.f,0.f,0.f,0.f};
    #pragma unroll
    for (int ks = 0; ks < 16; ++ks) {
        s16x8 a = *reinterpret_cast<const s16x8*>(&s_u[r_lo*UST + ks*32 + kb*8]);
        #pragma unroll
        for (int c4 = 0; c4 < 2; ++c4) {
            const int c4t = wvid*2 + c4;
            s16x8 bf = *reinterpret_cast<const s16x8*>(
                outw_b + (size_t)((ks*16 + c4t)*64 + lane)*8);
            acc4[c4] = __builtin_amdgcn_mfma_f32_16x16x32_bf16(a, bf, acc4[c4], 0, 0, 0);
        }
    }
    #pragma unroll
    for (int c4 = 0; c4 < 2; ++c4) {
        const int d = wvid*32 + c4*16 + r_lo;
        const float ob = outb[d];
        #pragma unroll
        for (int r = 0; r < 4; ++r) {
            const int cr = kb*4 + r;
            const int t = t0 + cr;
            if (t < NT)
                hout[(rowbase + t)*ND + d] = hres[c4][r] + acc4[c4][r] + ob;
        }
    }
}

// ---------------- final layernorm (in place) ----------------
__global__ __launch_bounds__(256) void kLN(float* __restrict__ h,
    const float* __restrict__ g, const float* __restrict__ bb)
{
    const int row = blockIdx.x;
    const int tid = threadIdx.x;
    const int lane = tid & 63, wvi = tid >> 6;
    __shared__ float2 part[4];
    float v = h[(size_t)row*ND + tid];
    float s = v, s2 = v*v;
    #pragma unroll
    for (int off = 32; off; off >>= 1) { s += __shfl_down(s, off); s2 += __shfl_down(s2, off); }
    if (lane == 0) part[wvi] = make_float2(s, s2);
    __syncthreads();
    float2 a0 = part[0], a1 = part[1], a2 = part[2], a3 = part[3];
    float S  = a0.x+a1.x+a2.x+a3.x;
    float S2 = a0.y+a1.y+a2.y+a3.y;
    float mu  = S*(1.0f/ND);
    float var = S2*(1.0f/ND) - mu*mu;
    float rs  = rsqrtf(var + EPSF);
    h[(size_t)row*ND + tid] = (v - mu)*rs*g[tid] + bb[tid];
}

extern "C" void kernel_launch(void* const* d_in, const int* in_sizes, int n_in,
                              void* d_out, int out_size, void* d_ws, size_t ws_size,
                              hipStream_t stream)
{
    const float* x    = (const float*)d_in[0];
    const float* w_in = (const float*)d_in[1];
    const float* b_in = (const float*)d_in[2];
    const float* pos  = (const float*)d_in[3];
    const float* ln_g = (const float*)d_in[4];
    const float* ln_b = (const float*)d_in[5];
    const float* inw  = (const float*)d_in[6];
    const float* inb  = (const float*)d_in[7];
    const float* dww  = (const float*)d_in[8];
    const float* mixw = (const float*)d_in[9];
    const float* mixb = (const float*)d_in[10];
    const float* outw = (const float*)d_in[11];
    const float* outb = (const float*)d_in[12];
    const float* olng = (const float*)d_in[13];
    const float* olnb = (const float*)d_in[14];

    float* hA = (float*)d_out;                         // h ping (final result here)
    float* hB = (float*)d_ws;                          // h pong
    unsigned short* outw_b = (unsigned short*)((char*)d_ws + (size_t)NPOS*ND*4);
    unsigned short* mixw_b = outw_b + 524288;          // L*D*H
    unsigned short* inw_b  = mixw_b + 131072;          // L*H*64 ; then L*1024*32
    float*          dws    = (float*)(inw_b + 131072); // L*512*4 symmetrized conv wts

    k_init<<<NPOS, 256, 0, stream>>>(x, w_in, b_in, pos, hA);
    k_prep<<<3104, 256, 0, stream>>>(outw, mixw, inw, dww, outw_b, mixw_b, inw_b, dws);
    for (int l = 0; l < 4; ++l) {
        const float* src = (l & 1) ? hB : hA;
        float*       dst = (l & 1) ? hA : hB;
        kL2<<<dim3(18, NB), 512, 0, stream>>>(src, dst,
            ln_g + l*ND, ln_b + l*ND,
            inw_b + (size_t)l*32768, inb + l*NHH,
            dws + (size_t)l*2048,
            mixw_b + (size_t)l*32768, mixb + l*NH,
            outw_b + (size_t)l*131072, outb + l*ND);
    }
    kLN<<<NPOS, 256, 0, stream>>>(hA, olng, olnb);
}

// Round 15
// 1422.763 us; speedup vs baseline: 2.0434x; 1.0645x over previous
//
#include <hip/hip_runtime.h>

#define NB 512
#define NT 274
#define ND 256
#define NH 512
#define NHH 1024
#define NPOS (NB*NT)
#define EPSF 1e-5f
#define TILE 16
#define HALO 22
#define YST 264    // y row stride (elems); 32 rows in s_a
#define UST 520    // u/uc/v row stride

typedef float f32x4 __attribute__((ext_vector_type(4)));
typedef unsigned int u32x4 __attribute__((ext_vector_type(4)));
typedef unsigned int u32x2 __attribute__((ext_vector_type(2)));
typedef short s16x8 __attribute__((ext_vector_type(8)));   // 8 bf16 = 4 VGPRs

__device__ __forceinline__ float bf2f(unsigned short s) {
    unsigned int u = ((unsigned int)s) << 16;
    float f; __builtin_memcpy(&f, &u, 4); return f;
}
__device__ __forceinline__ unsigned short f2bf(float f) {
    unsigned int u; __builtin_memcpy(&u, &f, 4);
    unsigned int r = u + 0x7FFFu + ((u >> 16) & 1u);   // round-to-nearest-even
    return (unsigned short)(r >> 16);
}

// ---------------- init: h = x[:,:,None]*w_in + b_in + pos ----------------
__global__ __launch_bounds__(256) void k_init(const float* __restrict__ x,
    const float* __restrict__ w_in, const float* __restrict__ b_in,
    const float* __restrict__ pos, float* __restrict__ h)
{
    int row = blockIdx.x;              // 0..NPOS-1  (b*NT + t)
    int d = threadIdx.x;
    int t = row % NT;
    float xv = x[row];
    h[(size_t)row*ND + d] = fmaf(xv, w_in[d], b_in[d] + pos[t*ND + d]);
}

// ------- prep: weights -> bf16 in MFMA-FRAGMENT ORDER; dww -> symmetrized f32 -------
__global__ __launch_bounds__(256) void k_prep(const float* __restrict__ outw,
    const float* __restrict__ mixw, const float* __restrict__ inw,
    const float* __restrict__ dww,
    unsigned short* __restrict__ ob, unsigned short* __restrict__ mb,
    unsigned short* __restrict__ iwb, float* __restrict__ dws)
{
    int i = blockIdx.x*256 + threadIdx.x;   // 0 .. 794623
    if (i < 524288) {
        // outw: per layer 256x512, instr = ks*16 + c4t
        int l = i >> 17, q = i & 131071;
        int j = q & 7, lane = (q >> 3) & 63, c4t = (q >> 9) & 15, ks = q >> 13;
        int src = (c4t*16 + (lane & 15))*512 + ks*32 + (lane >> 4)*8 + j;
        ob[i] = f2bf(outw[(size_t)l*131072 + src]);
    } else if (i < 655360) {
        // mixw: per layer 512x64, instr = (g*4+nt)*2 + half
        int v = i - 524288;
        int l = v >> 15, q = v & 32767;
        int j = q & 7, lane = (q >> 3) & 63, half = (q >> 9) & 1, gnt = q >> 10;
        int g = gnt >> 2, nt = gnt & 3;
        int src = (g*64 + nt*16 + (lane & 15))*64 + half*32 + (lane >> 4)*8 + j;
        mb[v] = f2bf(mixw[(size_t)l*32768 + src]);
    } else if (i < 786432) {
        // inw: per layer 1024x32, instr = g*8 + nt
        int v = i - 655360;
        int l = v >> 15, q = v & 32767;
        int j = q & 7, lane = (q >> 3) & 63, gnt = q >> 9;
        int g = gnt >> 3, nt = gnt & 7;
        int src = (g*128 + nt*16 + (lane & 15))*32 + (lane >> 4)*8 + j;
        iwb[v] = f2bf(inw[(size_t)l*32768 + src]);
    } else if (i < 794624) {
        // dws[l][c][k] = 0.5*(dww[k] + dww[6-k]), k=0..3
        int v = i - 786432;
        int l = v >> 11, c = (v >> 2) & 511, k = v & 3;
        const float* w = dww + (size_t)l*3584 + c*7;
        dws[v] = 0.5f*(w[k] + w[6-k]);
    }
}

// ======= kL2: whole layer fused, 512 thr / 8 waves, 39.8KB LDS =======
// launch_bounds (512,6): VGPR cap ~80 -> NO SPILL (r14 spilled at cap 64:
// WRITE_SIZE 482MB vs 144MB needed). Conv uses rolling 7-reg window.
__global__ __launch_bounds__(512, 6) void kL2(const float* __restrict__ hin,
    float* __restrict__ hout,
    const float* __restrict__ lng, const float* __restrict__ lnb,
    const unsigned short* __restrict__ inw_b, const float* __restrict__ inb,
    const float* __restrict__ dws,
    const unsigned short* __restrict__ mixw_b, const float* __restrict__ mixb,
    const unsigned short* __restrict__ outw_b, const float* __restrict__ outb)
{
    const int b   = blockIdx.y;
    const int t0  = blockIdx.x * TILE;
    const int tid = threadIdx.x;            // 0..511
    const int lane = tid & 63, wvid = tid >> 6;   // 8 waves
    const int r_lo = lane & 15, kb = lane >> 4;
    const size_t rowbase = (size_t)b*NT;
    __shared__ __align__(16) unsigned short s_a[32*YST];   // y (32 rows) -> uc (16xUST)
    __shared__ __align__(16) unsigned short s_u[HALO*UST]; // u (22 rows) -> v (16 rows)

    // --- prefetch residual h + conv weights (latency hides under P0/P1) ---
    float hres[2][4];
    #pragma unroll
    for (int c4 = 0; c4 < 2; ++c4) {
        const int d = wvid*32 + c4*16 + r_lo;
        #pragma unroll
        for (int r = 0; r < 4; ++r) {
            const int t = t0 + kb*4 + r;
            hres[c4][r] = (t < NT) ? hin[(rowbase + t)*ND + d] : 0.0f;
        }
    }
    const float4 cw = *reinterpret_cast<const float4*>(dws + tid*4);

    // --- P0: load h halo rows t0-3..t0+18, LN -> y (bf16 in s_a) ---
    {
        const int r  = tid >> 4;            // 0..31 (rows >=22 zeroed)
        const int c0 = (tid & 15) * 16;
        const int t  = t0 - 3 + r;
        const bool vld = (r < HALO) && (t >= 0) && (t < NT);
        float vals[16];
        if (vld) {
            const float4* hp = reinterpret_cast<const float4*>(
                hin + (rowbase + t)*ND + c0);
            #pragma unroll
            for (int j = 0; j < 4; ++j) {
                float4 f = hp[j];
                vals[4*j+0]=f.x; vals[4*j+1]=f.y; vals[4*j+2]=f.z; vals[4*j+3]=f.w;
            }
        } else {
            #pragma unroll
            for (int j = 0; j < 16; ++j) vals[j] = 0.0f;
        }
        float s = 0.f, s2 = 0.f;
        #pragma unroll
        for (int j = 0; j < 16; ++j) { s += vals[j]; s2 += vals[j]*vals[j]; }
        #pragma unroll
        for (int off = 1; off < 16; off <<= 1) {   // 16 lanes per row, aligned
            s  += __shfl_xor(s, off);
            s2 += __shfl_xor(s2, off);
        }
        float mu  = s * (1.0f/ND);
        float var = s2 * (1.0f/ND) - mu*mu;
        float rs  = rsqrtf(var + EPSF);
        if (vld) {
            #pragma unroll
            for (int j = 0; j < 4; ++j) {
                float4 g4 = *reinterpret_cast<const float4*>(lng + c0 + 4*j);
                float4 b4 = *reinterpret_cast<const float4*>(lnb + c0 + 4*j);
                float y0 = (vals[4*j+0]-mu)*rs*g4.x + b4.x;
                float y1 = (vals[4*j+1]-mu)*rs*g4.y + b4.y;
                float y2 = (vals[4*j+2]-mu)*rs*g4.z + b4.z;
                float y3 = (vals[4*j+3]-mu)*rs*g4.w + b4.w;
                u32x2 pk;
                pk[0] = (unsigned)f2bf(y0) | ((unsigned)f2bf(y1) << 16);
                pk[1] = (unsigned)f2bf(y2) | ((unsigned)f2bf(y3) << 16);
                *reinterpret_cast<u32x2*>(&s_a[r*YST + c0 + 4*j]) = pk;
            }
        } else {
            #pragma unroll
            for (int j = 0; j < 4; ++j)
                *reinterpret_cast<u32x2*>(&s_a[r*YST + c0 + 4*j]) = (u32x2){0u,0u};
        }
    }
    __syncthreads();

    // --- P1: grouped in-proj. u over halo rows -> s_u; gates (central) -> regs ---
    unsigned int gpk[8];    // gates bf16-packed: [nt*2 + (r>>1)]
    {
        // u-part: wave = (rt = wvid>>2, g = wvid&3); 8 col-tiles (nt 0..7)
        const int rt = wvid >> 2, g = wvid & 3;
        s16x8 a = *reinterpret_cast<const s16x8*>(
            &s_a[(rt*16 + r_lo)*YST + g*32 + kb*8]);
        #pragma unroll
        for (int half = 0; half < 2; ++half) {
            f32x4 acc[4];
            #pragma unroll
            for (int q = 0; q < 4; ++q) acc[q] = (f32x4){0.f,0.f,0.f,0.f};
            #pragma unroll
            for (int q = 0; q < 4; ++q) {
                const int nt = half*4 + q;
                s16x8 bf = *reinterpret_cast<const s16x8*>(
                    inw_b + (size_t)((g*8 + nt)*64 + lane)*8);
                acc[q] = __builtin_amdgcn_mfma_f32_16x16x32_bf16(a, bf, acc[q], 0, 0, 0);
            }
            #pragma unroll
            for (int q = 0; q < 4; ++q) {
                const int nt = half*4 + q;
                const int ocol = g*128 + nt*16 + r_lo;
                const float bia = inb[ocol];
                #pragma unroll
                for (int r = 0; r < 4; ++r) {
                    const int hr = rt*16 + kb*4 + r;
                    if (hr < HALO) {
                        const int t = t0 - 3 + hr;
                        unsigned short val = 0;
                        if (t >= 0 && t < NT) {
                            float tv = acc[q][r] + bia;
                            float sg = 1.0f / (1.0f + __expf(-tv));
                            val = f2bf(tv * sg);
                        }
                        s_u[hr*UST + ocol] = val;
                    }
                }
            }
        }
        // gate-part: central rows (y rows 3..18); wave owns gate cols wvid*64..+63.
        // C layout puts gate[row kb*4+r][col wvid*64+nt*16+r_lo] in THIS thread.
        s16x8 ag = *reinterpret_cast<const s16x8*>(
            &s_a[(3 + r_lo)*YST + 128 + (wvid >> 1)*32 + kb*8]);
        f32x4 gacc[4];
        #pragma unroll
        for (int nt = 0; nt < 4; ++nt) gacc[nt] = (f32x4){0.f,0.f,0.f,0.f};
        #pragma unroll
        for (int nt = 0; nt < 4; ++nt) {
            const int instr = (4 + (wvid >> 1))*8 + (wvid & 1)*4 + nt;
            s16x8 bf = *reinterpret_cast<const s16x8*>(
                inw_b + (size_t)(instr*64 + lane)*8);
            gacc[nt] = __builtin_amdgcn_mfma_f32_16x16x32_bf16(ag, bf, gacc[nt], 0, 0, 0);
        }
        #pragma unroll
        for (int nt = 0; nt < 4; ++nt) {
            const float bia = inb[512 + wvid*64 + nt*16 + r_lo];
            #pragma unroll
            for (int rp = 0; rp < 2; ++rp) {
                float s0 = 1.0f / (1.0f + __expf(-(gacc[nt][2*rp]   + bia)));
                float s1 = 1.0f / (1.0f + __expf(-(gacc[nt][2*rp+1] + bia)));
                gpk[nt*2 + rp] = (unsigned)f2bf(s0) | ((unsigned)f2bf(s1) << 16);
            }
        }
    }
    __syncthreads();

    // --- P2: symmetric conv (4 taps), ROLLING 7-reg window; channel tid -> s_a ---
    {
        float w0 = bf2f(s_u[0*UST + tid]);
        float w1 = bf2f(s_u[1*UST + tid]);
        float w2 = bf2f(s_u[2*UST + tid]);
        float w3 = bf2f(s_u[3*UST + tid]);
        float w4 = bf2f(s_u[4*UST + tid]);
        float w5 = bf2f(s_u[5*UST + tid]);
        #pragma unroll
        for (int cr = 0; cr < TILE; ++cr) {
            float w6 = bf2f(s_u[(cr + 6)*UST + tid]);
            float s = cw.w * w3;
            s = fmaf(cw.x, w0 + w6, s);
            s = fmaf(cw.y, w1 + w5, s);
            s = fmaf(cw.z, w2 + w4, s);
            s_a[cr*UST + tid] = f2bf(s);
            w0 = w1; w1 = w2; w2 = w3; w3 = w4; w4 = w5; w5 = w6;
        }
    }
    __syncthreads();

    // --- P3: grouped mix (K=64) + in-reg gates -> v (s_u rows 0..15) ---
    {
        const int g = wvid;
        s16x8 a0 = *reinterpret_cast<const s16x8*>(&s_a[r_lo*UST + g*64 + kb*8]);
        s16x8 a1 = *reinterpret_cast<const s16x8*>(&s_a[r_lo*UST + g*64 + 32 + kb*8]);
        f32x4 acc[4];
        #pragma unroll
        for (int nt = 0; nt < 4; ++nt) acc[nt] = (f32x4){0.f,0.f,0.f,0.f};
        #pragma unroll
        for (int nt = 0; nt < 4; ++nt) {
            s16x8 b0 = *reinterpret_cast<const s16x8*>(
                mixw_b + (size_t)(((g*4 + nt)*2 + 0)*64 + lane)*8);
            acc[nt] = __builtin_amdgcn_mfma_f32_16x16x32_bf16(a0, b0, acc[nt], 0, 0, 0);
        }
        #pragma unroll
        for (int nt = 0; nt < 4; ++nt) {
            s16x8 b1 = *reinterpret_cast<const s16x8*>(
                mixw_b + (size_t)(((g*4 + nt)*2 + 1)*64 + lane)*8);
            acc[nt] = __builtin_amdgcn_mfma_f32_16x16x32_bf16(a1, b1, acc[nt], 0, 0, 0);
        }
        #pragma unroll
        for (int nt = 0; nt < 4; ++nt) {
            const int ocol = g*64 + nt*16 + r_lo;
            const float bia = mixb[ocol];
            #pragma unroll
            for (int r = 0; r < 4; ++r) {
                const int cr = kb*4 + r;
                unsigned short gu = (unsigned short)
                    ((gpk[nt*2 + (r >> 1)] >> ((r & 1)*16)) & 0xffffu);
                s_u[cr*UST + ocol] = f2bf((acc[nt][r] + bia) * bf2f(gu));
            }
        }
    }
    __syncthreads();

    // --- P4: out-proj (K=512) + bias + residual -> hout ---
    f32x4 acc4[2];
    #pragma unroll
    for (int c4 = 0; c4 < 2; ++c4) acc4[c4] = (f32x4){0.f,0.f,0.f,0.f};
    #pragma unroll
    for (int ks = 0; ks < 16; ++ks) {
        s16x8 a = *reinterpret_cast<const s16x8*>(&s_u[r_lo*UST + ks*32 + kb*8]);
        #pragma unroll
        for (int c4 = 0; c4 < 2; ++c4) {
            const int c4t = wvid*2 + c4;
            s16x8 bf = *reinterpret_cast<const s16x8*>(
                outw_b + (size_t)((ks*16 + c4t)*64 + lane)*8);
            acc4[c4] = __builtin_amdgcn_mfma_f32_16x16x32_bf16(a, bf, acc4[c4], 0, 0, 0);
        }
    }
    #pragma unroll
    for (int c4 = 0; c4 < 2; ++c4) {
        const int d = wvid*32 + c4*16 + r_lo;
        const float ob = outb[d];
        #pragma unroll
        for (int r = 0; r < 4; ++r) {
            const int cr = kb*4 + r;
            const int t = t0 + cr;
            if (t < NT)
                hout[(rowbase + t)*ND + d] = hres[c4][r] + acc4[c4][r] + ob;
        }
    }
}

// ---------------- final layernorm (in place) ----------------
__global__ __launch_bounds__(256) void kLN(float* __restrict__ h,
    const float* __restrict__ g, const float* __restrict__ bb)
{
    const int row = blockIdx.x;
    const int tid = threadIdx.x;
    const int lane = tid & 63, wvi = tid >> 6;
    __shared__ float2 part[4];
    float v = h[(size_t)row*ND + tid];
    float s = v, s2 = v*v;
    #pragma unroll
    for (int off = 32; off; off >>= 1) { s += __shfl_down(s, off); s2 += __shfl_down(s2, off); }
    if (lane == 0) part[wvi] = make_float2(s, s2);
    __syncthreads();
    float2 a0 = part[0], a1 = part[1], a2 = part[2], a3 = part[3];
    float S  = a0.x+a1.x+a2.x+a3.x;
    float S2 = a0.y+a1.y+a2.y+a3.y;
    float mu  = S*(1.0f/ND);
    float var = S2*(1.0f/ND) - mu*mu;
    float rs  = rsqrtf(var + EPSF);
    h[(size_t)row*ND + tid] = (v - mu)*rs*g[tid] + bb[tid];
}

extern "C" void kernel_launch(void* const* d_in, const int* in_sizes, int n_in,
                              void* d_out, int out_size, void* d_ws, size_t ws_size,
                              hipStream_t stream)
{
    const float* x    = (const float*)d_in[0];
    const float* w_in = (const float*)d_in[1];
    const float* b_in = (const float*)d_in[2];
    const float* pos  = (const float*)d_in[3];
    const float* ln_g = (const float*)d_in[4];
    const float* ln_b = (const float*)d_in[5];
    const float* inw  = (const float*)d_in[6];
    const float* inb  = (const float*)d_in[7];
    const float* dww  = (const float*)d_in[8];
    const float* mixw = (const float*)d_in[9];
    const float* mixb = (const float*)d_in[10];
    const float* outw = (const float*)d_in[11];
    const float* outb = (const float*)d_in[12];
    const float* olng = (const float*)d_in[13];
    const float* olnb = (const float*)d_in[14];

    float* hA = (float*)d_out;                         // h ping (final result here)
    float* hB = (float*)d_ws;                          // h pong
    unsigned short* outw_b = (unsigned short*)((char*)d_ws + (size_t)NPOS*ND*4);
    unsigned short* mixw_b = outw_b + 524288;          // L*D*H
    unsigned short* inw_b  = mixw_b + 131072;          // L*H*64 ; then L*1024*32
    float*          dws    = (float*)(inw_b + 131072); // L*512*4 symmetrized conv wts

    k_init<<<NPOS, 256, 0, stream>>>(x, w_in, b_in, pos, hA);
    k_prep<<<3104, 256, 0, stream>>>(outw, mixw, inw, dww, outw_b, mixw_b, inw_b, dws);
    for (int l = 0; l < 4; ++l) {
        const float* src = (l & 1) ? hB : hA;
        float*       dst = (l & 1) ? hA : hB;
        kL2<<<dim3(18, NB), 512, 0, stream>>>(src, dst,
            ln_g + l*ND, ln_b + l*ND,
            inw_b + (size_t)l*32768, inb + l*NHH,
            dws + (size_t)l*2048,
            mixw_b + (size_t)l*32768, mixb + l*NH,
            outw_b + (size_t)l*131072, outb + l*ND);
    }
    kLN<<<NPOS, 256, 0, stream>>>(hA, olng, olnb);
}

// Round 16
// 1181.936 us; speedup vs baseline: 2.4598x; 1.2038x over previous
//
#include <hip/hip_runtime.h>

#define NB 512
#define NT 274
#define ND 256
#define NH 512
#define NHH 1024
#define NPOS (NB*NT)
#define EPSF 1e-5f
#define TILE 16
#define HALO 22
#define YST 264    // y row stride (elems); 32 rows in s_a
#define UST 520    // u/uc/v row stride

typedef float f32x4 __attribute__((ext_vector_type(4)));
typedef unsigned int u32x4 __attribute__((ext_vector_type(4)));
typedef unsigned int u32x2 __attribute__((ext_vector_type(2)));
typedef short s16x8 __attribute__((ext_vector_type(8)));   // 8 bf16 = 4 VGPRs

__device__ __forceinline__ float bf2f(unsigned short s) {
    unsigned int u = ((unsigned int)s) << 16;
    float f; __builtin_memcpy(&f, &u, 4); return f;
}
__device__ __forceinline__ unsigned short f2bf(float f) {
    unsigned int u; __builtin_memcpy(&u, &f, 4);
    unsigned int r = u + 0x7FFFu + ((u >> 16) & 1u);   // round-to-nearest-even
    return (unsigned short)(r >> 16);
}

// ---------------- init: h = x[:,:,None]*w_in + b_in + pos ----------------
__global__ __launch_bounds__(256) void k_init(const float* __restrict__ x,
    const float* __restrict__ w_in, const float* __restrict__ b_in,
    const float* __restrict__ pos, float* __restrict__ h)
{
    int row = blockIdx.x;              // 0..NPOS-1  (b*NT + t)
    int d = threadIdx.x;
    int t = row % NT;
    float xv = x[row];
    h[(size_t)row*ND + d] = fmaf(xv, w_in[d], b_in[d] + pos[t*ND + d]);
}

// ------- prep: weights -> bf16 in MFMA-FRAGMENT ORDER; dww -> symmetrized f32 -------
__global__ __launch_bounds__(256) void k_prep(const float* __restrict__ outw,
    const float* __restrict__ mixw, const float* __restrict__ inw,
    const float* __restrict__ dww,
    unsigned short* __restrict__ ob, unsigned short* __restrict__ mb,
    unsigned short* __restrict__ iwb, float* __restrict__ dws)
{
    int i = blockIdx.x*256 + threadIdx.x;   // 0 .. 794623
    if (i < 524288) {
        // outw: per layer 256x512, instr = ks*16 + c4t
        int l = i >> 17, q = i & 131071;
        int j = q & 7, lane = (q >> 3) & 63, c4t = (q >> 9) & 15, ks = q >> 13;
        int src = (c4t*16 + (lane & 15))*512 + ks*32 + (lane >> 4)*8 + j;
        ob[i] = f2bf(outw[(size_t)l*131072 + src]);
    } else if (i < 655360) {
        // mixw: per layer 512x64, instr = (g*4+nt)*2 + half
        int v = i - 524288;
        int l = v >> 15, q = v & 32767;
        int j = q & 7, lane = (q >> 3) & 63, half = (q >> 9) & 1, gnt = q >> 10;
        int g = gnt >> 2, nt = gnt & 3;
        int src = (g*64 + nt*16 + (lane & 15))*64 + half*32 + (lane >> 4)*8 + j;
        mb[v] = f2bf(mixw[(size_t)l*32768 + src]);
    } else if (i < 786432) {
        // inw: per layer 1024x32, instr = g*8 + nt
        int v = i - 655360;
        int l = v >> 15, q = v & 32767;
        int j = q & 7, lane = (q >> 3) & 63, gnt = q >> 9;
        int g = gnt >> 3, nt = gnt & 7;
        int src = (g*128 + nt*16 + (lane & 15))*32 + (lane >> 4)*8 + j;
        iwb[v] = f2bf(inw[(size_t)l*32768 + src]);
    } else if (i < 794624) {
        // dws[l][c][k] = 0.5*(dww[k] + dww[6-k]), k=0..3
        int v = i - 786432;
        int l = v >> 11, c = (v >> 2) & 511, k = v & 3;
        const float* w = dww + (size_t)l*3584 + c*7;
        dws[v] = 0.5f*(w[k] + w[6-k]);
    }
}

// ======= kL2: whole layer fused, 512 thr / 8 waves, 39.8KB LDS =======
// (512,6): cap 80. All global loads issued IN the phase that consumes them
// (r15 lesson: prologue prefetch of P4's residual = 4-barrier live range ->
// spilled to scratch, +151MB HBM write. Short live ranges, no spill).
__global__ __launch_bounds__(512, 6) void kL2(const float* __restrict__ hin,
    float* __restrict__ hout,
    const float* __restrict__ lng, const float* __restrict__ lnb,
    const unsigned short* __restrict__ inw_b, const float* __restrict__ inb,
    const float* __restrict__ dws,
    const unsigned short* __restrict__ mixw_b, const float* __restrict__ mixb,
    const unsigned short* __restrict__ outw_b, const float* __restrict__ outb)
{
    const int b   = blockIdx.y;
    const int t0  = blockIdx.x * TILE;
    const int tid = threadIdx.x;            // 0..511
    const int lane = tid & 63, wvid = tid >> 6;   // 8 waves
    const int r_lo = lane & 15, kb = lane >> 4;
    const size_t rowbase = (size_t)b*NT;
    __shared__ __align__(16) unsigned short s_a[32*YST];   // y (32 rows) -> uc (16xUST)
    __shared__ __align__(16) unsigned short s_u[HALO*UST]; // u (22 rows) -> v (16 rows)

    // --- P0: load h halo rows t0-3..t0+18, LN -> y (bf16 in s_a) ---
    {
        const int r  = tid >> 4;            // 0..31 (rows >=22 zeroed)
        const int c0 = (tid & 15) * 16;
        const int t  = t0 - 3 + r;
        const bool vld = (r < HALO) && (t >= 0) && (t < NT);
        float vals[16];
        if (vld) {
            const float4* hp = reinterpret_cast<const float4*>(
                hin + (rowbase + t)*ND + c0);
            #pragma unroll
            for (int j = 0; j < 4; ++j) {
                float4 f = hp[j];
                vals[4*j+0]=f.x; vals[4*j+1]=f.y; vals[4*j+2]=f.z; vals[4*j+3]=f.w;
            }
        } else {
            #pragma unroll
            for (int j = 0; j < 16; ++j) vals[j] = 0.0f;
        }
        float s = 0.f, s2 = 0.f;
        #pragma unroll
        for (int j = 0; j < 16; ++j) { s += vals[j]; s2 += vals[j]*vals[j]; }
        #pragma unroll
        for (int off = 1; off < 16; off <<= 1) {   // 16 lanes per row, aligned
            s  += __shfl_xor(s, off);
            s2 += __shfl_xor(s2, off);
        }
        float mu  = s * (1.0f/ND);
        float var = s2 * (1.0f/ND) - mu*mu;
        float rs  = rsqrtf(var + EPSF);
        if (vld) {
            #pragma unroll
            for (int j = 0; j < 4; ++j) {
                float4 g4 = *reinterpret_cast<const float4*>(lng + c0 + 4*j);
                float4 b4 = *reinterpret_cast<const float4*>(lnb + c0 + 4*j);
                float y0 = (vals[4*j+0]-mu)*rs*g4.x + b4.x;
                float y1 = (vals[4*j+1]-mu)*rs*g4.y + b4.y;
                float y2 = (vals[4*j+2]-mu)*rs*g4.z + b4.z;
                float y3 = (vals[4*j+3]-mu)*rs*g4.w + b4.w;
                u32x2 pk;
                pk[0] = (unsigned)f2bf(y0) | ((unsigned)f2bf(y1) << 16);
                pk[1] = (unsigned)f2bf(y2) | ((unsigned)f2bf(y3) << 16);
                *reinterpret_cast<u32x2*>(&s_a[r*YST + c0 + 4*j]) = pk;
            }
        } else {
            #pragma unroll
            for (int j = 0; j < 4; ++j)
                *reinterpret_cast<u32x2*>(&s_a[r*YST + c0 + 4*j]) = (u32x2){0u,0u};
        }
    }
    __syncthreads();

    // --- P1: grouped in-proj. u over halo rows -> s_u; gates (central) -> regs ---
    unsigned int gpk[8];    // gates bf16-packed: [nt*2 + (r>>1)]
    {
        // u-part: wave = (rt = wvid>>2, g = wvid&3); 8 col-tiles (nt 0..7)
        const int rt = wvid >> 2, g = wvid & 3;
        s16x8 a = *reinterpret_cast<const s16x8*>(
            &s_a[(rt*16 + r_lo)*YST + g*32 + kb*8]);
        #pragma unroll
        for (int half = 0; half < 2; ++half) {
            f32x4 acc[4];
            #pragma unroll
            for (int q = 0; q < 4; ++q) acc[q] = (f32x4){0.f,0.f,0.f,0.f};
            #pragma unroll
            for (int q = 0; q < 4; ++q) {
                const int nt = half*4 + q;
                s16x8 bf = *reinterpret_cast<const s16x8*>(
                    inw_b + (size_t)((g*8 + nt)*64 + lane)*8);
                acc[q] = __builtin_amdgcn_mfma_f32_16x16x32_bf16(a, bf, acc[q], 0, 0, 0);
            }
            #pragma unroll
            for (int q = 0; q < 4; ++q) {
                const int nt = half*4 + q;
                const int ocol = g*128 + nt*16 + r_lo;
                const float bia = inb[ocol];
                #pragma unroll
                for (int r = 0; r < 4; ++r) {
                    const int hr = rt*16 + kb*4 + r;
                    if (hr < HALO) {
                        const int t = t0 - 3 + hr;
                        unsigned short val = 0;
                        if (t >= 0 && t < NT) {
                            float tv = acc[q][r] + bia;
                            float sg = 1.0f / (1.0f + __expf(-tv));
                            val = f2bf(tv * sg);
                        }
                        s_u[hr*UST + ocol] = val;
                    }
                }
            }
        }
        // gate-part: central rows (y rows 3..18); wave owns gate cols wvid*64..+63.
        s16x8 ag = *reinterpret_cast<const s16x8*>(
            &s_a[(3 + r_lo)*YST + 128 + (wvid >> 1)*32 + kb*8]);
        f32x4 gacc[4];
        #pragma unroll
        for (int nt = 0; nt < 4; ++nt) gacc[nt] = (f32x4){0.f,0.f,0.f,0.f};
        #pragma unroll
        for (int nt = 0; nt < 4; ++nt) {
            const int instr = (4 + (wvid >> 1))*8 + (wvid & 1)*4 + nt;
            s16x8 bf = *reinterpret_cast<const s16x8*>(
                inw_b + (size_t)(instr*64 + lane)*8);
            gacc[nt] = __builtin_amdgcn_mfma_f32_16x16x32_bf16(ag, bf, gacc[nt], 0, 0, 0);
        }
        #pragma unroll
        for (int nt = 0; nt < 4; ++nt) {
            const float bia = inb[512 + wvid*64 + nt*16 + r_lo];
            #pragma unroll
            for (int rp = 0; rp < 2; ++rp) {
                float s0 = 1.0f / (1.0f + __expf(-(gacc[nt][2*rp]   + bia)));
                float s1 = 1.0f / (1.0f + __expf(-(gacc[nt][2*rp+1] + bia)));
                gpk[nt*2 + rp] = (unsigned)f2bf(s0) | ((unsigned)f2bf(s1) << 16);
            }
        }
    }
    __syncthreads();

    // --- P2: symmetric conv (4 taps), rolling 7-reg window; channel tid -> s_a ---
    {
        const float4 cw = *reinterpret_cast<const float4*>(dws + tid*4);
        float w0 = bf2f(s_u[0*UST + tid]);
        float w1 = bf2f(s_u[1*UST + tid]);
        float w2 = bf2f(s_u[2*UST + tid]);
        float w3 = bf2f(s_u[3*UST + tid]);
        float w4 = bf2f(s_u[4*UST + tid]);
        float w5 = bf2f(s_u[5*UST + tid]);
        #pragma unroll
        for (int cr = 0; cr < TILE; ++cr) {
            float w6 = bf2f(s_u[(cr + 6)*UST + tid]);
            float s = cw.w * w3;
            s = fmaf(cw.x, w0 + w6, s);
            s = fmaf(cw.y, w1 + w5, s);
            s = fmaf(cw.z, w2 + w4, s);
            s_a[cr*UST + tid] = f2bf(s);
            w0 = w1; w1 = w2; w2 = w3; w3 = w4; w4 = w5; w5 = w6;
        }
    }
    __syncthreads();

    // --- P3: grouped mix (K=64) + in-reg gates -> v (s_u rows 0..15) ---
    {
        const int g = wvid;
        s16x8 a0 = *reinterpret_cast<const s16x8*>(&s_a[r_lo*UST + g*64 + kb*8]);
        s16x8 a1 = *reinterpret_cast<const s16x8*>(&s_a[r_lo*UST + g*64 + 32 + kb*8]);
        f32x4 acc[4];
        #pragma unroll
        for (int nt = 0; nt < 4; ++nt) acc[nt] = (f32x4){0.f,0.f,0.f,0.f};
        #pragma unroll
        for (int nt = 0; nt < 4; ++nt) {
            s16x8 b0 = *reinterpret_cast<const s16x8*>(
                mixw_b + (size_t)(((g*4 + nt)*2 + 0)*64 + lane)*8);
            acc[nt] = __builtin_amdgcn_mfma_f32_16x16x32_bf16(a0, b0, acc[nt], 0, 0, 0);
        }
        #pragma unroll
        for (int nt = 0; nt < 4; ++nt) {
            s16x8 b1 = *reinterpret_cast<const s16x8*>(
                mixw_b + (size_t)(((g*4 + nt)*2 + 1)*64 + lane)*8);
            acc[nt] = __builtin_amdgcn_mfma_f32_16x16x32_bf16(a1, b1, acc[nt], 0, 0, 0);
        }
        #pragma unroll
        for (int nt = 0; nt < 4; ++nt) {
            const int ocol = g*64 + nt*16 + r_lo;
            const float bia = mixb[ocol];
            #pragma unroll
            for (int r = 0; r < 4; ++r) {
                const int cr = kb*4 + r;
                unsigned short gu = (unsigned short)
                    ((gpk[nt*2 + (r >> 1)] >> ((r & 1)*16)) & 0xffffu);
                s_u[cr*UST + ocol] = f2bf((acc[nt][r] + bia) * bf2f(gu));
            }
        }
    }
    __syncthreads();

    // --- P4: residual load (issued first, hides under MFMAs) + out-proj -> hout ---
    float hres[2][4];
    #pragma unroll
    for (int c4 = 0; c4 < 2; ++c4) {
        const int d = wvid*32 + c4*16 + r_lo;
        #pragma unroll
        for (int r = 0; r < 4; ++r) {
            const int t = t0 + kb*4 + r;
            hres[c4][r] = (t < NT) ? hin[(rowbase + t)*ND + d] : 0.0f;
        }
    }
    f32x4 acc4[2];
    #pragma unroll
    for (int c4 = 0; c4 < 2; ++c4) acc4[c4] = (f32x4){0.f,0.f,0.f,0.f};
    #pragma unroll
    for (int ks = 0; ks < 16; ++ks) {
        s16x8 a = *reinterpret_cast<const s16x8*>(&s_u[r_lo*UST + ks*32 + kb*8]);
        #pragma unroll
        for (int c4 = 0; c4 < 2; ++c4) {
            const int c4t = wvid*2 + c4;
            s16x8 bf = *reinterpret_cast<const s16x8*>(
                outw_b + (size_t)((ks*16 + c4t)*64 + lane)*8);
            acc4[c4] = __builtin_amdgcn_mfma_f32_16x16x32_bf16(a, bf, acc4[c4], 0, 0, 0);
        }
    }
    #pragma unroll
    for (int c4 = 0; c4 < 2; ++c4) {
        const int d = wvid*32 + c4*16 + r_lo;
        const float ob = outb[d];
        #pragma unroll
        for (int r = 0; r < 4; ++r) {
            const int cr = kb*4 + r;
            const int t = t0 + cr;
            if (t < NT)
                hout[(rowbase + t)*ND + d] = hres[c4][r] + acc4[c4][r] + ob;
        }
    }
}

// ---------------- final layernorm (in place) ----------------
__global__ __launch_bounds__(256) void kLN(float* __restrict__ h,
    const float* __restrict__ g, const float* __restrict__ bb)
{
    const int row = blockIdx.x;
    const int tid = threadIdx.x;
    const int lane = tid & 63, wvi = tid >> 6;
    __shared__ float2 part[4];
    float v = h[(size_t)row*ND + tid];
    float s = v, s2 = v*v;
    #pragma unroll
    for (int off = 32; off; off >>= 1) { s += __shfl_down(s, off); s2 += __shfl_down(s2, off); }
    if (lane == 0) part[wvi] = make_float2(s, s2);
    __syncthreads();
    float2 a0 = part[0], a1 = part[1], a2 = part[2], a3 = part[3];
    float S  = a0.x+a1.x+a2.x+a3.x;
    float S2 = a0.y+a1.y+a2.y+a3.y;
    float mu  = S*(1.0f/ND);
    float var = S2*(1.0f/ND) - mu*mu;
    float rs  = rsqrtf(var + EPSF);
    h[(size_t)row*ND + tid] = (v - mu)*rs*g[tid] + bb[tid];
}

extern "C" void kernel_launch(void* const* d_in, const int* in_sizes, int n_in,
                              void* d_out, int out_size, void* d_ws, size_t ws_size,
                              hipStream_t stream)
{
    const float* x    = (const float*)d_in[0];
    const float* w_in = (const float*)d_in[1];
    const float* b_in = (const float*)d_in[2];
    const float* pos  = (const float*)d_in[3];
    const float* ln_g = (const float*)d_in[4];
    const float* ln_b = (const float*)d_in[5];
    const float* inw  = (const float*)d_in[6];
    const float* inb  = (const float*)d_in[7];
    const float* dww  = (const float*)d_in[8];
    const float* mixw = (const float*)d_in[9];
    const float* mixb = (const float*)d_in[10];
    const float* outw = (const float*)d_in[11];
    const float* outb = (const float*)d_in[12];
    const float* olng = (const float*)d_in[13];
    const float* olnb = (const float*)d_in[14];

    float* hA = (float*)d_out;                         // h ping (final result here)
    float* hB = (float*)d_ws;                          // h pong
    unsigned short* outw_b = (unsigned short*)((char*)d_ws + (size_t)NPOS*ND*4);
    unsigned short* mixw_b = outw_b + 524288;          // L*D*H
    unsigned short* inw_b  = mixw_b + 131072;          // L*H*64 ; then L*1024*32
    float*          dws    = (float*)(inw_b + 131072); // L*512*4 symmetrized conv wts

    k_init<<<NPOS, 256, 0, stream>>>(x, w_in, b_in, pos, hA);
    k_prep<<<3104, 256, 0, stream>>>(outw, mixw, inw, dww, outw_b, mixw_b, inw_b, dws);
    for (int l = 0; l < 4; ++l) {
        const float* src = (l & 1) ? hB : hA;
        float*       dst = (l & 1) ? hA : hB;
        kL2<<<dim3(18, NB), 512, 0, stream>>>(src, dst,
            ln_g + l*ND, ln_b + l*ND,
            inw_b + (size_t)l*32768, inb + l*NHH,
            dws + (size_t)l*2048,
            mixw_b + (size_t)l*32768, mixb + l*NH,
            outw_b + (size_t)l*131072, outb + l*ND);
    }
    kLN<<<NPOS, 256, 0, stream>>>(hA, olng, olnb);
}

// Round 17
// 1169.239 us; speedup vs baseline: 2.4865x; 1.0109x over previous
//
#include <hip/hip_runtime.h>
#include <hip/hip_bf16.h>

#define NB 512
#define NT 274
#define ND 256
#define NH 512
#define NHH 1024
#define NPOS (NB*NT)
#define EPSF 1e-5f
#define TILE 16
#define HALO 22
#define YST 264    // y row stride (elems); 32 rows in s_a
#define UST 520    // u/uc/v row stride

typedef float f32x4 __attribute__((ext_vector_type(4)));
typedef float f32x2 __attribute__((ext_vector_type(2)));
typedef unsigned int u32x4 __attribute__((ext_vector_type(4)));
typedef unsigned int u32x2 __attribute__((ext_vector_type(2)));
typedef short s16x8 __attribute__((ext_vector_type(8)));   // 8 bf16 = 4 VGPRs

__device__ __forceinline__ float bf2f(unsigned short s) {
    unsigned int u = ((unsigned int)s) << 16;
    float f; __builtin_memcpy(&f, &u, 4); return f;
}
// native conversion (RNE) -> compiler emits HW cvt, not 5-op bit math
__device__ __forceinline__ unsigned short f2bf(float f) {
    __hip_bfloat16 b = __float2bfloat16(f);
    unsigned short r; __builtin_memcpy(&r, &b, 2); return r;
}
__device__ __forceinline__ unsigned int f2bf2(float lo, float hi) {
    return (unsigned)f2bf(lo) | ((unsigned)f2bf(hi) << 16);
}

// ---------------- init: h = x[:,:,None]*w_in + b_in + pos ----------------
__global__ __launch_bounds__(256) void k_init(const float* __restrict__ x,
    const float* __restrict__ w_in, const float* __restrict__ b_in,
    const float* __restrict__ pos, float* __restrict__ h)
{
    int row = blockIdx.x;              // 0..NPOS-1  (b*NT + t)
    int d = threadIdx.x;
    int t = row % NT;
    float xv = x[row];
    h[(size_t)row*ND + d] = fmaf(xv, w_in[d], b_in[d] + pos[t*ND + d]);
}

// ------- prep: weights -> bf16 in MFMA-FRAGMENT ORDER; dww -> symmetrized f32 -------
__global__ __launch_bounds__(256) void k_prep(const float* __restrict__ outw,
    const float* __restrict__ mixw, const float* __restrict__ inw,
    const float* __restrict__ dww,
    unsigned short* __restrict__ ob, unsigned short* __restrict__ mb,
    unsigned short* __restrict__ iwb, float* __restrict__ dws)
{
    int i = blockIdx.x*256 + threadIdx.x;   // 0 .. 794623
    if (i < 524288) {
        // outw: per layer 256x512, instr = ks*16 + c4t
        int l = i >> 17, q = i & 131071;
        int j = q & 7, lane = (q >> 3) & 63, c4t = (q >> 9) & 15, ks = q >> 13;
        int src = (c4t*16 + (lane & 15))*512 + ks*32 + (lane >> 4)*8 + j;
        ob[i] = f2bf(outw[(size_t)l*131072 + src]);
    } else if (i < 655360) {
        // mixw: per layer 512x64, instr = (g*4+nt)*2 + half
        int v = i - 524288;
        int l = v >> 15, q = v & 32767;
        int j = q & 7, lane = (q >> 3) & 63, half = (q >> 9) & 1, gnt = q >> 10;
        int g = gnt >> 2, nt = gnt & 3;
        int src = (g*64 + nt*16 + (lane & 15))*64 + half*32 + (lane >> 4)*8 + j;
        mb[v] = f2bf(mixw[(size_t)l*32768 + src]);
    } else if (i < 786432) {
        // inw: per layer 1024x32, instr = g*8 + nt
        int v = i - 655360;
        int l = v >> 15, q = v & 32767;
        int j = q & 7, lane = (q >> 3) & 63, gnt = q >> 9;
        int g = gnt >> 3, nt = gnt & 7;
        int src = (g*128 + nt*16 + (lane & 15))*32 + (lane >> 4)*8 + j;
        iwb[v] = f2bf(inw[(size_t)l*32768 + src]);
    } else if (i < 794624) {
        // dws[l][c][k] = 0.5*(dww[k] + dww[6-k]), k=0..3
        int v = i - 786432;
        int l = v >> 11, c = (v >> 2) & 511, k = v & 3;
        const float* w = dww + (size_t)l*3584 + c*7;
        dws[v] = 0.5f*(w[k] + w[6-k]);
    }
}

// ======= kL2: whole layer fused, 512 thr / 8 waves, 39.8KB LDS =======
// (512,6): cap 80, no spill (r15/r16 lesson: loads live only in their phase).
// r17: native bf16 cvt, packed-f32 conv (row pairs), rotated P0 stores.
__global__ __launch_bounds__(512, 6) void kL2(const float* __restrict__ hin,
    float* __restrict__ hout,
    const float* __restrict__ lng, const float* __restrict__ lnb,
    const unsigned short* __restrict__ inw_b, const float* __restrict__ inb,
    const float* __restrict__ dws,
    const unsigned short* __restrict__ mixw_b, const float* __restrict__ mixb,
    const unsigned short* __restrict__ outw_b, const float* __restrict__ outb)
{
    const int b   = blockIdx.y;
    const int t0  = blockIdx.x * TILE;
    const int tid = threadIdx.x;            // 0..511
    const int lane = tid & 63, wvid = tid >> 6;   // 8 waves
    const int r_lo = lane & 15, kb = lane >> 4;
    const size_t rowbase = (size_t)b*NT;
    __shared__ __align__(16) unsigned short s_a[32*YST];   // y (32 rows) -> uc (16xUST)
    __shared__ __align__(16) unsigned short s_u[HALO*UST]; // u (22 rows) -> v (16 rows)

    // --- P0: load h halo rows t0-3..t0+18, LN -> y (bf16 in s_a) ---
    {
        const int r  = tid >> 4;            // 0..31 (rows >=22 zeroed)
        const int c0 = (tid & 15) * 16;
        const int t  = t0 - 3 + r;
        const bool vld = (r < HALO) && (t >= 0) && (t < NT);
        float vals[16];
        if (vld) {
            const float4* hp = reinterpret_cast<const float4*>(
                hin + (rowbase + t)*ND + c0);
            #pragma unroll
            for (int j = 0; j < 4; ++j) {
                float4 f = hp[j];
                vals[4*j+0]=f.x; vals[4*j+1]=f.y; vals[4*j+2]=f.z; vals[4*j+3]=f.w;
            }
        } else {
            #pragma unroll
            for (int j = 0; j < 16; ++j) vals[j] = 0.0f;
        }
        float s = 0.f, s2 = 0.f;
        #pragma unroll
        for (int j = 0; j < 16; ++j) { s += vals[j]; s2 += vals[j]*vals[j]; }
        #pragma unroll
        for (int off = 1; off < 16; off <<= 1) {   // 16 lanes per row, aligned
            s  += __shfl_xor(s, off);
            s2 += __shfl_xor(s2, off);
        }
        float mu  = s * (1.0f/ND);
        float var = s2 * (1.0f/ND) - mu*mu;
        float rs  = rsqrtf(var + EPSF);
        u32x2 pk[4];
        if (vld) {
            #pragma unroll
            for (int j = 0; j < 4; ++j) {
                float4 g4 = *reinterpret_cast<const float4*>(lng + c0 + 4*j);
                float4 b4 = *reinterpret_cast<const float4*>(lnb + c0 + 4*j);
                float y0 = (vals[4*j+0]-mu)*rs*g4.x + b4.x;
                float y1 = (vals[4*j+1]-mu)*rs*g4.y + b4.y;
                float y2 = (vals[4*j+2]-mu)*rs*g4.z + b4.z;
                float y3 = (vals[4*j+3]-mu)*rs*g4.w + b4.w;
                pk[j][0] = f2bf2(y0, y1);
                pk[j][1] = f2bf2(y2, y3);
            }
        } else {
            #pragma unroll
            for (int j = 0; j < 4; ++j) pk[j] = (u32x2){0u,0u};
        }
        // rotated store order: lanes start at different chunk -> fewer bank conflicts
        const int rot = tid & 3;
        #pragma unroll
        for (int j0 = 0; j0 < 4; ++j0) {
            const int j = (j0 + rot) & 3;
            *reinterpret_cast<u32x2*>(&s_a[r*YST + c0 + 4*j]) = pk[j];
        }
    }
    __syncthreads();

    // --- P1: grouped in-proj. u over halo rows -> s_u; gates (central) -> regs ---
    unsigned int gpk[8];    // gates bf16-packed: [nt*2 + (r>>1)]
    {
        // u-part: wave = (rt = wvid>>2, g = wvid&3); 8 col-tiles (nt 0..7)
        const int rt = wvid >> 2, g = wvid & 3;
        s16x8 a = *reinterpret_cast<const s16x8*>(
            &s_a[(rt*16 + r_lo)*YST + g*32 + kb*8]);
        #pragma unroll
        for (int half = 0; half < 2; ++half) {
            f32x4 acc[4];
            #pragma unroll
            for (int q = 0; q < 4; ++q) acc[q] = (f32x4){0.f,0.f,0.f,0.f};
            #pragma unroll
            for (int q = 0; q < 4; ++q) {
                const int nt = half*4 + q;
                s16x8 bf = *reinterpret_cast<const s16x8*>(
                    inw_b + (size_t)((g*8 + nt)*64 + lane)*8);
                acc[q] = __builtin_amdgcn_mfma_f32_16x16x32_bf16(a, bf, acc[q], 0, 0, 0);
            }
            #pragma unroll
            for (int q = 0; q < 4; ++q) {
                const int nt = half*4 + q;
                const int ocol = g*128 + nt*16 + r_lo;
                const float bia = inb[ocol];
                #pragma unroll
                for (int r = 0; r < 4; ++r) {
                    const int hr = rt*16 + kb*4 + r;
                    if (hr < HALO) {
                        const int t = t0 - 3 + hr;
                        unsigned short val = 0;
                        if (t >= 0 && t < NT) {
                            float tv = acc[q][r] + bia;
                            float sg = 1.0f / (1.0f + __expf(-tv));
                            val = f2bf(tv * sg);
                        }
                        s_u[hr*UST + ocol] = val;
                    }
                }
            }
        }
        // gate-part: central rows (y rows 3..18); wave owns gate cols wvid*64..+63.
        s16x8 ag = *reinterpret_cast<const s16x8*>(
            &s_a[(3 + r_lo)*YST + 128 + (wvid >> 1)*32 + kb*8]);
        f32x4 gacc[4];
        #pragma unroll
        for (int nt = 0; nt < 4; ++nt) gacc[nt] = (f32x4){0.f,0.f,0.f,0.f};
        #pragma unroll
        for (int nt = 0; nt < 4; ++nt) {
            const int instr = (4 + (wvid >> 1))*8 + (wvid & 1)*4 + nt;
            s16x8 bf = *reinterpret_cast<const s16x8*>(
                inw_b + (size_t)(instr*64 + lane)*8);
            gacc[nt] = __builtin_amdgcn_mfma_f32_16x16x32_bf16(ag, bf, gacc[nt], 0, 0, 0);
        }
        #pragma unroll
        for (int nt = 0; nt < 4; ++nt) {
            const float bia = inb[512 + wvid*64 + nt*16 + r_lo];
            #pragma unroll
            for (int rp = 0; rp < 2; ++rp) {
                float s0 = 1.0f / (1.0f + __expf(-(gacc[nt][2*rp]   + bia)));
                float s1 = 1.0f / (1.0f + __expf(-(gacc[nt][2*rp+1] + bia)));
                gpk[nt*2 + rp] = f2bf2(s0, s1);
            }
        }
    }
    __syncthreads();

    // --- P2: symmetric conv (4 taps), PACKED row-pairs (cr, cr+8) via f32x2 ---
    {
        const float4 cw = *reinterpret_cast<const float4*>(dws + tid*4);
        f32x2 w0, w1, w2, w3, w4, w5;
        w0 = (f32x2){bf2f(s_u[0*UST + tid]), bf2f(s_u[ 8*UST + tid])};
        w1 = (f32x2){bf2f(s_u[1*UST + tid]), bf2f(s_u[ 9*UST + tid])};
        w2 = (f32x2){bf2f(s_u[2*UST + tid]), bf2f(s_u[10*UST + tid])};
        w3 = (f32x2){bf2f(s_u[3*UST + tid]), bf2f(s_u[11*UST + tid])};
        w4 = (f32x2){bf2f(s_u[4*UST + tid]), bf2f(s_u[12*UST + tid])};
        w5 = (f32x2){bf2f(s_u[5*UST + tid]), bf2f(s_u[13*UST + tid])};
        #pragma unroll
        for (int cr = 0; cr < 8; ++cr) {
            f32x2 w6 = (f32x2){bf2f(s_u[(cr + 6)*UST + tid]),
                               bf2f(s_u[(cr + 14)*UST + tid])};
            f32x2 s = cw.w * w3;
            s += cw.x * (w0 + w6);
            s += cw.y * (w1 + w5);
            s += cw.z * (w2 + w4);
            s_a[cr*UST + tid]       = f2bf(s[0]);
            s_a[(cr + 8)*UST + tid] = f2bf(s[1]);
            w0 = w1; w1 = w2; w2 = w3; w3 = w4; w4 = w5; w5 = w6;
        }
    }
    __syncthreads();

    // --- P3: grouped mix (K=64) + in-reg gates -> v (s_u rows 0..15) ---
    {
        const int g = wvid;
        s16x8 a0 = *reinterpret_cast<const s16x8*>(&s_a[r_lo*UST + g*64 + kb*8]);
        s16x8 a1 = *reinterpret_cast<const s16x8*>(&s_a[r_lo*UST + g*64 + 32 + kb*8]);
        f32x4 acc[4];
        #pragma unroll
        for (int nt = 0; nt < 4; ++nt) acc[nt] = (f32x4){0.f,0.f,0.f,0.f};
        #pragma unroll
        for (int nt = 0; nt < 4; ++nt) {
            s16x8 b0 = *reinterpret_cast<const s16x8*>(
                mixw_b + (size_t)(((g*4 + nt)*2 + 0)*64 + lane)*8);
            acc[nt] = __builtin_amdgcn_mfma_f32_16x16x32_bf16(a0, b0, acc[nt], 0, 0, 0);
        }
        #pragma unroll
        for (int nt = 0; nt < 4; ++nt) {
            s16x8 b1 = *reinterpret_cast<const s16x8*>(
                mixw_b + (size_t)(((g*4 + nt)*2 + 1)*64 + lane)*8);
            acc[nt] = __builtin_amdgcn_mfma_f32_16x16x32_bf16(a1, b1, acc[nt], 0, 0, 0);
        }
        #pragma unroll
        for (int nt = 0; nt < 4; ++nt) {
            const int ocol = g*64 + nt*16 + r_lo;
            const float bia = mixb[ocol];
            #pragma unroll
            for (int r = 0; r < 4; ++r) {
                const int cr = kb*4 + r;
                unsigned short gu = (unsigned short)
                    ((gpk[nt*2 + (r >> 1)] >> ((r & 1)*16)) & 0xffffu);
                s_u[cr*UST + ocol] = f2bf((acc[nt][r] + bia) * bf2f(gu));
            }
        }
    }
    __syncthreads();

    // --- P4: residual load (issued first, hides under MFMAs) + out-proj -> hout ---
    float hres[2][4];
    #pragma unroll
    for (int c4 = 0; c4 < 2; ++c4) {
        const int d = wvid*32 + c4*16 + r_lo;
        #pragma unroll
        for (int r = 0; r < 4; ++r) {
            const int t = t0 + kb*4 + r;
            hres[c4][r] = (t < NT) ? hin[(rowbase + t)*ND + d] : 0.0f;
        }
    }
    f32x4 acc4[2];
    #pragma unroll
    for (int c4 = 0; c4 < 2; ++c4) acc4[c4] = (f32x4){0.f,0.f,0.f,0.f};
    #pragma unroll
    for (int ks = 0; ks < 16; ++ks) {
        s16x8 a = *reinterpret_cast<const s16x8*>(&s_u[r_lo*UST + ks*32 + kb*8]);
        #pragma unroll
        for (int c4 = 0; c4 < 2; ++c4) {
            const int c4t = wvid*2 + c4;
            s16x8 bf = *reinterpret_cast<const s16x8*>(
                outw_b + (size_t)((ks*16 + c4t)*64 + lane)*8);
            acc4[c4] = __builtin_amdgcn_mfma_f32_16x16x32_bf16(a, bf, acc4[c4], 0, 0, 0);
        }
    }
    #pragma unroll
    for (int c4 = 0; c4 < 2; ++c4) {
        const int d = wvid*32 + c4*16 + r_lo;
        const float ob = outb[d];
        #pragma unroll
        for (int r = 0; r < 4; ++r) {
            const int cr = kb*4 + r;
            const int t = t0 + cr;
            if (t < NT)
                hout[(rowbase + t)*ND + d] = hres[c4][r] + acc4[c4][r] + ob;
        }
    }
}

// ---------------- final layernorm (in place) ----------------
__global__ __launch_bounds__(256) void kLN(float* __restrict__ h,
    const float* __restrict__ g, const float* __restrict__ bb)
{
    const int row = blockIdx.x;
    const int tid = threadIdx.x;
    const int lane = tid & 63, wvi = tid >> 6;
    __shared__ float2 part[4];
    float v = h[(size_t)row*ND + tid];
    float s = v, s2 = v*v;
    #pragma unroll
    for (int off = 32; off; off >>= 1) { s += __shfl_down(s, off); s2 += __shfl_down(s2, off); }
    if (lane == 0) part[wvi] = make_float2(s, s2);
    __syncthreads();
    float2 a0 = part[0], a1 = part[1], a2 = part[2], a3 = part[3];
    float S  = a0.x+a1.x+a2.x+a3.x;
    float S2 = a0.y+a1.y+a2.y+a3.y;
    float mu  = S*(1.0f/ND);
    float var = S2*(1.0f/ND) - mu*mu;
    float rs  = rsqrtf(var + EPSF);
    h[(size_t)row*ND + tid] = (v - mu)*rs*g[tid] + bb[tid];
}

extern "C" void kernel_launch(void* const* d_in, const int* in_sizes, int n_in,
                              void* d_out, int out_size, void* d_ws, size_t ws_size,
                              hipStream_t stream)
{
    const float* x    = (const float*)d_in[0];
    const float* w_in = (const float*)d_in[1];
    const float* b_in = (const float*)d_in[2];
    const float* pos  = (const float*)d_in[3];
    const float* ln_g = (const float*)d_in[4];
    const float* ln_b = (const float*)d_in[5];
    const float* inw  = (const float*)d_in[6];
    const float* inb  = (const float*)d_in[7];
    const float* dww  = (const float*)d_in[8];
    const float* mixw = (const float*)d_in[9];
    const float* mixb = (const float*)d_in[10];
    const float* outw = (const float*)d_in[11];
    const float* outb = (const float*)d_in[12];
    const float* olng = (const float*)d_in[13];
    const float* olnb = (const float*)d_in[14];

    float* hA = (float*)d_out;                         // h ping (final result here)
    float* hB = (float*)d_ws;                          // h pong
    unsigned short* outw_b = (unsigned short*)((char*)d_ws + (size_t)NPOS*ND*4);
    unsigned short* mixw_b = outw_b + 524288;          // L*D*H
    unsigned short* inw_b  = mixw_b + 131072;          // L*H*64 ; then L*1024*32
    float*          dws    = (float*)(inw_b + 131072); // L*512*4 symmetrized conv wts

    k_init<<<NPOS, 256, 0, stream>>>(x, w_in, b_in, pos, hA);
    k_prep<<<3104, 256, 0, stream>>>(outw, mixw, inw, dww, outw_b, mixw_b, inw_b, dws);
    for (int l = 0; l < 4; ++l) {
        const float* src = (l & 1) ? hB : hA;
        float*       dst = (l & 1) ? hA : hB;
        kL2<<<dim3(18, NB), 512, 0, stream>>>(src, dst,
            ln_g + l*ND, ln_b + l*ND,
            inw_b + (size_t)l*32768, inb + l*NHH,
            dws + (size_t)l*2048,
            mixw_b + (size_t)l*32768, mixb + l*NH,
            outw_b + (size_t)l*131072, outb + l*ND);
    }
    kLN<<<NPOS, 256, 0, stream>>>(hA, olng, olnb);
}

// Round 18
// 1097.502 us; speedup vs baseline: 2.6490x; 1.0654x over previous
//
#include <hip/hip_runtime.h>
#include <hip/hip_bf16.h>

#define NB 512
#define NT 274
#define ND 256
#define NH 512
#define NHH 1024
#define NPOS (NB*NT)
#define EPSF 1e-5f
#define TILE 16
#define HALO 22
#define YST 264    // y row stride (elems); 32 rows in s_a
#define UST 520    // u/uc/v row stride

typedef float f32x4 __attribute__((ext_vector_type(4)));
typedef float f32x2 __attribute__((ext_vector_type(2)));
typedef unsigned int u32x4 __attribute__((ext_vector_type(4)));
typedef unsigned int u32x2 __attribute__((ext_vector_type(2)));
typedef short s16x8 __attribute__((ext_vector_type(8)));   // 8 bf16 = 4 VGPRs

__device__ __forceinline__ float bf2f(unsigned short s) {
    unsigned int u = ((unsigned int)s) << 16;
    float f; __builtin_memcpy(&f, &u, 4); return f;
}
// native conversion (RNE) -> compiler emits HW cvt / fuses pairs to cvt_pk
__device__ __forceinline__ unsigned short f2bf(float f) {
    __hip_bfloat16 b = __float2bfloat16(f);
    unsigned short r; __builtin_memcpy(&r, &b, 2); return r;
}
__device__ __forceinline__ unsigned int f2bf2(float lo, float hi) {
    return (unsigned)f2bf(lo) | ((unsigned)f2bf(hi) << 16);
}

// ---------------- init: h = x[:,:,None]*w_in + b_in + pos ----------------
__global__ __launch_bounds__(256) void k_init(const float* __restrict__ x,
    const float* __restrict__ w_in, const float* __restrict__ b_in,
    const float* __restrict__ pos, float* __restrict__ h)
{
    int row = blockIdx.x;              // 0..NPOS-1  (b*NT + t)
    int d = threadIdx.x;
    int t = row % NT;
    float xv = x[row];
    h[(size_t)row*ND + d] = fmaf(xv, w_in[d], b_in[d] + pos[t*ND + d]);
}

// ------- prep: weights -> bf16 in MFMA-FRAGMENT ORDER; dww -> symmetrized f32 -------
__global__ __launch_bounds__(256) void k_prep(const float* __restrict__ outw,
    const float* __restrict__ mixw, const float* __restrict__ inw,
    const float* __restrict__ dww,
    unsigned short* __restrict__ ob, unsigned short* __restrict__ mb,
    unsigned short* __restrict__ iwb, float* __restrict__ dws)
{
    int i = blockIdx.x*256 + threadIdx.x;   // 0 .. 794623
    if (i < 524288) {
        // outw: per layer 256x512, instr = ks*16 + c4t
        int l = i >> 17, q = i & 131071;
        int j = q & 7, lane = (q >> 3) & 63, c4t = (q >> 9) & 15, ks = q >> 13;
        int src = (c4t*16 + (lane & 15))*512 + ks*32 + (lane >> 4)*8 + j;
        ob[i] = f2bf(outw[(size_t)l*131072 + src]);
    } else if (i < 655360) {
        // mixw: per layer 512x64, instr = (g*4+nt)*2 + half
        int v = i - 524288;
        int l = v >> 15, q = v & 32767;
        int j = q & 7, lane = (q >> 3) & 63, half = (q >> 9) & 1, gnt = q >> 10;
        int g = gnt >> 2, nt = gnt & 3;
        int src = (g*64 + nt*16 + (lane & 15))*64 + half*32 + (lane >> 4)*8 + j;
        mb[v] = f2bf(mixw[(size_t)l*32768 + src]);
    } else if (i < 786432) {
        // inw: per layer 1024x32, instr = g*8 + nt
        int v = i - 655360;
        int l = v >> 15, q = v & 32767;
        int j = q & 7, lane = (q >> 3) & 63, gnt = q >> 9;
        int g = gnt >> 3, nt = gnt & 7;
        int src = (g*128 + nt*16 + (lane & 15))*32 + (lane >> 4)*8 + j;
        iwb[v] = f2bf(inw[(size_t)l*32768 + src]);
    } else if (i < 794624) {
        // dws[l][c][k] = 0.5*(dww[k] + dww[6-k]), k=0..3
        int v = i - 786432;
        int l = v >> 11, c = (v >> 2) & 511, k = v & 3;
        const float* w = dww + (size_t)l*3584 + c*7;
        dws[v] = 0.5f*(w[k] + w[6-k]);
    }
}

// ======= kL2: whole layer fused, 512 thr / 8 waves, 39.8KB LDS =======
// (512,8): VGPR cap 64 (usage ~40, no spill) -> 4 blocks/CU, 32 waves.
// r18: raised occupancy floor (r17 ran at 65% on a VALU-bound kernel);
// reverted r17's store rotation (bank conflicts rose 8.26M->9.44M).
__global__ __launch_bounds__(512, 8) void kL2(const float* __restrict__ hin,
    float* __restrict__ hout,
    const float* __restrict__ lng, const float* __restrict__ lnb,
    const unsigned short* __restrict__ inw_b, const float* __restrict__ inb,
    const float* __restrict__ dws,
    const unsigned short* __restrict__ mixw_b, const float* __restrict__ mixb,
    const unsigned short* __restrict__ outw_b, const float* __restrict__ outb)
{
    const int b   = blockIdx.y;
    const int t0  = blockIdx.x * TILE;
    const int tid = threadIdx.x;            // 0..511
    const int lane = tid & 63, wvid = tid >> 6;   // 8 waves
    const int r_lo = lane & 15, kb = lane >> 4;
    const size_t rowbase = (size_t)b*NT;
    __shared__ __align__(16) unsigned short s_a[32*YST];   // y (32 rows) -> uc (16xUST)
    __shared__ __align__(16) unsigned short s_u[HALO*UST]; // u (22 rows) -> v (16 rows)

    // --- P0: load h halo rows t0-3..t0+18, LN -> y (bf16 in s_a) ---
    {
        const int r  = tid >> 4;            // 0..31 (rows >=22 zeroed)
        const int c0 = (tid & 15) * 16;
        const int t  = t0 - 3 + r;
        const bool vld = (r < HALO) && (t >= 0) && (t < NT);
        float vals[16];
        if (vld) {
            const float4* hp = reinterpret_cast<const float4*>(
                hin + (rowbase + t)*ND + c0);
            #pragma unroll
            for (int j = 0; j < 4; ++j) {
                float4 f = hp[j];
                vals[4*j+0]=f.x; vals[4*j+1]=f.y; vals[4*j+2]=f.z; vals[4*j+3]=f.w;
            }
        } else {
            #pragma unroll
            for (int j = 0; j < 16; ++j) vals[j] = 0.0f;
        }
        float s = 0.f, s2 = 0.f;
        #pragma unroll
        for (int j = 0; j < 16; ++j) { s += vals[j]; s2 += vals[j]*vals[j]; }
        #pragma unroll
        for (int off = 1; off < 16; off <<= 1) {   // 16 lanes per row, aligned
            s  += __shfl_xor(s, off);
            s2 += __shfl_xor(s2, off);
        }
        float mu  = s * (1.0f/ND);
        float var = s2 * (1.0f/ND) - mu*mu;
        float rs  = rsqrtf(var + EPSF);
        if (vld) {
            #pragma unroll
            for (int j = 0; j < 4; ++j) {
                float4 g4 = *reinterpret_cast<const float4*>(lng + c0 + 4*j);
                float4 b4 = *reinterpret_cast<const float4*>(lnb + c0 + 4*j);
                float y0 = (vals[4*j+0]-mu)*rs*g4.x + b4.x;
                float y1 = (vals[4*j+1]-mu)*rs*g4.y + b4.y;
                float y2 = (vals[4*j+2]-mu)*rs*g4.z + b4.z;
                float y3 = (vals[4*j+3]-mu)*rs*g4.w + b4.w;
                u32x2 pk;
                pk[0] = f2bf2(y0, y1);
                pk[1] = f2bf2(y2, y3);
                *reinterpret_cast<u32x2*>(&s_a[r*YST + c0 + 4*j]) = pk;
            }
        } else {
            #pragma unroll
            for (int j = 0; j < 4; ++j)
                *reinterpret_cast<u32x2*>(&s_a[r*YST + c0 + 4*j]) = (u32x2){0u,0u};
        }
    }
    __syncthreads();

    // --- P1: grouped in-proj. u over halo rows -> s_u; gates (central) -> regs ---
    unsigned int gpk[8];    // gates bf16-packed: [nt*2 + (r>>1)]
    {
        // u-part: wave = (rt = wvid>>2, g = wvid&3); 8 col-tiles (nt 0..7)
        const int rt = wvid >> 2, g = wvid & 3;
        s16x8 a = *reinterpret_cast<const s16x8*>(
            &s_a[(rt*16 + r_lo)*YST + g*32 + kb*8]);
        #pragma unroll
        for (int half = 0; half < 2; ++half) {
            f32x4 acc[4];
            #pragma unroll
            for (int q = 0; q < 4; ++q) acc[q] = (f32x4){0.f,0.f,0.f,0.f};
            #pragma unroll
            for (int q = 0; q < 4; ++q) {
                const int nt = half*4 + q;
                s16x8 bf = *reinterpret_cast<const s16x8*>(
                    inw_b + (size_t)((g*8 + nt)*64 + lane)*8);
                acc[q] = __builtin_amdgcn_mfma_f32_16x16x32_bf16(a, bf, acc[q], 0, 0, 0);
            }
            #pragma unroll
            for (int q = 0; q < 4; ++q) {
                const int nt = half*4 + q;
                const int ocol = g*128 + nt*16 + r_lo;
                const float bia = inb[ocol];
                #pragma unroll
                for (int r = 0; r < 4; ++r) {
                    const int hr = rt*16 + kb*4 + r;
                    if (hr < HALO) {
                        const int t = t0 - 3 + hr;
                        unsigned short val = 0;
                        if (t >= 0 && t < NT) {
                            float tv = acc[q][r] + bia;
                            float sg = 1.0f / (1.0f + __expf(-tv));
                            val = f2bf(tv * sg);
                        }
                        s_u[hr*UST + ocol] = val;
                    }
                }
            }
        }
        // gate-part: central rows (y rows 3..18); wave owns gate cols wvid*64..+63.
        s16x8 ag = *reinterpret_cast<const s16x8*>(
            &s_a[(3 + r_lo)*YST + 128 + (wvid >> 1)*32 + kb*8]);
        f32x4 gacc[4];
        #pragma unroll
        for (int nt = 0; nt < 4; ++nt) gacc[nt] = (f32x4){0.f,0.f,0.f,0.f};
        #pragma unroll
        for (int nt = 0; nt < 4; ++nt) {
            const int instr = (4 + (wvid >> 1))*8 + (wvid & 1)*4 + nt;
            s16x8 bf = *reinterpret_cast<const s16x8*>(
                inw_b + (size_t)(instr*64 + lane)*8);
            gacc[nt] = __builtin_amdgcn_mfma_f32_16x16x32_bf16(ag, bf, gacc[nt], 0, 0, 0);
        }
        #pragma unroll
        for (int nt = 0; nt < 4; ++nt) {
            const float bia = inb[512 + wvid*64 + nt*16 + r_lo];
            #pragma unroll
            for (int rp = 0; rp < 2; ++rp) {
                float s0 = 1.0f / (1.0f + __expf(-(gacc[nt][2*rp]   + bia)));
                float s1 = 1.0f / (1.0f + __expf(-(gacc[nt][2*rp+1] + bia)));
                gpk[nt*2 + rp] = f2bf2(s0, s1);
            }
        }
    }
    __syncthreads();

    // --- P2: symmetric conv (4 taps), PACKED row-pairs (cr, cr+8) via f32x2 ---
    {
        const float4 cw = *reinterpret_cast<const float4*>(dws + tid*4);
        f32x2 w0, w1, w2, w3, w4, w5;
        w0 = (f32x2){bf2f(s_u[0*UST + tid]), bf2f(s_u[ 8*UST + tid])};
        w1 = (f32x2){bf2f(s_u[1*UST + tid]), bf2f(s_u[ 9*UST + tid])};
        w2 = (f32x2){bf2f(s_u[2*UST + tid]), bf2f(s_u[10*UST + tid])};
        w3 = (f32x2){bf2f(s_u[3*UST + tid]), bf2f(s_u[11*UST + tid])};
        w4 = (f32x2){bf2f(s_u[4*UST + tid]), bf2f(s_u[12*UST + tid])};
        w5 = (f32x2){bf2f(s_u[5*UST + tid]), bf2f(s_u[13*UST + tid])};
        #pragma unroll
        for (int cr = 0; cr < 8; ++cr) {
            f32x2 w6 = (f32x2){bf2f(s_u[(cr + 6)*UST + tid]),
                               bf2f(s_u[(cr + 14)*UST + tid])};
            f32x2 s = cw.w * w3;
            s += cw.x * (w0 + w6);
            s += cw.y * (w1 + w5);
            s += cw.z * (w2 + w4);
            s_a[cr*UST + tid]       = f2bf(s[0]);
            s_a[(cr + 8)*UST + tid] = f2bf(s[1]);
            w0 = w1; w1 = w2; w2 = w3; w3 = w4; w4 = w5; w5 = w6;
        }
    }
    __syncthreads();

    // --- P3: grouped mix (K=64) + in-reg gates -> v (s_u rows 0..15) ---
    {
        const int g = wvid;
        s16x8 a0 = *reinterpret_cast<const s16x8*>(&s_a[r_lo*UST + g*64 + kb*8]);
        s16x8 a1 = *reinterpret_cast<const s16x8*>(&s_a[r_lo*UST + g*64 + 32 + kb*8]);
        f32x4 acc[4];
        #pragma unroll
        for (int nt = 0; nt < 4; ++nt) acc[nt] = (f32x4){0.f,0.f,0.f,0.f};
        #pragma unroll
        for (int nt = 0; nt < 4; ++nt) {
            s16x8 b0 = *reinterpret_cast<const s16x8*>(
                mixw_b + (size_t)(((g*4 + nt)*2 + 0)*64 + lane)*8);
            acc[nt] = __builtin_amdgcn_mfma_f32_16x16x32_bf16(a0, b0, acc[nt], 0, 0, 0);
        }
        #pragma unroll
        for (int nt = 0; nt < 4; ++nt) {
            s16x8 b1 = *reinterpret_cast<const s16x8*>(
                mixw_b + (size_t)(((g*4 + nt)*2 + 1)*64 + lane)*8);
            acc[nt] = __builtin_amdgcn_mfma_f32_16x16x32_bf16(a1, b1, acc[nt], 0, 0, 0);
        }
        #pragma unroll
        for (int nt = 0; nt < 4; ++nt) {
            const int ocol = g*64 + nt*16 + r_lo;
            const float bia = mixb[ocol];
            #pragma unroll
            for (int r = 0; r < 4; ++r) {
                const int cr = kb*4 + r;
                unsigned short gu = (unsigned short)
                    ((gpk[nt*2 + (r >> 1)] >> ((r & 1)*16)) & 0xffffu);
                s_u[cr*UST + ocol] = f2bf((acc[nt][r] + bia) * bf2f(gu));
            }
        }
    }
    __syncthreads();

    // --- P4: residual load (issued first, hides under MFMAs) + out-proj -> hout ---
    float hres[2][4];
    #pragma unroll
    for (int c4 = 0; c4 < 2; ++c4) {
        const int d = wvid*32 + c4*16 + r_lo;
        #pragma unroll
        for (int r = 0; r < 4; ++r) {
            const int t = t0 + kb*4 + r;
            hres[c4][r] = (t < NT) ? hin[(rowbase + t)*ND + d] : 0.0f;
        }
    }
    f32x4 acc4[2];
    #pragma unroll
    for (int c4 = 0; c4 < 2; ++c4) acc4[c4] = (f32x4){0.f,0.f,0.f,0.f};
    #pragma unroll
    for (int ks = 0; ks < 16; ++ks) {
        s16x8 a = *reinterpret_cast<const s16x8*>(&s_u[r_lo*UST + ks*32 + kb*8]);
        #pragma unroll
        for (int c4 = 0; c4 < 2; ++c4) {
            const int c4t = wvid*2 + c4;
            s16x8 bf = *reinterpret_cast<const s16x8*>(
                outw_b + (size_t)((ks*16 + c4t)*64 + lane)*8);
            acc4[c4] = __builtin_amdgcn_mfma_f32_16x16x32_bf16(a, bf, acc4[c4], 0, 0, 0);
        }
    }
    #pragma unroll
    for (int c4 = 0; c4 < 2; ++c4) {
        const int d = wvid*32 + c4*16 + r_lo;
        const float ob = outb[d];
        #pragma unroll
        for (int r = 0; r < 4; ++r) {
            const int cr = kb*4 + r;
            const int t = t0 + cr;
            if (t < NT)
                hout[(rowbase + t)*ND + d] = hres[c4][r] + acc4[c4][r] + ob;
        }
    }
}

// ---------------- final layernorm (in place) ----------------
__global__ __launch_bounds__(256) void kLN(float* __restrict__ h,
    const float* __restrict__ g, const float* __restrict__ bb)
{
    const int row = blockIdx.x;
    const int tid = threadIdx.x;
    const int lane = tid & 63, wvi = tid >> 6;
    __shared__ float2 part[4];
    float v = h[(size_t)row*ND + tid];
    float s = v, s2 = v*v;
    #pragma unroll
    for (int off = 32; off; off >>= 1) { s += __shfl_down(s, off); s2 += __shfl_down(s2, off); }
    if (lane == 0) part[wvi] = make_float2(s, s2);
    __syncthreads();
    float2 a0 = part[0], a1 = part[1], a2 = part[2], a3 = part[3];
    float S  = a0.x+a1.x+a2.x+a3.x;
    float S2 = a0.y+a1.y+a2.y+a3.y;
    float mu  = S*(1.0f/ND);
    float var = S2*(1.0f/ND) - mu*mu;
    float rs  = rsqrtf(var + EPSF);
    h[(size_t)row*ND + tid] = (v - mu)*rs*g[tid] + bb[tid];
}

extern "C" void kernel_launch(void* const* d_in, const int* in_sizes, int n_in,
                              void* d_out, int out_size, void* d_ws, size_t ws_size,
                              hipStream_t stream)
{
    const float* x    = (const float*)d_in[0];
    const float* w_in = (const float*)d_in[1];
    const float* b_in = (const float*)d_in[2];
    const float* pos  = (const float*)d_in[3];
    const float* ln_g = (const float*)d_in[4];
    const float* ln_b = (const float*)d_in[5];
    const float* inw  = (const float*)d_in[6];
    const float* inb  = (const float*)d_in[7];
    const float* dww  = (const float*)d_in[8];
    const float* mixw = (const float*)d_in[9];
    const float* mixb = (const float*)d_in[10];
    const float* outw = (const float*)d_in[11];
    const float* outb = (const float*)d_in[12];
    const float* olng = (const float*)d_in[13];
    const float* olnb = (const float*)d_in[14];

    float* hA = (float*)d_out;                         // h ping (final result here)
    float* hB = (float*)d_ws;                          // h pong
    unsigned short* outw_b = (unsigned short*)((char*)d_ws + (size_t)NPOS*ND*4);
    unsigned short* mixw_b = outw_b + 524288;          // L*D*H
    unsigned short* inw_b  = mixw_b + 131072;          // L*H*64 ; then L*1024*32
    float*          dws    = (float*)(inw_b + 131072); // L*512*4 symmetrized conv wts

    k_init<<<NPOS, 256, 0, stream>>>(x, w_in, b_in, pos, hA);
    k_prep<<<3104, 256, 0, stream>>>(outw, mixw, inw, dww, outw_b, mixw_b, inw_b, dws);
    for (int l = 0; l < 4; ++l) {
        const float* src = (l & 1) ? hB : hA;
        float*       dst = (l & 1) ? hA : hB;
        kL2<<<dim3(18, NB), 512, 0, stream>>>(src, dst,
            ln_g + l*ND, ln_b + l*ND,
            inw_b + (size_t)l*32768, inb + l*NHH,
            dws + (size_t)l*2048,
            mixw_b + (size_t)l*32768, mixb + l*NH,
            outw_b + (size_t)l*131072, outb + l*ND);
    }
    kLN<<<NPOS, 256, 0, stream>>>(hA, olng, olnb);
}

// Round 19
// 1030.298 us; speedup vs baseline: 2.8218x; 1.0652x over previous
//
#include <hip/hip_runtime.h>
#include <hip/hip_bf16.h>

#define NB 512
#define NT 274
#define ND 256
#define NH 512
#define NHH 1024
#define NPOS (NB*NT)
#define EPSF 1e-5f
#define TILE 16
#define HALO 22
#define YST 264    // y row stride (elems); 32 rows in s_a
#define UST 520    // u/uc/v row stride

typedef float f32x4 __attribute__((ext_vector_type(4)));
typedef float f32x2 __attribute__((ext_vector_type(2)));
typedef unsigned int u32x4 __attribute__((ext_vector_type(4)));
typedef unsigned int u32x2 __attribute__((ext_vector_type(2)));
typedef short s16x8 __attribute__((ext_vector_type(8)));   // 8 bf16 = 4 VGPRs

__device__ __forceinline__ float bf2f(unsigned short s) {
    unsigned int u = ((unsigned int)s) << 16;
    float f; __builtin_memcpy(&f, &u, 4); return f;
}
// native conversion (RNE) -> compiler emits HW cvt / fuses pairs to cvt_pk
__device__ __forceinline__ unsigned short f2bf(float f) {
    __hip_bfloat16 b = __float2bfloat16(f);
    unsigned short r; __builtin_memcpy(&r, &b, 2); return r;
}
__device__ __forceinline__ unsigned int f2bf2(float lo, float hi) {
    return (unsigned)f2bf(lo) | ((unsigned)f2bf(hi) << 16);
}
// fast sigmoid: v_rcp_f32 approx (<=1e-7 rel err) instead of IEEE divide
// (~8-op div_scale/fma-refine/div_fixup sequence). Output feeds bf16 -> safe.
__device__ __forceinline__ float sigm(float x) {
    return __builtin_amdgcn_rcpf(1.0f + __expf(-x));
}

// ---------------- init: h = x[:,:,None]*w_in + b_in + pos ----------------
__global__ __launch_bounds__(256) void k_init(const float* __restrict__ x,
    const float* __restrict__ w_in, const float* __restrict__ b_in,
    const float* __restrict__ pos, float* __restrict__ h)
{
    int row = blockIdx.x;              // 0..NPOS-1  (b*NT + t)
    int d = threadIdx.x;
    int t = row % NT;
    float xv = x[row];
    h[(size_t)row*ND + d] = fmaf(xv, w_in[d], b_in[d] + pos[t*ND + d]);
}

// ------- prep: weights -> bf16 in MFMA-FRAGMENT ORDER; dww -> symmetrized f32 -------
__global__ __launch_bounds__(256) void k_prep(const float* __restrict__ outw,
    const float* __restrict__ mixw, const float* __restrict__ inw,
    const float* __restrict__ dww,
    unsigned short* __restrict__ ob, unsigned short* __restrict__ mb,
    unsigned short* __restrict__ iwb, float* __restrict__ dws)
{
    int i = blockIdx.x*256 + threadIdx.x;   // 0 .. 794623
    if (i < 524288) {
        // outw: per layer 256x512, instr = ks*16 + c4t
        int l = i >> 17, q = i & 131071;
        int j = q & 7, lane = (q >> 3) & 63, c4t = (q >> 9) & 15, ks = q >> 13;
        int src = (c4t*16 + (lane & 15))*512 + ks*32 + (lane >> 4)*8 + j;
        ob[i] = f2bf(outw[(size_t)l*131072 + src]);
    } else if (i < 655360) {
        // mixw: per layer 512x64, instr = (g*4+nt)*2 + half
        int v = i - 524288;
        int l = v >> 15, q = v & 32767;
        int j = q & 7, lane = (q >> 3) & 63, half = (q >> 9) & 1, gnt = q >> 10;
        int g = gnt >> 2, nt = gnt & 3;
        int src = (g*64 + nt*16 + (lane & 15))*64 + half*32 + (lane >> 4)*8 + j;
        mb[v] = f2bf(mixw[(size_t)l*32768 + src]);
    } else if (i < 786432) {
        // inw: per layer 1024x32, instr = g*8 + nt
        int v = i - 655360;
        int l = v >> 15, q = v & 32767;
        int j = q & 7, lane = (q >> 3) & 63, gnt = q >> 9;
        int g = gnt >> 3, nt = gnt & 7;
        int src = (g*128 + nt*16 + (lane & 15))*32 + (lane >> 4)*8 + j;
        iwb[v] = f2bf(inw[(size_t)l*32768 + src]);
    } else if (i < 794624) {
        // dws[l][c][k] = 0.5*(dww[k] + dww[6-k]), k=0..3
        int v = i - 786432;
        int l = v >> 11, c = (v >> 2) & 511, k = v & 3;
        const float* w = dww + (size_t)l*3584 + c*7;
        dws[v] = 0.5f*(w[k] + w[6-k]);
    }
}

// ======= kL2: whole layer fused, 512 thr / 8 waves, 39.8KB LDS =======
// (512,8): 4 blocks/CU, 32 waves, no spill (VGPR 32).
// r19: rcp-sigmoid (48 IEEE divides -> v_rcp); P0 early-exit for r>=HALO
// (dead A-rows only corrupt discarded C rows -> safe, saves 31% of P0 issue).
__global__ __launch_bounds__(512, 8) void kL2(const float* __restrict__ hin,
    float* __restrict__ hout,
    const float* __restrict__ lng, const float* __restrict__ lnb,
    const unsigned short* __restrict__ inw_b, const float* __restrict__ inb,
    const float* __restrict__ dws,
    const unsigned short* __restrict__ mixw_b, const float* __restrict__ mixb,
    const unsigned short* __restrict__ outw_b, const float* __restrict__ outb)
{
    const int b   = blockIdx.y;
    const int t0  = blockIdx.x * TILE;
    const int tid = threadIdx.x;            // 0..511
    const int lane = tid & 63, wvid = tid >> 6;   // 8 waves
    const int r_lo = lane & 15, kb = lane >> 4;
    const size_t rowbase = (size_t)b*NT;
    __shared__ __align__(16) unsigned short s_a[32*YST];   // y (32 rows) -> uc (16xUST)
    __shared__ __align__(16) unsigned short s_u[HALO*UST]; // u (22 rows) -> v (16 rows)

    // --- P0: load h halo rows t0-3..t0+18, LN -> y (bf16 in s_a) ---
    {
        const int r  = tid >> 4;            // 0..31; rows >= HALO skipped entirely
        const int c0 = (tid & 15) * 16;
        if (r < HALO) {
            const int t  = t0 - 3 + r;
            const bool vld = (t >= 0) && (t < NT);
            float vals[16];
            if (vld) {
                const float4* hp = reinterpret_cast<const float4*>(
                    hin + (rowbase + t)*ND + c0);
                #pragma unroll
                for (int j = 0; j < 4; ++j) {
                    float4 f = hp[j];
                    vals[4*j+0]=f.x; vals[4*j+1]=f.y; vals[4*j+2]=f.z; vals[4*j+3]=f.w;
                }
            } else {
                #pragma unroll
                for (int j = 0; j < 16; ++j) vals[j] = 0.0f;
            }
            float s = 0.f, s2 = 0.f;
            #pragma unroll
            for (int j = 0; j < 16; ++j) { s += vals[j]; s2 += vals[j]*vals[j]; }
            #pragma unroll
            for (int off = 1; off < 16; off <<= 1) {   // 16 lanes per row, aligned
                s  += __shfl_xor(s, off);
                s2 += __shfl_xor(s2, off);
            }
            float mu  = s * (1.0f/ND);
            float var = s2 * (1.0f/ND) - mu*mu;
            float rs  = rsqrtf(var + EPSF);
            if (vld) {
                #pragma unroll
                for (int j = 0; j < 4; ++j) {
                    float4 g4 = *reinterpret_cast<const float4*>(lng + c0 + 4*j);
                    float4 b4 = *reinterpret_cast<const float4*>(lnb + c0 + 4*j);
                    float y0 = (vals[4*j+0]-mu)*rs*g4.x + b4.x;
                    float y1 = (vals[4*j+1]-mu)*rs*g4.y + b4.y;
                    float y2 = (vals[4*j+2]-mu)*rs*g4.z + b4.z;
                    float y3 = (vals[4*j+3]-mu)*rs*g4.w + b4.w;
                    u32x2 pk;
                    pk[0] = f2bf2(y0, y1);
                    pk[1] = f2bf2(y2, y3);
                    *reinterpret_cast<u32x2*>(&s_a[r*YST + c0 + 4*j]) = pk;
                } 
            } else {
                #pragma unroll
                for (int j = 0; j < 4; ++j)
                    *reinterpret_cast<u32x2*>(&s_a[r*YST + c0 + 4*j]) = (u32x2){0u,0u};
            }
        }
    }
    __syncthreads();

    // --- P1: grouped in-proj. u over halo rows -> s_u; gates (central) -> regs ---
    unsigned int gpk[8];    // gates bf16-packed: [nt*2 + (r>>1)]
    {
        // u-part: wave = (rt = wvid>>2, g = wvid&3); 8 col-tiles (nt 0..7)
        const int rt = wvid >> 2, g = wvid & 3;
        s16x8 a = *reinterpret_cast<const s16x8*>(
            &s_a[(rt*16 + r_lo)*YST + g*32 + kb*8]);
        #pragma unroll
        for (int half = 0; half < 2; ++half) {
            f32x4 acc[4];
            #pragma unroll
            for (int q = 0; q < 4; ++q) acc[q] = (f32x4){0.f,0.f,0.f,0.f};
            #pragma unroll
            for (int q = 0; q < 4; ++q) {
                const int nt = half*4 + q;
                s16x8 bf = *reinterpret_cast<const s16x8*>(
                    inw_b + (size_t)((g*8 + nt)*64 + lane)*8);
                acc[q] = __builtin_amdgcn_mfma_f32_16x16x32_bf16(a, bf, acc[q], 0, 0, 0);
            }
            #pragma unroll
            for (int q = 0; q < 4; ++q) {
                const int nt = half*4 + q;
                const int ocol = g*128 + nt*16 + r_lo;
                const float bia = inb[ocol];
                #pragma unroll
                for (int r = 0; r < 4; ++r) {
                    const int hr = rt*16 + kb*4 + r;
                    if (hr < HALO) {
                        const int t = t0 - 3 + hr;
                        unsigned short val = 0;
                        if (t >= 0 && t < NT) {
                            float tv = acc[q][r] + bia;
                            val = f2bf(tv * sigm(tv));
                        }
                        s_u[hr*UST + ocol] = val;
                    }
                }
            }
        }
        // gate-part: central rows (y rows 3..18); wave owns gate cols wvid*64..+63.
        s16x8 ag = *reinterpret_cast<const s16x8*>(
            &s_a[(3 + r_lo)*YST + 128 + (wvid >> 1)*32 + kb*8]);
        f32x4 gacc[4];
        #pragma unroll
        for (int nt = 0; nt < 4; ++nt) gacc[nt] = (f32x4){0.f,0.f,0.f,0.f};
        #pragma unroll
        for (int nt = 0; nt < 4; ++nt) {
            const int instr = (4 + (wvid >> 1))*8 + (wvid & 1)*4 + nt;
            s16x8 bf = *reinterpret_cast<const s16x8*>(
                inw_b + (size_t)(instr*64 + lane)*8);
            gacc[nt] = __builtin_amdgcn_mfma_f32_16x16x32_bf16(ag, bf, gacc[nt], 0, 0, 0);
        }
        #pragma unroll
        for (int nt = 0; nt < 4; ++nt) {
            const float bia = inb[512 + wvid*64 + nt*16 + r_lo];
            #pragma unroll
            for (int rp = 0; rp < 2; ++rp) {
                float s0 = sigm(gacc[nt][2*rp]   + bia);
                float s1 = sigm(gacc[nt][2*rp+1] + bia);
                gpk[nt*2 + rp] = f2bf2(s0, s1);
            }
        }
    }
    __syncthreads();

    // --- P2: symmetric conv (4 taps), PACKED row-pairs (cr, cr+8) via f32x2 ---
    {
        const float4 cw = *reinterpret_cast<const float4*>(dws + tid*4);
        f32x2 w0, w1, w2, w3, w4, w5;
        w0 = (f32x2){bf2f(s_u[0*UST + tid]), bf2f(s_u[ 8*UST + tid])};
        w1 = (f32x2){bf2f(s_u[1*UST + tid]), bf2f(s_u[ 9*UST + tid])};
        w2 = (f32x2){bf2f(s_u[2*UST + tid]), bf2f(s_u[10*UST + tid])};
        w3 = (f32x2){bf2f(s_u[3*UST + tid]), bf2f(s_u[11*UST + tid])};
        w4 = (f32x2){bf2f(s_u[4*UST + tid]), bf2f(s_u[12*UST + tid])};
        w5 = (f32x2){bf2f(s_u[5*UST + tid]), bf2f(s_u[13*UST + tid])};
        #pragma unroll
        for (int cr = 0; cr < 8; ++cr) {
            f32x2 w6 = (f32x2){bf2f(s_u[(cr + 6)*UST + tid]),
                               bf2f(s_u[(cr + 14)*UST + tid])};
            f32x2 s = cw.w * w3;
            s += cw.x * (w0 + w6);
            s += cw.y * (w1 + w5);
            s += cw.z * (w2 + w4);
            s_a[cr*UST + tid]       = f2bf(s[0]);
            s_a[(cr + 8)*UST + tid] = f2bf(s[1]);
            w0 = w1; w1 = w2; w2 = w3; w3 = w4; w4 = w5; w5 = w6;
        }
    }
    __syncthreads();

    // --- P3: grouped mix (K=64) + in-reg gates -> v (s_u rows 0..15) ---
    {
        const int g = wvid;
        s16x8 a0 = *reinterpret_cast<const s16x8*>(&s_a[r_lo*UST + g*64 + kb*8]);
        s16x8 a1 = *reinterpret_cast<const s16x8*>(&s_a[r_lo*UST + g*64 + 32 + kb*8]);
        f32x4 acc[4];
        #pragma unroll
        for (int nt = 0; nt < 4; ++nt) acc[nt] = (f32x4){0.f,0.f,0.f,0.f};
        #pragma unroll
        for (int nt = 0; nt < 4; ++nt) {
            s16x8 b0 = *reinterpret_cast<const s16x8*>(
                mixw_b + (size_t)(((g*4 + nt)*2 + 0)*64 + lane)*8);
            acc[nt] = __builtin_amdgcn_mfma_f32_16x16x32_bf16(a0, b0, acc[nt], 0, 0, 0);
        }
        #pragma unroll
        for (int nt = 0; nt < 4; ++nt) {
            s16x8 b1 = *reinterpret_cast<const s16x8*>(
                mixw_b + (size_t)(((g*4 + nt)*2 + 1)*64 + lane)*8);
            acc[nt] = __builtin_amdgcn_mfma_f32_16x16x32_bf16(a1, b1, acc[nt], 0, 0, 0);
        }
        #pragma unroll
        for (int nt = 0; nt < 4; ++nt) {
            const int ocol = g*64 + nt*16 + r_lo;
            const float bia = mixb[ocol];
            #pragma unroll
            for (int r = 0; r < 4; ++r) {
                const int cr = kb*4 + r;
                unsigned short gu = (unsigned short)
                    ((gpk[nt*2 + (r >> 1)] >> ((r & 1)*16)) & 0xffffu);
                s_u[cr*UST + ocol] = f2bf((acc[nt][r] + bia) * bf2f(gu));
            }
        }
    }
    __syncthreads();

    // --- P4: residual load (issued first, hides under MFMAs) + out-proj -> hout ---
    float hres[2][4];
    #pragma unroll
    for (int c4 = 0; c4 < 2; ++c4) {
        const int d = wvid*32 + c4*16 + r_lo;
        #pragma unroll
        for (int r = 0; r < 4; ++r) {
            const int t = t0 + kb*4 + r;
            hres[c4][r] = (t < NT) ? hin[(rowbase + t)*ND + d] : 0.0f;
        }
    }
    f32x4 acc4[2];
    #pragma unroll
    for (int c4 = 0; c4 < 2; ++c4) acc4[c4] = (f32x4){0.f,0.f,0.f,0.f};
    #pragma unroll
    for (int ks = 0; ks < 16; ++ks) {
        s16x8 a = *reinterpret_cast<const s16x8*>(&s_u[r_lo*UST + ks*32 + kb*8]);
        #pragma unroll
        for (int c4 = 0; c4 < 2; ++c4) {
            const int c4t = wvid*2 + c4;
            s16x8 bf = *reinterpret_cast<const s16x8*>(
                outw_b + (size_t)((ks*16 + c4t)*64 + lane)*8);
            acc4[c4] = __builtin_amdgcn_mfma_f32_16x16x32_bf16(a, bf, acc4[c4], 0, 0, 0);
        }
    }
    #pragma unroll
    for (int c4 = 0; c4 < 2; ++c4) {
        const int d = wvid*32 + c4*16 + r_lo;
        const float ob = outb[d];
        #pragma unroll
        for (int r = 0; r < 4; ++r) {
            const int cr = kb*4 + r;
            const int t = t0 + cr;
            if (t < NT)
                hout[(rowbase + t)*ND + d] = hres[c4][r] + acc4[c4][r] + ob;
        }
    }
}

// ---------------- final layernorm (in place) ----------------
__global__ __launch_bounds__(256) void kLN(float* __restrict__ h,
    const float* __restrict__ g, const float* __restrict__ bb)
{
    const int row = blockIdx.x;
    const int tid = threadIdx.x;
    const int lane = tid & 63, wvi = tid >> 6;
    __shared__ float2 part[4];
    float v = h[(size_t)row*ND + tid];
    float s = v, s2 = v*v;
    #pragma unroll
    for (int off = 32; off; off >>= 1) { s += __shfl_down(s, off); s2 += __shfl_down(s2, off); }
    if (lane == 0) part[wvi] = make_float2(s, s2);
    __syncthreads();
    float2 a0 = part[0], a1 = part[1], a2 = part[2], a3 = part[3];
    float S  = a0.x+a1.x+a2.x+a3.x;
    float S2 = a0.y+a1.y+a2.y+a3.y;
    float mu  = S*(1.0f/ND);
    float var = S2*(1.0f/ND) - mu*mu;
    float rs  = rsqrtf(var + EPSF);
    h[(size_t)row*ND + tid] = (v - mu)*rs*g[tid] + bb[tid];
}

extern "C" void kernel_launch(void* const* d_in, const int* in_sizes, int n_in,
                              void* d_out, int out_size, void* d_ws, size_t ws_size,
                              hipStream_t stream)
{
    const float* x    = (const float*)d_in[0];
    const float* w_in = (const float*)d_in[1];
    const float* b_in = (const float*)d_in[2];
    const float* pos  = (const float*)d_in[3];
    const float* ln_g = (const float*)d_in[4];
    const float* ln_b = (const float*)d_in[5];
    const float* inw  = (const float*)d_in[6];
    const float* inb  = (const float*)d_in[7];
    const float* dww  = (const float*)d_in[8];
    const float* mixw = (const float*)d_in[9];
    const float* mixb = (const float*)d_in[10];
    const float* outw = (const float*)d_in[11];
    const float* outb = (const float*)d_in[12];
    const float* olng = (const float*)d_in[13];
    const float* olnb = (const float*)d_in[14];

    float* hA = (float*)d_out;                         // h ping (final result here)
    float* hB = (float*)d_ws;                          // h pong
    unsigned short* outw_b = (unsigned short*)((char*)d_ws + (size_t)NPOS*ND*4);
    unsigned short* mixw_b = outw_b + 524288;          // L*D*H
    unsigned short* inw_b  = mixw_b + 131072;          // L*H*64 ; then L*1024*32
    float*          dws    = (float*)(inw_b + 131072); // L*512*4 symmetrized conv wts

    k_init<<<NPOS, 256, 0, stream>>>(x, w_in, b_in, pos, hA);
    k_prep<<<3104, 256, 0, stream>>>(outw, mixw, inw, dww, outw_b, mixw_b, inw_b, dws);
    for (int l = 0; l < 4; ++l) {
        const float* src = (l & 1) ? hB : hA;
        float*       dst = (l & 1) ? hA : hB;
        kL2<<<dim3(18, NB), 512, 0, stream>>>(src, dst,
            ln_g + l*ND, ln_b + l*ND,
            inw_b + (size_t)l*32768, inb + l*NHH,
            dws + (size_t)l*2048,
            mixw_b + (size_t)l*32768, mixb + l*NH,
            outw_b + (size_t)l*131072, outb + l*ND);
    }
    kLN<<<NPOS, 256, 0, stream>>>(hA, olng, olnb);
}

// Round 20
// 966.539 us; speedup vs baseline: 3.0079x; 1.0660x over previous
//
#include <hip/hip_runtime.h>
#include <hip/hip_bf16.h>

#define NB 512
#define NT 274
#define ND 256
#define NH 512
#define NHH 1024
#define NPOS (NB*NT)
#define EPSF 1e-5f
#define TILE 16
#define HALO 22
#define YST 264    // y row stride (elems); 32 rows in s_a
#define UST 520    // u/uc/v row stride

typedef float f32x4 __attribute__((ext_vector_type(4)));
typedef float f32x2 __attribute__((ext_vector_type(2)));
typedef unsigned int u32x4 __attribute__((ext_vector_type(4)));
typedef unsigned int u32x2 __attribute__((ext_vector_type(2)));
typedef short s16x8 __attribute__((ext_vector_type(8)));   // 8 bf16 = 4 VGPRs

__device__ __forceinline__ float bf2f(unsigned short s) {
    unsigned int u = ((unsigned int)s) << 16;
    float f; __builtin_memcpy(&f, &u, 4); return f;
}
__device__ __forceinline__ unsigned short f2bf(float f) {
    __hip_bfloat16 b = __float2bfloat16(f);
    unsigned short r; __builtin_memcpy(&r, &b, 2); return r;
}
__device__ __forceinline__ unsigned int f2bf2(float lo, float hi) {
    return (unsigned)f2bf(lo) | ((unsigned)f2bf(hi) << 16);
}
// fast sigmoid via v_rcp_f32 (<=1e-7 rel err); output feeds bf16 -> safe
__device__ __forceinline__ float sigm(float x) {
    return __builtin_amdgcn_rcpf(1.0f + __expf(-x));
}

// ---------------- init: h = x[:,:,None]*w_in + b_in + pos ----------------
__global__ __launch_bounds__(256) void k_init(const float* __restrict__ x,
    const float* __restrict__ w_in, const float* __restrict__ b_in,
    const float* __restrict__ pos, float* __restrict__ h)
{
    int row = blockIdx.x;              // 0..NPOS-1  (b*NT + t)
    int d = threadIdx.x;
    int t = row % NT;
    float xv = x[row];
    h[(size_t)row*ND + d] = fmaf(xv, w_in[d], b_in[d] + pos[t*ND + d]);
}

// ------- prep: weights -> bf16 MFMA-FRAGMENT ORDER; LN gamma folded into inw;
//         inb_f = inb + inw . lnb ; dww -> symmetrized f32 -------
__global__ __launch_bounds__(256) void k_prep(const float* __restrict__ outw,
    const float* __restrict__ mixw, const float* __restrict__ inw,
    const float* __restrict__ dww,
    const float* __restrict__ lng, const float* __restrict__ lnb,
    const float* __restrict__ inb,
    unsigned short* __restrict__ ob, unsigned short* __restrict__ mb,
    unsigned short* __restrict__ iwb, float* __restrict__ dws,
    float* __restrict__ inb_f)
{
    int i = blockIdx.x*256 + threadIdx.x;   // 0 .. 798719
    if (i < 524288) {
        // outw: per layer 256x512, instr = ks*16 + c4t
        int l = i >> 17, q = i & 131071;
        int j = q & 7, lane = (q >> 3) & 63, c4t = (q >> 9) & 15, ks = q >> 13;
        int src = (c4t*16 + (lane & 15))*512 + ks*32 + (lane >> 4)*8 + j;
        ob[i] = f2bf(outw[(size_t)l*131072 + src]);
    } else if (i < 655360) {
        // mixw: per layer 512x64, instr = (g*4+nt)*2 + half
        int v = i - 524288;
        int l = v >> 15, q = v & 32767;
        int j = q & 7, lane = (q >> 3) & 63, half = (q >> 9) & 1, gnt = q >> 10;
        int g = gnt >> 2, nt = gnt & 3;
        int src = (g*64 + nt*16 + (lane & 15))*64 + half*32 + (lane >> 4)*8 + j;
        mb[v] = f2bf(mixw[(size_t)l*32768 + src]);
    } else if (i < 786432) {
        // inw: per layer 1024x32, instr = g*8 + nt ; LN gamma folded in
        int v = i - 655360;
        int l = v >> 15, q = v & 32767;
        int j = q & 7, lane = (q >> 3) & 63, gnt = q >> 9;
        int g = gnt >> 3, nt = gnt & 7;
        int kk = (lane >> 4)*8 + j;               // k within group
        int src = (g*128 + nt*16 + (lane & 15))*32 + kk;
        float w = inw[(size_t)l*32768 + src] * lng[l*ND + g*32 + kk];
        iwb[v] = f2bf(w);
    } else if (i < 794624) {
        // dws[l][c][k] = 0.5*(dww[k] + dww[6-k]), k=0..3
        int v = i - 786432;
        int l = v >> 11, c = (v >> 2) & 511, k = v & 3;
        const float* w = dww + (size_t)l*3584 + c*7;
        dws[v] = 0.5f*(w[k] + w[6-k]);
    } else if (i < 798720) {
        // inb_f[l][c] = inb[l][c] + sum_k inw[l][c][k]*lnb[l][g*32+k]
        int v = i - 794624;
        int l = v >> 10, c = v & 1023, g = c >> 7;
        const float* wr = inw + (size_t)l*32768 + c*32;
        const float* lb = lnb + l*ND + g*32;
        float s = inb[l*NHH + c];
        #pragma unroll
        for (int k = 0; k < 32; ++k) s = fmaf(wr[k], lb[k], s);
        inb_f[v] = s;
    }
}

// ======= kL2: whole layer fused, 512 thr / 8 waves, 39.8KB LDS =======
// (512,8): 4 blocks/CU, 32 waves, no spill. r20: LN gamma/beta folded into
// in-proj weights/bias (P0 stores (h-mu)*rs only); wave-uniform `interior`
// fast path drops per-element t-bounds checks in P1 for blocks 1..15.
__global__ __launch_bounds__(512, 8) void kL2(const float* __restrict__ hin,
    float* __restrict__ hout,
    const unsigned short* __restrict__ inw_b, const float* __restrict__ inb_f,
    const float* __restrict__ dws,
    const unsigned short* __restrict__ mixw_b, const float* __restrict__ mixb,
    const unsigned short* __restrict__ outw_b, const float* __restrict__ outb)
{
    const int b   = blockIdx.y;
    const int t0  = blockIdx.x * TILE;
    const int tid = threadIdx.x;            // 0..511
    const int lane = tid & 63, wvid = tid >> 6;   // 8 waves
    const int r_lo = lane & 15, kb = lane >> 4;
    const size_t rowbase = (size_t)b*NT;
    const bool interior = (t0 >= 3) && (t0 + HALO - 3 <= NT);  // halo fully in-range
    __shared__ __align__(16) unsigned short s_a[32*YST];   // y (32 rows) -> uc (16xUST)
    __shared__ __align__(16) unsigned short s_u[HALO*UST]; // u (22 rows) -> v (16 rows)

    // --- P0: load h halo rows t0-3..t0+18, LN (no gamma/beta) -> s_a ---
    {
        const int r  = tid >> 4;            // 0..31; rows >= HALO skipped
        const int c0 = (tid & 15) * 16;
        if (r < HALO) {
            const int t  = t0 - 3 + r;
            const bool vld = interior || ((t >= 0) && (t < NT));
            float vals[16];
            if (vld) {
                const float4* hp = reinterpret_cast<const float4*>(
                    hin + (rowbase + t)*ND + c0);
                #pragma unroll
                for (int j = 0; j < 4; ++j) {
                    float4 f = hp[j];
                    vals[4*j+0]=f.x; vals[4*j+1]=f.y; vals[4*j+2]=f.z; vals[4*j+3]=f.w;
                }
            } else {
                #pragma unroll
                for (int j = 0; j < 16; ++j) vals[j] = 0.0f;
            }
            float s = 0.f, s2 = 0.f;
            #pragma unroll
            for (int j = 0; j < 16; ++j) { s += vals[j]; s2 += vals[j]*vals[j]; }
            #pragma unroll
            for (int off = 1; off < 16; off <<= 1) {
                s  += __shfl_xor(s, off);
                s2 += __shfl_xor(s2, off);
            }
            float mu  = s * (1.0f/ND);
            float var = s2 * (1.0f/ND) - mu*mu;
            float rs  = rsqrtf(var + EPSF);
            if (!vld) rs = 0.0f;           // zero rows stay zero
            #pragma unroll
            for (int j = 0; j < 4; ++j) {
                float y0 = (vals[4*j+0]-mu)*rs;
                float y1 = (vals[4*j+1]-mu)*rs;
                float y2 = (vals[4*j+2]-mu)*rs;
                float y3 = (vals[4*j+3]-mu)*rs;
                u32x2 pk;
                pk[0] = f2bf2(y0, y1);
                pk[1] = f2bf2(y2, y3);
                *reinterpret_cast<u32x2*>(&s_a[r*YST + c0 + 4*j]) = pk;
            }
        }
    }
    __syncthreads();

    // --- P1: grouped in-proj. u over halo rows -> s_u; gates (central) -> regs ---
    unsigned int gpk[8];    // gates bf16-packed: [nt*2 + (r>>1)]
    {
        // u-part: wave = (rt = wvid>>2, g = wvid&3); 8 col-tiles (nt 0..7)
        const int rt = wvid >> 2, g = wvid & 3;
        s16x8 a = *reinterpret_cast<const s16x8*>(
            &s_a[(rt*16 + r_lo)*YST + g*32 + kb*8]);
        #pragma unroll
        for (int half = 0; half < 2; ++half) {
            f32x4 acc[4];
            #pragma unroll
            for (int q = 0; q < 4; ++q) acc[q] = (f32x4){0.f,0.f,0.f,0.f};
            #pragma unroll
            for (int q = 0; q < 4; ++q) {
                const int nt = half*4 + q;
                s16x8 bf = *reinterpret_cast<const s16x8*>(
                    inw_b + (size_t)((g*8 + nt)*64 + lane)*8);
                acc[q] = __builtin_amdgcn_mfma_f32_16x16x32_bf16(a, bf, acc[q], 0, 0, 0);
            }
            if (interior) {
                #pragma unroll
                for (int q = 0; q < 4; ++q) {
                    const int nt = half*4 + q;
                    const int ocol = g*128 + nt*16 + r_lo;
                    const float bia = inb_f[ocol];
                    #pragma unroll
                    for (int r = 0; r < 4; ++r) {
                        const int hr = rt*16 + kb*4 + r;
                        if (hr < HALO) {
                            float tv = acc[q][r] + bia;
                            s_u[hr*UST + ocol] = f2bf(tv * sigm(tv));
                        }
                    }
                }
            } else {
                #pragma unroll
                for (int q = 0; q < 4; ++q) {
                    const int nt = half*4 + q;
                    const int ocol = g*128 + nt*16 + r_lo;
                    const float bia = inb_f[ocol];
                    #pragma unroll
                    for (int r = 0; r < 4; ++r) {
                        const int hr = rt*16 + kb*4 + r;
                        if (hr < HALO) {
                            const int t = t0 - 3 + hr;
                            unsigned short val = 0;
                            if (t >= 0 && t < NT) {
                                float tv = acc[q][r] + bia;
                                val = f2bf(tv * sigm(tv));
                            }
                            s_u[hr*UST + ocol] = val;
                        }
                    }
                }
            }
        }
        // gate-part: central rows (y rows 3..18); wave owns gate cols wvid*64..+63.
        s16x8 ag = *reinterpret_cast<const s16x8*>(
            &s_a[(3 + r_lo)*YST + 128 + (wvid >> 1)*32 + kb*8]);
        f32x4 gacc[4];
        #pragma unroll
        for (int nt = 0; nt < 4; ++nt) gacc[nt] = (f32x4){0.f,0.f,0.f,0.f};
        #pragma unroll
        for (int nt = 0; nt < 4; ++nt) {
            const int instr = (4 + (wvid >> 1))*8 + (wvid & 1)*4 + nt;
            s16x8 bf = *reinterpret_cast<const s16x8*>(
                inw_b + (size_t)(instr*64 + lane)*8);
            gacc[nt] = __builtin_amdgcn_mfma_f32_16x16x32_bf16(ag, bf, gacc[nt], 0, 0, 0);
        }
        #pragma unroll
        for (int nt = 0; nt < 4; ++nt) {
            const float bia = inb_f[512 + wvid*64 + nt*16 + r_lo];
            #pragma unroll
            for (int rp = 0; rp < 2; ++rp) {
                float s0 = sigm(gacc[nt][2*rp]   + bia);
                float s1 = sigm(gacc[nt][2*rp+1] + bia);
                gpk[nt*2 + rp] = f2bf2(s0, s1);
            }
        }
    }
    __syncthreads();

    // --- P2: symmetric conv (4 taps), PACKED row-pairs (cr, cr+8) via f32x2 ---
    {
        const float4 cw = *reinterpret_cast<const float4*>(dws + tid*4);
        f32x2 w0, w1, w2, w3, w4, w5;
        w0 = (f32x2){bf2f(s_u[0*UST + tid]), bf2f(s_u[ 8*UST + tid])};
        w1 = (f32x2){bf2f(s_u[1*UST + tid]), bf2f(s_u[ 9*UST + tid])};
        w2 = (f32x2){bf2f(s_u[2*UST + tid]), bf2f(s_u[10*UST + tid])};
        w3 = (f32x2){bf2f(s_u[3*UST + tid]), bf2f(s_u[11*UST + tid])};
        w4 = (f32x2){bf2f(s_u[4*UST + tid]), bf2f(s_u[12*UST + tid])};
        w5 = (f32x2){bf2f(s_u[5*UST + tid]), bf2f(s_u[13*UST + tid])};
        #pragma unroll
        for (int cr = 0; cr < 8; ++cr) {
            f32x2 w6 = (f32x2){bf2f(s_u[(cr + 6)*UST + tid]),
                               bf2f(s_u[(cr + 14)*UST + tid])};
            f32x2 s = cw.w * w3;
            s += cw.x * (w0 + w6);
            s += cw.y * (w1 + w5);
            s += cw.z * (w2 + w4);
            s_a[cr*UST + tid]       = f2bf(s[0]);
            s_a[(cr + 8)*UST + tid] = f2bf(s[1]);
            w0 = w1; w1 = w2; w2 = w3; w3 = w4; w4 = w5; w5 = w6;
        }
    }
    __syncthreads();

    // --- P3: grouped mix (K=64) + in-reg gates -> v (s_u rows 0..15) ---
    {
        const int g = wvid;
        s16x8 a0 = *reinterpret_cast<const s16x8*>(&s_a[r_lo*UST + g*64 + kb*8]);
        s16x8 a1 = *reinterpret_cast<const s16x8*>(&s_a[r_lo*UST + g*64 + 32 + kb*8]);
        f32x4 acc[4];
        #pragma unroll
        for (int nt = 0; nt < 4; ++nt) acc[nt] = (f32x4){0.f,0.f,0.f,0.f};
        #pragma unroll
        for (int nt = 0; nt < 4; ++nt) {
            s16x8 b0 = *reinterpret_cast<const s16x8*>(
                mixw_b + (size_t)(((g*4 + nt)*2 + 0)*64 + lane)*8);
            acc[nt] = __builtin_amdgcn_mfma_f32_16x16x32_bf16(a0, b0, acc[nt], 0, 0, 0);
        }
        #pragma unroll
        for (int nt = 0; nt < 4; ++nt) {
            s16x8 b1 = *reinterpret_cast<const s16x8*>(
                mixw_b + (size_t)(((g*4 + nt)*2 + 1)*64 + lane)*8);
            acc[nt] = __builtin_amdgcn_mfma_f32_16x16x32_bf16(a1, b1, acc[nt], 0, 0, 0);
        }
        #pragma unroll
        for (int nt = 0; nt < 4; ++nt) {
            const int ocol = g*64 + nt*16 + r_lo;
            const float bia = mixb[ocol];
            #pragma unroll
            for (int r = 0; r < 4; ++r) {
                const int cr = kb*4 + r;
                unsigned short gu = (unsigned short)
                    ((gpk[nt*2 + (r >> 1)] >> ((r & 1)*16)) & 0xffffu);
                s_u[cr*UST + ocol] = f2bf((acc[nt][r] + bia) * bf2f(gu));
            }
        }
    }
    __syncthreads();

    // --- P4: residual load (issued first, hides under MFMAs) + out-proj -> hout ---
    float hres[2][4];
    #pragma unroll
    for (int c4 = 0; c4 < 2; ++c4) {
        const int d = wvid*32 + c4*16 + r_lo;
        #pragma unroll
        for (int r = 0; r < 4; ++r) {
            const int t = t0 + kb*4 + r;
            hres[c4][r] = (t < NT) ? hin[(rowbase + t)*ND + d] : 0.0f;
        }
    }
    f32x4 acc4[2];
    #pragma unroll
    for (int c4 = 0; c4 < 2; ++c4) acc4[c4] = (f32x4){0.f,0.f,0.f,0.f};
    #pragma unroll
    for (int ks = 0; ks < 16; ++ks) {
        s16x8 a = *reinterpret_cast<const s16x8*>(&s_u[r_lo*UST + ks*32 + kb*8]);
        #pragma unroll
        for (int c4 = 0; c4 < 2; ++c4) {
            const int c4t = wvid*2 + c4;
            s16x8 bf = *reinterpret_cast<const s16x8*>(
                outw_b + (size_t)((ks*16 + c4t)*64 + lane)*8);
            acc4[c4] = __builtin_amdgcn_mfma_f32_16x16x32_bf16(a, bf, acc4[c4], 0, 0, 0);
        }
    }
    #pragma unroll
    for (int c4 = 0; c4 < 2; ++c4) {
        const int d = wvid*32 + c4*16 + r_lo;
        const float ob = outb[d];
        #pragma unroll
        for (int r = 0; r < 4; ++r) {
            const int cr = kb*4 + r;
            const int t = t0 + cr;
            if (t < NT)
                hout[(rowbase + t)*ND + d] = hres[c4][r] + acc4[c4][r] + ob;
        }
    }
}

// ---------------- final layernorm (in place) ----------------
__global__ __launch_bounds__(256) void kLN(float* __restrict__ h,
    const float* __restrict__ g, const float* __restrict__ bb)
{
    const int row = blockIdx.x;
    const int tid = threadIdx.x;
    const int lane = tid & 63, wvi = tid >> 6;
    __shared__ float2 part[4];
    float v = h[(size_t)row*ND + tid];
    float s = v, s2 = v*v;
    #pragma unroll
    for (int off = 32; off; off >>= 1) { s += __shfl_down(s, off); s2 += __shfl_down(s2, off); }
    if (lane == 0) part[wvi] = make_float2(s, s2);
    __syncthreads();
    float2 a0 = part[0], a1 = part[1], a2 = part[2], a3 = part[3];
    float S  = a0.x+a1.x+a2.x+a3.x;
    float S2 = a0.y+a1.y+a2.y+a3.y;
    float mu  = S*(1.0f/ND);
    float var = S2*(1.0f/ND) - mu*mu;
    float rs  = rsqrtf(var + EPSF);
    h[(size_t)row*ND + tid] = (v - mu)*rs*g[tid] + bb[tid];
}

extern "C" void kernel_launch(void* const* d_in, const int* in_sizes, int n_in,
                              void* d_out, int out_size, void* d_ws, size_t ws_size,
                              hipStream_t stream)
{
    const float* x    = (const float*)d_in[0];
    const float* w_in = (const float*)d_in[1];
    const float* b_in = (const float*)d_in[2];
    const float* pos  = (const float*)d_in[3];
    const float* ln_g = (const float*)d_in[4];
    const float* ln_b = (const float*)d_in[5];
    const float* inw  = (const float*)d_in[6];
    const float* inb  = (const float*)d_in[7];
    const float* dww  = (const float*)d_in[8];
    const float* mixw = (const float*)d_in[9];
    const float* mixb = (const float*)d_in[10];
    const float* outw = (const float*)d_in[11];
    const float* outb = (const float*)d_in[12];
    const float* olng = (const float*)d_in[13];
    const float* olnb = (const float*)d_in[14];

    float* hA = (float*)d_out;                         // h ping (final result here)
    float* hB = (float*)d_ws;                          // h pong
    unsigned short* outw_b = (unsigned short*)((char*)d_ws + (size_t)NPOS*ND*4);
    unsigned short* mixw_b = outw_b + 524288;          // L*D*H
    unsigned short* inw_b  = mixw_b + 131072;          // L*H*64 ; then L*1024*32
    float*          dws    = (float*)(inw_b + 131072); // L*512*4 symmetrized conv wts
    float*          inb_f  = dws + 8192;               // L*1024 folded in-proj bias

    k_init<<<NPOS, 256, 0, stream>>>(x, w_in, b_in, pos, hA);
    k_prep<<<3120, 256, 0, stream>>>(outw, mixw, inw, dww, ln_g, ln_b, inb,
                                     outw_b, mixw_b, inw_b, dws, inb_f);
    for (int l = 0; l < 4; ++l) {
        const float* src = (l & 1) ? hB : hA;
        float*       dst = (l & 1) ? hA : hB;
        kL2<<<dim3(18, NB), 512, 0, stream>>>(src, dst,
            inw_b + (size_t)l*32768, inb_f + l*NHH,
            dws + (size_t)l*2048,
            mixw_b + (size_t)l*32768, mixb + l*NH,
            outw_b + (size_t)l*131072, outb + l*ND);
    }
    kLN<<<NPOS, 256, 0, stream>>>(hA, olng, olnb);
}

// Round 21
// 867.639 us; speedup vs baseline: 3.3508x; 1.1140x over previous
//
#include <hip/hip_runtime.h>
#include <hip/hip_bf16.h>

#define NB 512
#define NT 274
#define ND 256
#define NH 512
#define NHH 1024
#define NPOS (NB*NT)
#define EPSF 1e-5f
#define TILE 16
#define HALO 22
#define YST 264    // y row stride (elems); 32 rows in s_a
#define UST 520    // u/uc/v row stride

typedef float f32x4 __attribute__((ext_vector_type(4)));
typedef float f32x2 __attribute__((ext_vector_type(2)));
typedef unsigned int u32x4 __attribute__((ext_vector_type(4)));
typedef unsigned int u32x2 __attribute__((ext_vector_type(2)));
typedef short s16x8 __attribute__((ext_vector_type(8)));   // 8 bf16 = 4 VGPRs

__device__ __forceinline__ float bf2f(unsigned short s) {
    unsigned int u = ((unsigned int)s) << 16;
    float f; __builtin_memcpy(&f, &u, 4); return f;
}
__device__ __forceinline__ unsigned short f2bf(float f) {
    __hip_bfloat16 b = __float2bfloat16(f);
    unsigned short r; __builtin_memcpy(&r, &b, 2); return r;
}
__device__ __forceinline__ unsigned int f2bf2(float lo, float hi) {
    return (unsigned)f2bf(lo) | ((unsigned)f2bf(hi) << 16);
}
// fast sigmoid via v_rcp_f32 (<=1e-7 rel err); output feeds bf16 -> safe
__device__ __forceinline__ float sigm(float x) {
    return __builtin_amdgcn_rcpf(1.0f + __expf(-x));
}

// ------- prep: weights -> bf16 MFMA-FRAGMENT ORDER; LN gamma folded into inw;
//         inb_f = inb + inw . lnb ; dww -> symmetrized f32 -------
__global__ __launch_bounds__(256) void k_prep(const float* __restrict__ outw,
    const float* __restrict__ mixw, const float* __restrict__ inw,
    const float* __restrict__ dww,
    const float* __restrict__ lng, const float* __restrict__ lnb,
    const float* __restrict__ inb,
    unsigned short* __restrict__ ob, unsigned short* __restrict__ mb,
    unsigned short* __restrict__ iwb, float* __restrict__ dws,
    float* __restrict__ inb_f)
{
    int i = blockIdx.x*256 + threadIdx.x;   // 0 .. 798719
    if (i < 524288) {
        // outw: per layer 256x512, instr = ks*16 + c4t
        int l = i >> 17, q = i & 131071;
        int j = q & 7, lane = (q >> 3) & 63, c4t = (q >> 9) & 15, ks = q >> 13;
        int src = (c4t*16 + (lane & 15))*512 + ks*32 + (lane >> 4)*8 + j;
        ob[i] = f2bf(outw[(size_t)l*131072 + src]);
    } else if (i < 655360) {
        // mixw: per layer 512x64, instr = (g*4+nt)*2 + half
        int v = i - 524288;
        int l = v >> 15, q = v & 32767;
        int j = q & 7, lane = (q >> 3) & 63, half = (q >> 9) & 1, gnt = q >> 10;
        int g = gnt >> 2, nt = gnt & 3;
        int src = (g*64 + nt*16 + (lane & 15))*64 + half*32 + (lane >> 4)*8 + j;
        mb[v] = f2bf(mixw[(size_t)l*32768 + src]);
    } else if (i < 786432) {
        // inw: per layer 1024x32, instr = g*8 + nt ; LN gamma folded in
        int v = i - 655360;
        int l = v >> 15, q = v & 32767;
        int j = q & 7, lane = (q >> 3) & 63, gnt = q >> 9;
        int g = gnt >> 3, nt = gnt & 7;
        int kk = (lane >> 4)*8 + j;               // k within group
        int src = (g*128 + nt*16 + (lane & 15))*32 + kk;
        float w = inw[(size_t)l*32768 + src] * lng[l*ND + g*32 + kk];
        iwb[v] = f2bf(w);
    } else if (i < 794624) {
        // dws[l][c][k] = 0.5*(dww[k] + dww[6-k]), k=0..3
        int v = i - 786432;
        int l = v >> 11, c = (v >> 2) & 511, k = v & 3;
        const float* w = dww + (size_t)l*3584 + c*7;
        dws[v] = 0.5f*(w[k] + w[6-k]);
    } else if (i < 798720) {
        // inb_f[l][c] = inb[l][c] + sum_k inw[l][c][k]*lnb[l][g*32+k]
        int v = i - 794624;
        int l = v >> 10, c = v & 1023, g = c >> 7;
        const float* wr = inw + (size_t)l*32768 + c*32;
        const float* lb = lnb + l*ND + g*32;
        float s = inb[l*NHH + c];
        #pragma unroll
        for (int k = 0; k < 32; ++k) s = fmaf(wr[k], lb[k], s);
        inb_f[v] = s;
    }
}

// ======= kL2<FIRST,LAST>: whole layer fused, 512 thr / 8 waves =======
// FIRST: h computed inline from x/w_in/b_in/pos (no k_init, no h HBM read).
// LAST : final layernorm fused into P4 (no kLN kernel).
template<bool FIRST, bool LAST>
__global__ __launch_bounds__(512, 8) void kL2(const float* __restrict__ hin,
    float* __restrict__ hout,
    const unsigned short* __restrict__ inw_b, const float* __restrict__ inb_f,
    const float* __restrict__ dws,
    const unsigned short* __restrict__ mixw_b, const float* __restrict__ mixb,
    const unsigned short* __restrict__ outw_b, const float* __restrict__ outb,
    const float* __restrict__ x, const float* __restrict__ w_in,
    const float* __restrict__ b_in, const float* __restrict__ pos,
    const float* __restrict__ olng, const float* __restrict__ olnb)
{
    const int b   = blockIdx.y;
    const int t0  = blockIdx.x * TILE;
    const int tid = threadIdx.x;            // 0..511
    const int lane = tid & 63, wvid = tid >> 6;   // 8 waves
    const int r_lo = lane & 15, kb = lane >> 4;
    const size_t rowbase = (size_t)b*NT;
    const bool interior = (t0 >= 3) && (t0 + HALO - 3 <= NT);  // halo fully in-range
    __shared__ __align__(16) unsigned short s_a[32*YST];   // y (32 rows) -> uc (16xUST)
    __shared__ __align__(16) unsigned short s_u[HALO*UST]; // u (22 rows) -> v (16 rows)

    // --- P0: h rows t0-3..t0+18 (load or inline-compute), LN -> s_a ---
    {
        const int r  = tid >> 4;            // 0..31; rows >= HALO skipped
        const int c0 = (tid & 15) * 16;
        if (r < HALO) {
            const int t  = t0 - 3 + r;
            const bool vld = interior || ((t >= 0) && (t < NT));
            float vals[16];
            if (vld) {
                if (FIRST) {
                    float xv = x[rowbase + t];
                    const float4* wp = reinterpret_cast<const float4*>(w_in + c0);
                    const float4* bp = reinterpret_cast<const float4*>(b_in + c0);
                    const float4* pp = reinterpret_cast<const float4*>(pos + t*ND + c0);
                    #pragma unroll
                    for (int j = 0; j < 4; ++j) {
                        float4 w = wp[j], bb = bp[j], p = pp[j];
                        vals[4*j+0] = fmaf(xv, w.x, bb.x + p.x);
                        vals[4*j+1] = fmaf(xv, w.y, bb.y + p.y);
                        vals[4*j+2] = fmaf(xv, w.z, bb.z + p.z);
                        vals[4*j+3] = fmaf(xv, w.w, bb.w + p.w);
                    }
                } else {
                    const float4* hp = reinterpret_cast<const float4*>(
                        hin + (rowbase + t)*ND + c0);
                    #pragma unroll
                    for (int j = 0; j < 4; ++j) {
                        float4 f = hp[j];
                        vals[4*j+0]=f.x; vals[4*j+1]=f.y; vals[4*j+2]=f.z; vals[4*j+3]=f.w;
                    }
                }
            } else {
                #pragma unroll
                for (int j = 0; j < 16; ++j) vals[j] = 0.0f;
            }
            float s = 0.f, s2 = 0.f;
            #pragma unroll
            for (int j = 0; j < 16; ++j) { s += vals[j]; s2 += vals[j]*vals[j]; }
            #pragma unroll
            for (int off = 1; off < 16; off <<= 1) {
                s  += __shfl_xor(s, off);
                s2 += __shfl_xor(s2, off);
            }
            float mu  = s * (1.0f/ND);
            float var = s2 * (1.0f/ND) - mu*mu;
            float rs  = rsqrtf(var + EPSF);
            if (!vld) rs = 0.0f;           // zero rows stay zero
            #pragma unroll
            for (int j = 0; j < 4; ++j) {
                float y0 = (vals[4*j+0]-mu)*rs;
                float y1 = (vals[4*j+1]-mu)*rs;
                float y2 = (vals[4*j+2]-mu)*rs;
                float y3 = (vals[4*j+3]-mu)*rs;
                u32x2 pk;
                pk[0] = f2bf2(y0, y1);
                pk[1] = f2bf2(y2, y3);
                *reinterpret_cast<u32x2*>(&s_a[r*YST + c0 + 4*j]) = pk;
            }
        }
    }
    __syncthreads();

    // --- P1: grouped in-proj. u over halo rows -> s_u; gates (central) -> regs ---
    unsigned int gpk[8];    // gates bf16-packed: [nt*2 + (r>>1)]
    {
        const int rt = wvid >> 2, g = wvid & 3;
        s16x8 a = *reinterpret_cast<const s16x8*>(
            &s_a[(rt*16 + r_lo)*YST + g*32 + kb*8]);
        #pragma unroll
        for (int half = 0; half < 2; ++half) {
            f32x4 acc[4];
            #pragma unroll
            for (int q = 0; q < 4; ++q) acc[q] = (f32x4){0.f,0.f,0.f,0.f};
            #pragma unroll
            for (int q = 0; q < 4; ++q) {
                const int nt = half*4 + q;
                s16x8 bf = *reinterpret_cast<const s16x8*>(
                    inw_b + (size_t)((g*8 + nt)*64 + lane)*8);
                acc[q] = __builtin_amdgcn_mfma_f32_16x16x32_bf16(a, bf, acc[q], 0, 0, 0);
            }
            if (interior) {
                #pragma unroll
                for (int q = 0; q < 4; ++q) {
                    const int nt = half*4 + q;
                    const int ocol = g*128 + nt*16 + r_lo;
                    const float bia = inb_f[ocol];
                    #pragma unroll
                    for (int r = 0; r < 4; ++r) {
                        const int hr = rt*16 + kb*4 + r;
                        if (hr < HALO) {
                            float tv = acc[q][r] + bia;
                            s_u[hr*UST + ocol] = f2bf(tv * sigm(tv));
                        }
                    }
                }
            } else {
                #pragma unroll
                for (int q = 0; q < 4; ++q) {
                    const int nt = half*4 + q;
                    const int ocol = g*128 + nt*16 + r_lo;
                    const float bia = inb_f[ocol];
                    #pragma unroll
                    for (int r = 0; r < 4; ++r) {
                        const int hr = rt*16 + kb*4 + r;
                        if (hr < HALO) {
                            const int t = t0 - 3 + hr;
                            unsigned short val = 0;
                            if (t >= 0 && t < NT) {
                                float tv = acc[q][r] + bia;
                                val = f2bf(tv * sigm(tv));
                            }
                            s_u[hr*UST + ocol] = val;
                        }
                    }
                }
            }
        }
        // gate-part: central rows (y rows 3..18); wave owns gate cols wvid*64..+63.
        s16x8 ag = *reinterpret_cast<const s16x8*>(
            &s_a[(3 + r_lo)*YST + 128 + (wvid >> 1)*32 + kb*8]);
        f32x4 gacc[4];
        #pragma unroll
        for (int nt = 0; nt < 4; ++nt) gacc[nt] = (f32x4){0.f,0.f,0.f,0.f};
        #pragma unroll
        for (int nt = 0; nt < 4; ++nt) {
            const int instr = (4 + (wvid >> 1))*8 + (wvid & 1)*4 + nt;
            s16x8 bf = *reinterpret_cast<const s16x8*>(
                inw_b + (size_t)(instr*64 + lane)*8);
            gacc[nt] = __builtin_amdgcn_mfma_f32_16x16x32_bf16(ag, bf, gacc[nt], 0, 0, 0);
        }
        #pragma unroll
        for (int nt = 0; nt < 4; ++nt) {
            const float bia = inb_f[512 + wvid*64 + nt*16 + r_lo];
            #pragma unroll
            for (int rp = 0; rp < 2; ++rp) {
                float s0 = sigm(gacc[nt][2*rp]   + bia);
                float s1 = sigm(gacc[nt][2*rp+1] + bia);
                gpk[nt*2 + rp] = f2bf2(s0, s1);
            }
        }
    }
    __syncthreads();

    // --- P2: symmetric conv (4 taps), PACKED row-pairs (cr, cr+8) via f32x2 ---
    {
        const float4 cw = *reinterpret_cast<const float4*>(dws + tid*4);
        f32x2 w0, w1, w2, w3, w4, w5;
        w0 = (f32x2){bf2f(s_u[0*UST + tid]), bf2f(s_u[ 8*UST + tid])};
        w1 = (f32x2){bf2f(s_u[1*UST + tid]), bf2f(s_u[ 9*UST + tid])};
        w2 = (f32x2){bf2f(s_u[2*UST + tid]), bf2f(s_u[10*UST + tid])};
        w3 = (f32x2){bf2f(s_u[3*UST + tid]), bf2f(s_u[11*UST + tid])};
        w4 = (f32x2){bf2f(s_u[4*UST + tid]), bf2f(s_u[12*UST + tid])};
        w5 = (f32x2){bf2f(s_u[5*UST + tid]), bf2f(s_u[13*UST + tid])};
        #pragma unroll
        for (int cr = 0; cr < 8; ++cr) {
            f32x2 w6 = (f32x2){bf2f(s_u[(cr + 6)*UST + tid]),
                               bf2f(s_u[(cr + 14)*UST + tid])};
            f32x2 s = cw.w * w3;
            s += cw.x * (w0 + w6);
            s += cw.y * (w1 + w5);
            s += cw.z * (w2 + w4);
            s_a[cr*UST + tid]       = f2bf(s[0]);
            s_a[(cr + 8)*UST + tid] = f2bf(s[1]);
            w0 = w1; w1 = w2; w2 = w3; w3 = w4; w4 = w5; w5 = w6;
        }
    }
    __syncthreads();

    // --- P3: grouped mix (K=64) + in-reg gates -> v (s_u rows 0..15) ---
    {
        const int g = wvid;
        s16x8 a0 = *reinterpret_cast<const s16x8*>(&s_a[r_lo*UST + g*64 + kb*8]);
        s16x8 a1 = *reinterpret_cast<const s16x8*>(&s_a[r_lo*UST + g*64 + 32 + kb*8]);
        f32x4 acc[4];
        #pragma unroll
        for (int nt = 0; nt < 4; ++nt) acc[nt] = (f32x4){0.f,0.f,0.f,0.f};
        #pragma unroll
        for (int nt = 0; nt < 4; ++nt) {
            s16x8 b0 = *reinterpret_cast<const s16x8*>(
                mixw_b + (size_t)(((g*4 + nt)*2 + 0)*64 + lane)*8);
            acc[nt] = __builtin_amdgcn_mfma_f32_16x16x32_bf16(a0, b0, acc[nt], 0, 0, 0);
        }
        #pragma unroll
        for (int nt = 0; nt < 4; ++nt) {
            s16x8 b1 = *reinterpret_cast<const s16x8*>(
                mixw_b + (size_t)(((g*4 + nt)*2 + 1)*64 + lane)*8);
            acc[nt] = __builtin_amdgcn_mfma_f32_16x16x32_bf16(a1, b1, acc[nt], 0, 0, 0);
        }
        #pragma unroll
        for (int nt = 0; nt < 4; ++nt) {
            const int ocol = g*64 + nt*16 + r_lo;
            const float bia = mixb[ocol];
            #pragma unroll
            for (int r = 0; r < 4; ++r) {
                const int cr = kb*4 + r;
                unsigned short gu = (unsigned short)
                    ((gpk[nt*2 + (r >> 1)] >> ((r & 1)*16)) & 0xffffu);
                s_u[cr*UST + ocol] = f2bf((acc[nt][r] + bia) * bf2f(gu));
            }
        }
    }
    __syncthreads();

    // --- P4: residual (load or recompute) + out-proj [+ final LN] -> hout ---
    float hres[2][4];
    #pragma unroll
    for (int c4 = 0; c4 < 2; ++c4) {
        const int d = wvid*32 + c4*16 + r_lo;
        #pragma unroll
        for (int r = 0; r < 4; ++r) {
            const int t = t0 + kb*4 + r;
            if (FIRST) {
                hres[c4][r] = (t < NT)
                    ? fmaf(x[rowbase + t], w_in[d], b_in[d] + pos[t*ND + d]) : 0.0f;
            } else {
                hres[c4][r] = (t < NT) ? hin[(rowbase + t)*ND + d] : 0.0f;
            }
        }
    }
    f32x4 acc4[2];
    #pragma unroll
    for (int c4 = 0; c4 < 2; ++c4) acc4[c4] = (f32x4){0.f,0.f,0.f,0.f};
    #pragma unroll
    for (int ks = 0; ks < 16; ++ks) {
        s16x8 a = *reinterpret_cast<const s16x8*>(&s_u[r_lo*UST + ks*32 + kb*8]);
        #pragma unroll
        for (int c4 = 0; c4 < 2; ++c4) {
            const int c4t = wvid*2 + c4;
            s16x8 bf = *reinterpret_cast<const s16x8*>(
                outw_b + (size_t)((ks*16 + c4t)*64 + lane)*8);
            acc4[c4] = __builtin_amdgcn_mfma_f32_16x16x32_bf16(a, bf, acc4[c4], 0, 0, 0);
        }
    }
    if (!LAST) {
        #pragma unroll
        for (int c4 = 0; c4 < 2; ++c4) {
            const int d = wvid*32 + c4*16 + r_lo;
            const float ob = outb[d];
            #pragma unroll
            for (int r = 0; r < 4; ++r) {
                const int cr = kb*4 + r;
                const int t = t0 + cr;
                if (t < NT)
                    hout[(rowbase + t)*ND + d] = hres[c4][r] + acc4[c4][r] + ob;
            }
        }
    } else {
        // final-LN fusion: block owns full 256-col rows.
        float outv[2][4];
        #pragma unroll
        for (int c4 = 0; c4 < 2; ++c4) {
            const int d = wvid*32 + c4*16 + r_lo;
            const float ob = outb[d];
            #pragma unroll
            for (int r = 0; r < 4; ++r)
                outv[c4][r] = hres[c4][r] + acc4[c4][r] + ob;
        }
        // per-row partial sums: reduce over r_lo (16 lanes) x c4 (2)
        f32x2* part = reinterpret_cast<f32x2*>(s_a);   // [16 rows][8 waves]
        #pragma unroll
        for (int r = 0; r < 4; ++r) {
            float s  = outv[0][r] + outv[1][r];
            float s2 = outv[0][r]*outv[0][r] + outv[1][r]*outv[1][r];
            #pragma unroll
            for (int off = 1; off < 16; off <<= 1) {   // within 16-lane group
                s  += __shfl_xor(s, off);
                s2 += __shfl_xor(s2, off);
            }
            if (r_lo == 0) part[(kb*4 + r)*8 + wvid] = (f32x2){s, s2};
        }
        __syncthreads();
        #pragma unroll
        for (int c4 = 0; c4 < 2; ++c4) {
            const int d = wvid*32 + c4*16 + r_lo;
            const float og = olng[d], obb = olnb[d];
            #pragma unroll
            for (int r = 0; r < 4; ++r) {
                const int cr = kb*4 + r;
                const int t = t0 + cr;
                if (t < NT) {
                    f32x2 tot = (f32x2){0.f, 0.f};
                    #pragma unroll
                    for (int w = 0; w < 8; ++w) tot += part[cr*8 + w];
                    float mu  = tot[0] * (1.0f/ND);
                    float var = tot[1] * (1.0f/ND) - mu*mu;
                    float rs  = rsqrtf(var + EPSF);
                    hout[(rowbase + t)*ND + d] =
                        (outv[c4][r] - mu)*rs*og + obb;
                }
            }
        }
    }
}

extern "C" void kernel_launch(void* const* d_in, const int* in_sizes, int n_in,
                              void* d_out, int out_size, void* d_ws, size_t ws_size,
                              hipStream_t stream)
{
    const float* x    = (const float*)d_in[0];
    const float* w_in = (const float*)d_in[1];
    const float* b_in = (const float*)d_in[2];
    const float* pos  = (const float*)d_in[3];
    const float* ln_g = (const float*)d_in[4];
    const float* ln_b = (const float*)d_in[5];
    const float* inw  = (const float*)d_in[6];
    const float* inb  = (const float*)d_in[7];
    const float* dww  = (const float*)d_in[8];
    const float* mixw = (const float*)d_in[9];
    const float* mixb = (const float*)d_in[10];
    const float* outw = (const float*)d_in[11];
    const float* outb = (const float*)d_in[12];
    const float* olng = (const float*)d_in[13];
    const float* olnb = (const float*)d_in[14];

    float* hA = (float*)d_out;                         // final result here
    float* hB = (float*)d_ws;
    unsigned short* outw_b = (unsigned short*)((char*)d_ws + (size_t)NPOS*ND*4);
    unsigned short* mixw_b = outw_b + 524288;          // L*D*H
    unsigned short* inw_b  = mixw_b + 131072;          // L*H*64 ; then L*1024*32
    float*          dws    = (float*)(inw_b + 131072); // L*512*4 symmetrized conv wts
    float*          inb_f  = dws + 8192;               // L*1024 folded in-proj bias

    k_prep<<<3120, 256, 0, stream>>>(outw, mixw, inw, dww, ln_g, ln_b, inb,
                                     outw_b, mixw_b, inw_b, dws, inb_f);
    // layer 0: FIRST (h inline from x/w_in/b_in/pos) -> hB
    kL2<true,false><<<dim3(18, NB), 512, 0, stream>>>(hA, hB,
        inw_b, inb_f, dws, mixw_b, mixb, outw_b, outb,
        x, w_in, b_in, pos, olng, olnb);
    // layer 1: hB -> hA
    kL2<false,false><<<dim3(18, NB), 512, 0, stream>>>(hB, hA,
        inw_b + 32768, inb_f + NHH, dws + 2048,
        mixw_b + 32768, mixb + NH, outw_b + 131072, outb + ND,
        x, w_in, b_in, pos, olng, olnb);
    // layer 2: hA -> hB
    kL2<false,false><<<dim3(18, NB), 512, 0, stream>>>(hA, hB,
        inw_b + 2*32768, inb_f + 2*NHH, dws + 2*2048,
        mixw_b + 2*32768, mixb + 2*NH, outw_b + 2*131072, outb + 2*ND,
        x, w_in, b_in, pos, olng, olnb);
    // layer 3: LAST (final LN fused) hB -> hA (= d_out)
    kL2<false,true><<<dim3(18, NB), 512, 0, stream>>>(hB, hA,
        inw_b + 3*32768, inb_f + 3*NHH, dws + 3*2048,
        mixw_b + 3*32768, mixb + 3*NH, outw_b + 3*131072, outb + 3*ND,
        x, w_in, b_in, pos, olng, olnb);
}

// Round 22
// 826.329 us; speedup vs baseline: 3.5183x; 1.0500x over previous
//
#include <hip/hip_runtime.h>
#include <hip/hip_bf16.h>

#define NB 512
#define NT 274
#define ND 256
#define NH 512
#define NHH 1024
#define NPOS (NB*NT)
#define EPSF 1e-5f
#define TILE 16
#define HALO 22
#define YST 264    // y row stride (elems); 32 rows in s_a
#define UST 520    // u/uc/v row stride

typedef float f32x4 __attribute__((ext_vector_type(4)));
typedef float f32x2 __attribute__((ext_vector_type(2)));
typedef unsigned int u32x4 __attribute__((ext_vector_type(4)));
typedef unsigned int u32x2 __attribute__((ext_vector_type(2)));
typedef short s16x8 __attribute__((ext_vector_type(8)));   // 8 bf16 = 4 VGPRs

__device__ __forceinline__ float bf2f(unsigned short s) {
    unsigned int u = ((unsigned int)s) << 16;
    float f; __builtin_memcpy(&f, &u, 4); return f;
}
__device__ __forceinline__ unsigned short f2bf(float f) {
    __hip_bfloat16 b = __float2bfloat16(f);
    unsigned short r; __builtin_memcpy(&r, &b, 2); return r;
}
__device__ __forceinline__ unsigned int f2bf2(float lo, float hi) {
    return (unsigned)f2bf(lo) | ((unsigned)f2bf(hi) << 16);
}
// fast sigmoid via v_rcp_f32 (<=1e-7 rel err); output feeds bf16 -> safe
__device__ __forceinline__ float sigm(float x) {
    return __builtin_amdgcn_rcpf(1.0f + __expf(-x));
}

// ------- prep: weights -> bf16 MFMA-FRAGMENT ORDER; LN gamma folded into inw;
//         inb_f = inb + inw . lnb ; dww -> symmetrized f32 -------
__global__ __launch_bounds__(256) void k_prep(const float* __restrict__ outw,
    const float* __restrict__ mixw, const float* __restrict__ inw,
    const float* __restrict__ dww,
    const float* __restrict__ lng, const float* __restrict__ lnb,
    const float* __restrict__ inb,
    unsigned short* __restrict__ ob, unsigned short* __restrict__ mb,
    unsigned short* __restrict__ iwb, float* __restrict__ dws,
    float* __restrict__ inb_f)
{
    int i = blockIdx.x*256 + threadIdx.x;   // 0 .. 798719
    if (i < 524288) {
        // outw: per layer 256x512, instr = ks*16 + c4t
        int l = i >> 17, q = i & 131071;
        int j = q & 7, lane = (q >> 3) & 63, c4t = (q >> 9) & 15, ks = q >> 13;
        int src = (c4t*16 + (lane & 15))*512 + ks*32 + (lane >> 4)*8 + j;
        ob[i] = f2bf(outw[(size_t)l*131072 + src]);
    } else if (i < 655360) {
        // mixw: per layer 512x64, instr = (g*4+nt)*2 + half
        int v = i - 524288;
        int l = v >> 15, q = v & 32767;
        int j = q & 7, lane = (q >> 3) & 63, half = (q >> 9) & 1, gnt = q >> 10;
        int g = gnt >> 2, nt = gnt & 3;
        int src = (g*64 + nt*16 + (lane & 15))*64 + half*32 + (lane >> 4)*8 + j;
        mb[v] = f2bf(mixw[(size_t)l*32768 + src]);
    } else if (i < 786432) {
        // inw: per layer 1024x32, instr = g*8 + nt ; LN gamma folded in
        int v = i - 655360;
        int l = v >> 15, q = v & 32767;
        int j = q & 7, lane = (q >> 3) & 63, gnt = q >> 9;
        int g = gnt >> 3, nt = gnt & 7;
        int kk = (lane >> 4)*8 + j;               // k within group
        int src = (g*128 + nt*16 + (lane & 15))*32 + kk;
        float w = inw[(size_t)l*32768 + src] * lng[l*ND + g*32 + kk];
        iwb[v] = f2bf(w);
    } else if (i < 794624) {
        // dws[l][c][k] = 0.5*(dww[k] + dww[6-k]), k=0..3
        int v = i - 786432;
        int l = v >> 11, c = (v >> 2) & 511, k = v & 3;
        const float* w = dww + (size_t)l*3584 + c*7;
        dws[v] = 0.5f*(w[k] + w[6-k]);
    } else if (i < 798720) {
        // inb_f[l][c] = inb[l][c] + sum_k inw[l][c][k]*lnb[l][g*32+k]
        int v = i - 794624;
        int l = v >> 10, c = v & 1023, g = c >> 7;
        const float* wr = inw + (size_t)l*32768 + c*32;
        const float* lb = lnb + l*ND + g*32;
        float s = inb[l*NHH + c];
        #pragma unroll
        for (int k = 0; k < 32; ++k) s = fmaf(wr[k], lb[k], s);
        inb_f[v] = s;
    }
}

// ======= kL2<FIRST,LAST>: whole layer fused, 512 thr / 8 waves =======
// FIRST: h computed inline from x/w_in/b_in/pos. LAST: final LN fused.
// r22: biases pre-loaded into MFMA accumulators (C-in == C-out) -> epilogue
// adds deleted (~72 VALU ops/thread); P0 LDS stores widened to b128.
template<bool FIRST, bool LAST>
__global__ __launch_bounds__(512, 8) void kL2(const float* __restrict__ hin,
    float* __restrict__ hout,
    const unsigned short* __restrict__ inw_b, const float* __restrict__ inb_f,
    const float* __restrict__ dws,
    const unsigned short* __restrict__ mixw_b, const float* __restrict__ mixb,
    const unsigned short* __restrict__ outw_b, const float* __restrict__ outb,
    const float* __restrict__ x, const float* __restrict__ w_in,
    const float* __restrict__ b_in, const float* __restrict__ pos,
    const float* __restrict__ olng, const float* __restrict__ olnb)
{
    const int b   = blockIdx.y;
    const int t0  = blockIdx.x * TILE;
    const int tid = threadIdx.x;            // 0..511
    const int lane = tid & 63, wvid = tid >> 6;   // 8 waves
    const int r_lo = lane & 15, kb = lane >> 4;
    const size_t rowbase = (size_t)b*NT;
    const bool interior = (t0 >= 3) && (t0 + HALO - 3 <= NT);  // halo fully in-range
    __shared__ __align__(16) unsigned short s_a[32*YST];   // y (32 rows) -> uc (16xUST)
    __shared__ __align__(16) unsigned short s_u[HALO*UST]; // u (22 rows) -> v (16 rows)

    // --- P0: h rows t0-3..t0+18 (load or inline-compute), LN -> s_a ---
    {
        const int r  = tid >> 4;            // 0..31; rows >= HALO skipped
        const int c0 = (tid & 15) * 16;
        if (r < HALO) {
            const int t  = t0 - 3 + r;
            const bool vld = interior || ((t >= 0) && (t < NT));
            float vals[16];
            if (vld) {
                if (FIRST) {
                    float xv = x[rowbase + t];
                    const float4* wp = reinterpret_cast<const float4*>(w_in + c0);
                    const float4* bp = reinterpret_cast<const float4*>(b_in + c0);
                    const float4* pp = reinterpret_cast<const float4*>(pos + t*ND + c0);
                    #pragma unroll
                    for (int j = 0; j < 4; ++j) {
                        float4 w = wp[j], bb = bp[j], p = pp[j];
                        vals[4*j+0] = fmaf(xv, w.x, bb.x + p.x);
                        vals[4*j+1] = fmaf(xv, w.y, bb.y + p.y);
                        vals[4*j+2] = fmaf(xv, w.z, bb.z + p.z);
                        vals[4*j+3] = fmaf(xv, w.w, bb.w + p.w);
                    }
                } else {
                    const float4* hp = reinterpret_cast<const float4*>(
                        hin + (rowbase + t)*ND + c0);
                    #pragma unroll
                    for (int j = 0; j < 4; ++j) {
                        float4 f = hp[j];
                        vals[4*j+0]=f.x; vals[4*j+1]=f.y; vals[4*j+2]=f.z; vals[4*j+3]=f.w;
                    }
                }
            } else {
                #pragma unroll
                for (int j = 0; j < 16; ++j) vals[j] = 0.0f;
            }
            float s = 0.f, s2 = 0.f;
            #pragma unroll
            for (int j = 0; j < 16; ++j) { s += vals[j]; s2 += vals[j]*vals[j]; }
            #pragma unroll
            for (int off = 1; off < 16; off <<= 1) {
                s  += __shfl_xor(s, off);
                s2 += __shfl_xor(s2, off);
            }
            float mu  = s * (1.0f/ND);
            float var = s2 * (1.0f/ND) - mu*mu;
            float rs  = rsqrtf(var + EPSF);
            if (!vld) rs = 0.0f;           // zero rows stay zero
            #pragma unroll
            for (int jj = 0; jj < 2; ++jj) {
                u32x4 pk;
                #pragma unroll
                for (int q = 0; q < 2; ++q) {
                    const int j = jj*2 + q;
                    float y0 = (vals[4*j+0]-mu)*rs;
                    float y1 = (vals[4*j+1]-mu)*rs;
                    float y2 = (vals[4*j+2]-mu)*rs;
                    float y3 = (vals[4*j+3]-mu)*rs;
                    pk[2*q+0] = f2bf2(y0, y1);
                    pk[2*q+1] = f2bf2(y2, y3);
                }
                *reinterpret_cast<u32x4*>(&s_a[r*YST + c0 + 8*jj]) = pk;
            }
        }
    }
    __syncthreads();

    // --- P1: grouped in-proj. u over halo rows -> s_u; gates (central) -> regs ---
    unsigned int gpk[8];    // gates bf16-packed: [nt*2 + (r>>1)]
    {
        const int rt = wvid >> 2, g = wvid & 3;
        s16x8 a = *reinterpret_cast<const s16x8*>(
            &s_a[(rt*16 + r_lo)*YST + g*32 + kb*8]);
        #pragma unroll
        for (int half = 0; half < 2; ++half) {
            f32x4 acc[4];
            #pragma unroll
            for (int q = 0; q < 4; ++q) {               // bias pre-loaded into C
                const float bia = inb_f[g*128 + (half*4 + q)*16 + r_lo];
                acc[q] = (f32x4){bia, bia, bia, bia};
            }
            #pragma unroll
            for (int q = 0; q < 4; ++q) {
                const int nt = half*4 + q;
                s16x8 bf = *reinterpret_cast<const s16x8*>(
                    inw_b + (size_t)((g*8 + nt)*64 + lane)*8);
                acc[q] = __builtin_amdgcn_mfma_f32_16x16x32_bf16(a, bf, acc[q], 0, 0, 0);
            }
            if (interior) {
                #pragma unroll
                for (int q = 0; q < 4; ++q) {
                    const int nt = half*4 + q;
                    const int ocol = g*128 + nt*16 + r_lo;
                    #pragma unroll
                    for (int r = 0; r < 4; ++r) {
                        const int hr = rt*16 + kb*4 + r;
                        if (hr < HALO) {
                            float tv = acc[q][r];
                            s_u[hr*UST + ocol] = f2bf(tv * sigm(tv));
                        }
                    }
                }
            } else {
                #pragma unroll
                for (int q = 0; q < 4; ++q) {
                    const int nt = half*4 + q;
                    const int ocol = g*128 + nt*16 + r_lo;
                    #pragma unroll
                    for (int r = 0; r < 4; ++r) {
                        const int hr = rt*16 + kb*4 + r;
                        if (hr < HALO) {
                            const int t = t0 - 3 + hr;
                            unsigned short val = 0;
                            if (t >= 0 && t < NT) {
                                float tv = acc[q][r];
                                val = f2bf(tv * sigm(tv));
                            }
                            s_u[hr*UST + ocol] = val;
                        }
                    }
                }
            }
        }
        // gate-part: central rows (y rows 3..18); wave owns gate cols wvid*64..+63.
        s16x8 ag = *reinterpret_cast<const s16x8*>(
            &s_a[(3 + r_lo)*YST + 128 + (wvid >> 1)*32 + kb*8]);
        f32x4 gacc[4];
        #pragma unroll
        for (int nt = 0; nt < 4; ++nt) {               // bias pre-loaded into C
            const float bia = inb_f[512 + wvid*64 + nt*16 + r_lo];
            gacc[nt] = (f32x4){bia, bia, bia, bia};
        }
        #pragma unroll
        for (int nt = 0; nt < 4; ++nt) {
            const int instr = (4 + (wvid >> 1))*8 + (wvid & 1)*4 + nt;
            s16x8 bf = *reinterpret_cast<const s16x8*>(
                inw_b + (size_t)(instr*64 + lane)*8);
            gacc[nt] = __builtin_amdgcn_mfma_f32_16x16x32_bf16(ag, bf, gacc[nt], 0, 0, 0);
        }
        #pragma unroll
        for (int nt = 0; nt < 4; ++nt) {
            #pragma unroll
            for (int rp = 0; rp < 2; ++rp) {
                float s0 = sigm(gacc[nt][2*rp]);
                float s1 = sigm(gacc[nt][2*rp+1]);
                gpk[nt*2 + rp] = f2bf2(s0, s1);
            }
        }
    }
    __syncthreads();

    // --- P2: symmetric conv (4 taps), PACKED row-pairs (cr, cr+8) via f32x2 ---
    {
        const float4 cw = *reinterpret_cast<const float4*>(dws + tid*4);
        f32x2 w0, w1, w2, w3, w4, w5;
        w0 = (f32x2){bf2f(s_u[0*UST + tid]), bf2f(s_u[ 8*UST + tid])};
        w1 = (f32x2){bf2f(s_u[1*UST + tid]), bf2f(s_u[ 9*UST + tid])};
        w2 = (f32x2){bf2f(s_u[2*UST + tid]), bf2f(s_u[10*UST + tid])};
        w3 = (f32x2){bf2f(s_u[3*UST + tid]), bf2f(s_u[11*UST + tid])};
        w4 = (f32x2){bf2f(s_u[4*UST + tid]), bf2f(s_u[12*UST + tid])};
        w5 = (f32x2){bf2f(s_u[5*UST + tid]), bf2f(s_u[13*UST + tid])};
        #pragma unroll
        for (int cr = 0; cr < 8; ++cr) {
            f32x2 w6 = (f32x2){bf2f(s_u[(cr + 6)*UST + tid]),
                               bf2f(s_u[(cr + 14)*UST + tid])};
            f32x2 s = cw.w * w3;
            s += cw.x * (w0 + w6);
            s += cw.y * (w1 + w5);
            s += cw.z * (w2 + w4);
            s_a[cr*UST + tid]       = f2bf(s[0]);
            s_a[(cr + 8)*UST + tid] = f2bf(s[1]);
            w0 = w1; w1 = w2; w2 = w3; w3 = w4; w4 = w5; w5 = w6;
        }
    }
    __syncthreads();

    // --- P3: grouped mix (K=64) + in-reg gates -> v (s_u rows 0..15) ---
    {
        const int g = wvid;
        s16x8 a0 = *reinterpret_cast<const s16x8*>(&s_a[r_lo*UST + g*64 + kb*8]);
        s16x8 a1 = *reinterpret_cast<const s16x8*>(&s_a[r_lo*UST + g*64 + 32 + kb*8]);
        f32x4 acc[4];
        #pragma unroll
        for (int nt = 0; nt < 4; ++nt) {               // bias pre-loaded into C
            const float bia = mixb[g*64 + nt*16 + r_lo];
            acc[nt] = (f32x4){bia, bia, bia, bia};
        }
        #pragma unroll
        for (int nt = 0; nt < 4; ++nt) {
            s16x8 b0 = *reinterpret_cast<const s16x8*>(
                mixw_b + (size_t)(((g*4 + nt)*2 + 0)*64 + lane)*8);
            acc[nt] = __builtin_amdgcn_mfma_f32_16x16x32_bf16(a0, b0, acc[nt], 0, 0, 0);
        }
        #pragma unroll
        for (int nt = 0; nt < 4; ++nt) {
            s16x8 b1 = *reinterpret_cast<const s16x8*>(
                mixw_b + (size_t)(((g*4 + nt)*2 + 1)*64 + lane)*8);
            acc[nt] = __builtin_amdgcn_mfma_f32_16x16x32_bf16(a1, b1, acc[nt], 0, 0, 0);
        }
        #pragma unroll
        for (int nt = 0; nt < 4; ++nt) {
            const int ocol = g*64 + nt*16 + r_lo;
            #pragma unroll
            for (int r = 0; r < 4; ++r) {
                const int cr = kb*4 + r;
                unsigned short gu = (unsigned short)
                    ((gpk[nt*2 + (r >> 1)] >> ((r & 1)*16)) & 0xffffu);
                s_u[cr*UST + ocol] = f2bf(acc[nt][r] * bf2f(gu));
            }
        }
    }
    __syncthreads();

    // --- P4: residual (load or recompute) + out-proj [+ final LN] -> hout ---
    float hres[2][4];
    #pragma unroll
    for (int c4 = 0; c4 < 2; ++c4) {
        const int d = wvid*32 + c4*16 + r_lo;
        #pragma unroll
        for (int r = 0; r < 4; ++r) {
            const int t = t0 + kb*4 + r;
            if (FIRST) {
                hres[c4][r] = (t < NT)
                    ? fmaf(x[rowbase + t], w_in[d], b_in[d] + pos[t*ND + d]) : 0.0f;
            } else {
                hres[c4][r] = (t < NT) ? hin[(rowbase + t)*ND + d] : 0.0f;
            }
        }
    }
    f32x4 acc4[2];
    #pragma unroll
    for (int c4 = 0; c4 < 2; ++c4) {                   // out-bias pre-loaded into C
        const float ob = outb[wvid*32 + c4*16 + r_lo];
        acc4[c4] = (f32x4){ob, ob, ob, ob};
    }
    #pragma unroll
    for (int ks = 0; ks < 16; ++ks) {
        s16x8 a = *reinterpret_cast<const s16x8*>(&s_u[r_lo*UST + ks*32 + kb*8]);
        #pragma unroll
        for (int c4 = 0; c4 < 2; ++c4) {
            const int c4t = wvid*2 + c4;
            s16x8 bf = *reinterpret_cast<const s16x8*>(
                outw_b + (size_t)((ks*16 + c4t)*64 + lane)*8);
            acc4[c4] = __builtin_amdgcn_mfma_f32_16x16x32_bf16(a, bf, acc4[c4], 0, 0, 0);
        }
    }
    if (!LAST) {
        #pragma unroll
        for (int c4 = 0; c4 < 2; ++c4) {
            const int d = wvid*32 + c4*16 + r_lo;
            #pragma unroll
            for (int r = 0; r < 4; ++r) {
                const int cr = kb*4 + r;
                const int t = t0 + cr;
                if (t < NT)
                    hout[(rowbase + t)*ND + d] = hres[c4][r] + acc4[c4][r];
            }
        }
    } else {
        // final-LN fusion: block owns full 256-col rows.
        float outv[2][4];
        #pragma unroll
        for (int c4 = 0; c4 < 2; ++c4) {
            #pragma unroll
            for (int r = 0; r < 4; ++r)
                outv[c4][r] = hres[c4][r] + acc4[c4][r];
        }
        // per-row partial sums: reduce over r_lo (16 lanes) x c4 (2)
        f32x2* part = reinterpret_cast<f32x2*>(s_a);   // [16 rows][8 waves]
        #pragma unroll
        for (int r = 0; r < 4; ++r) {
            float s  = outv[0][r] + outv[1][r];
            float s2 = outv[0][r]*outv[0][r] + outv[1][r]*outv[1][r];
            #pragma unroll
            for (int off = 1; off < 16; off <<= 1) {   // within 16-lane group
                s  += __shfl_xor(s, off);
                s2 += __shfl_xor(s2, off);
            }
            if (r_lo == 0) part[(kb*4 + r)*8 + wvid] = (f32x2){s, s2};
        }
        __syncthreads();
        #pragma unroll
        for (int c4 = 0; c4 < 2; ++c4) {
            const int d = wvid*32 + c4*16 + r_lo;
            const float og = olng[d], obb = olnb[d];
            #pragma unroll
            for (int r = 0; r < 4; ++r) {
                const int cr = kb*4 + r;
                const int t = t0 + cr;
                if (t < NT) {
                    f32x2 tot = (f32x2){0.f, 0.f};
                    #pragma unroll
                    for (int w = 0; w < 8; ++w) tot += part[cr*8 + w];
                    float mu  = tot[0] * (1.0f/ND);
                    float var = tot[1] * (1.0f/ND) - mu*mu;
                    float rs  = rsqrtf(var + EPSF);
                    hout[(rowbase + t)*ND + d] =
                        (outv[c4][r] - mu)*rs*og + obb;
                }
            }
        }
    }
}

extern "C" void kernel_launch(void* const* d_in, const int* in_sizes, int n_in,
                              void* d_out, int out_size, void* d_ws, size_t ws_size,
                              hipStream_t stream)
{
    const float* x    = (const float*)d_in[0];
    const float* w_in = (const float*)d_in[1];
    const float* b_in = (const float*)d_in[2];
    const float* pos  = (const float*)d_in[3];
    const float* ln_g = (const float*)d_in[4];
    const float* ln_b = (const float*)d_in[5];
    const float* inw  = (const float*)d_in[6];
    const float* inb  = (const float*)d_in[7];
    const float* dww  = (const float*)d_in[8];
    const float* mixw = (const float*)d_in[9];
    const float* mixb = (const float*)d_in[10];
    const float* outw = (const float*)d_in[11];
    const float* outb = (const float*)d_in[12];
    const float* olng = (const float*)d_in[13];
    const float* olnb = (const float*)d_in[14];

    float* hA = (float*)d_out;                         // final result here
    float* hB = (float*)d_ws;
    unsigned short* outw_b = (unsigned short*)((char*)d_ws + (size_t)NPOS*ND*4);
    unsigned short* mixw_b = outw_b + 524288;          // L*D*H
    unsigned short* inw_b  = mixw_b + 131072;          // L*H*64 ; then L*1024*32
    float*          dws    = (float*)(inw_b + 131072); // L*512*4 symmetrized conv wts
    float*          inb_f  = dws + 8192;               // L*1024 folded in-proj bias

    k_prep<<<3120, 256, 0, stream>>>(outw, mixw, inw, dww, ln_g, ln_b, inb,
                                     outw_b, mixw_b, inw_b, dws, inb_f);
    // layer 0: FIRST (h inline from x/w_in/b_in/pos) -> hB
    kL2<true,false><<<dim3(18, NB), 512, 0, stream>>>(hA, hB,
        inw_b, inb_f, dws, mixw_b, mixb, outw_b, outb,
        x, w_in, b_in, pos, olng, olnb);
    // layer 1: hB -> hA
    kL2<false,false><<<dim3(18, NB), 512, 0, stream>>>(hB, hA,
        inw_b + 32768, inb_f + NHH, dws + 2048,
        mixw_b + 32768, mixb + NH, outw_b + 131072, outb + ND,
        x, w_in, b_in, pos, olng, olnb);
    // layer 2: hA -> hB
    kL2<false,false><<<dim3(18, NB), 512, 0, stream>>>(hA, hB,
        inw_b + 2*32768, inb_f + 2*NHH, dws + 2*2048,
        mixw_b + 2*32768, mixb + 2*NH, outw_b + 2*131072, outb + 2*ND,
        x, w_in, b_in, pos, olng, olnb);
    // layer 3: LAST (final LN fused) hB -> hA (= d_out)
    kL2<false,true><<<dim3(18, NB), 512, 0, stream>>>(hB, hA,
        inw_b + 3*32768, inb_f + 3*NHH, dws + 3*2048,
        mixw_b + 3*32768, mixb + 3*NH, outw_b + 3*131072, outb + 3*ND,
        x, w_in, b_in, pos, olng, olnb);
}